// Round 3
// baseline (1232.264 us; speedup 1.0000x reference)
//
#include <hip/hip_runtime.h>

// dtypes per harness contract: float tensors fp32 (per reference), edge_index
// int32 ("integer -> const int*"), output fp32.
// Pipeline:
//   deg/dinv -> scatter norm*x into agg1 (GCN1 aggregate BEFORE matmul, 32 dims)
//   node_pre: h1 = tanh(agg1 @ Wg1 + b); atab/btab = h1 @ split(W1)  (EdgeConv algebra:
//             [x_i, x_j-x_i]@W1 = x_i@(W1a-W1b) + x_j@W1b)
//   edge_mlp: u = relu(atab[c]+btab[r]); m = u@W2+b2; hmax[c] = max(hmax[c], relu(m))
//   gcn2:     h2 = hmax@Wg2; out = bg2 + dinv^2*h2 + scatter(norm*h2[row])

__global__ void k_zero4(float4* p, int n4) {
    int i = blockIdx.x * blockDim.x + threadIdx.x;
    if (i < n4) p[i] = make_float4(0.f, 0.f, 0.f, 0.f);
}

__global__ void k_deg(const int* __restrict__ col, int* __restrict__ deg, int E) {
    int e = blockIdx.x * blockDim.x + threadIdx.x;
    if (e < E) atomicAdd(&deg[col[e]], 1);
}

__global__ void k_dinv(const int* __restrict__ deg, float* __restrict__ dinv, int n) {
    int v = blockIdx.x * blockDim.x + threadIdx.x;
    if (v < n) dinv[v] = rsqrtf((float)(deg[v] + 1));   // +1 self loop
}

// scatter norm * x[row] (32 dims) into agg1[col]
__global__ void k_gcn1_scatter(const int* __restrict__ row, const int* __restrict__ col,
                               const float* __restrict__ x, const float* __restrict__ dinv,
                               float* __restrict__ agg1, int E) {
    int t = blockIdx.x * blockDim.x + threadIdx.x;
    int e = t >> 3, g = t & 7;       // 8 threads/edge, 4 floats each
    if (e >= E) return;
    int r = row[e], c = col[e];
    float norm = dinv[r] * dinv[c];
    const float4* x4 = (const float4*)x;
    float4 xv = x4[r * 8 + g];
    float* dst = agg1 + c * 32 + g * 4;
    atomicAdd(dst + 0, norm * xv.x);
    atomicAdd(dst + 1, norm * xv.y);
    atomicAdd(dst + 2, norm * xv.z);
    atomicAdd(dst + 3, norm * xv.w);
}

// fused GCN1-finish + EdgeConv-layer1 tables; one node per wave (64 threads)
__global__ void k_node_pre(const float* __restrict__ agg1, const float* __restrict__ x,
                           const float* __restrict__ dinv,
                           const float* __restrict__ gw, const float* __restrict__ gb,
                           const float* __restrict__ w1, const float* __restrict__ b1,
                           float* __restrict__ atab, float* __restrict__ btab, int n) {
    int v = blockIdx.x;
    int j = threadIdx.x;             // 64
    float dv = dinv[v], d2 = dv * dv;
    float acc = gb[j];
#pragma unroll
    for (int d = 0; d < 32; ++d) {
        float s = agg1[v * 32 + d] + d2 * x[v * 32 + d];
        acc = fmaf(s, gw[d * 64 + j], acc);
    }
    float hj = tanhf(acc);
    float acca = b1[j], accb = 0.f;
#pragma unroll 8
    for (int d = 0; d < 64; ++d) {
        float hd = __shfl(hj, d, 64);
        float wt = w1[d * 64 + j];
        float wb = w1[(64 + d) * 64 + j];
        acca = fmaf(hd, wt - wb, acca);
        accb = fmaf(hd, wb, accb);
    }
    atab[v * 64 + j] = acca;
    btab[v * 64 + j] = accb;
}

// 8 edges per wave; W2 staged in LDS once per block
__global__ __launch_bounds__(256) void k_edge_mlp(
        const int* __restrict__ row, const int* __restrict__ col,
        const float* __restrict__ atab, const float* __restrict__ btab,
        const float* __restrict__ w2, const float* __restrict__ b2,
        unsigned int* __restrict__ hmax, int E) {
    __shared__ float w2s[64 * 64];
    for (int i = threadIdx.x; i < 64 * 64; i += 256) w2s[i] = w2[i];
    __syncthreads();
    const int EPW = 8;
    int lane = threadIdx.x & 63;
    int wid  = blockIdx.x * 4 + (threadIdx.x >> 6);
    int ebase = wid * EPW;
    float bias = b2[lane];
    float u[EPW];
    int   cc[EPW];
#pragma unroll
    for (int q = 0; q < EPW; ++q) {
        int e = ebase + q;
        if (e < E) {
            int r = row[e], c = col[e];
            cc[q] = c;
            u[q] = fmaxf(atab[c * 64 + lane] + btab[r * 64 + lane], 0.f);
        } else { cc[q] = -1; u[q] = 0.f; }
    }
    float acc[EPW];
#pragma unroll
    for (int q = 0; q < EPW; ++q) acc[q] = bias;
    for (int k2 = 0; k2 < 64; ++k2) {
        float w = w2s[k2 * 64 + lane];
#pragma unroll
        for (int q = 0; q < EPW; ++q) {
            float uk = __shfl(u[q], k2, 64);
            acc[q] = fmaf(uk, w, acc[q]);
        }
    }
#pragma unroll
    for (int q = 0; q < EPW; ++q) {
        if (cc[q] >= 0) {
            float mm = fmaxf(acc[q], 0.f);           // fold relu + empty-segment-0 into max
            atomicMax(&hmax[cc[q] * 64 + lane], __float_as_uint(mm));  // vals >= 0: uint order ok
        }
    }
}

// h2 = hmax @ Wg2 (64->16); out = bg2 + dinv^2 * h2  (fully initializes d_out)
__global__ void k_gcn2_node(const float* __restrict__ hmax_f,
                            const float* __restrict__ wg, const float* __restrict__ bg,
                            const float* __restrict__ dinv,
                            float* __restrict__ h2, float* __restrict__ out, int n) {
    int t = blockIdx.x * blockDim.x + threadIdx.x;
    int v = t >> 4, j = t & 15;
    if (v >= n) return;
    float acc = 0.f;
#pragma unroll 8
    for (int d = 0; d < 64; ++d)
        acc = fmaf(hmax_f[v * 64 + d], wg[d * 16 + j], acc);
    h2[v * 16 + j] = acc;
    float dv = dinv[v];
    out[v * 16 + j] = bg[j] + dv * dv * acc;
}

__global__ void k_gcn2_scatter(const int* __restrict__ row, const int* __restrict__ col,
                               const float* __restrict__ h2, const float* __restrict__ dinv,
                               float* __restrict__ out, int E) {
    int t = blockIdx.x * blockDim.x + threadIdx.x;
    int e = t >> 2, g = t & 3;       // 4 threads/edge, 4 floats each
    if (e >= E) return;
    int r = row[e], c = col[e];
    float norm = dinv[r] * dinv[c];
    const float4* h24 = (const float4*)h2;
    float4 hv = h24[r * 4 + g];
    float* dst = out + c * 16 + g * 4;
    atomicAdd(dst + 0, norm * hv.x);
    atomicAdd(dst + 1, norm * hv.y);
    atomicAdd(dst + 2, norm * hv.z);
    atomicAdd(dst + 3, norm * hv.w);
}

extern "C" void kernel_launch(void* const* d_in, const int* in_sizes, int n_in,
                              void* d_out, int out_size, void* d_ws, size_t ws_size,
                              hipStream_t stream) {
    const float* x   = (const float*)d_in[0];
    const int*   ei  = (const int*)d_in[1];
    const float* g1w = (const float*)d_in[2];
    const float* g1b = (const float*)d_in[3];
    const float* ew1 = (const float*)d_in[4];
    const float* eb1 = (const float*)d_in[5];
    const float* ew2 = (const float*)d_in[6];
    const float* eb2 = (const float*)d_in[7];
    const float* g2w = (const float*)d_in[8];
    const float* g2b = (const float*)d_in[9];
    float* out = (float*)d_out;
    float* ws  = (float*)d_ws;

    const int n = in_sizes[0] / 32;      // 50000
    const int E = in_sizes[1] / 2;       // 800000
    const int* row = ei;
    const int* col = ei + E;

    // workspace layout (float words)
    size_t npad   = ((size_t)n + 63) & ~(size_t)63;
    size_t o_deg  = 0;
    size_t o_dinv = npad;
    size_t o_agg1 = o_dinv + npad;            // n*32 (reused for h2 later)
    size_t o_hmax = o_agg1 + (size_t)n * 32;  // n*64
    size_t o_atab = o_hmax + (size_t)n * 64;  // n*64
    size_t o_btab = o_atab + (size_t)n * 64;  // n*64
    // end = o_btab + n*64  (~45 MB)

    int*   deg  = (int*)(ws + o_deg);
    float* dinv = ws + o_dinv;
    float* agg1 = ws + o_agg1;
    float* hmax = ws + o_hmax;
    float* atab = ws + o_atab;
    float* btab = ws + o_btab;
    float* h2   = ws + o_agg1;               // overlay: agg1 dead after k_node_pre

    // zero [0, o_atab): deg + dinv + agg1 + hmax
    int n4 = (int)(o_atab / 4);
    k_zero4<<<(n4 + 255) / 256, 256, 0, stream>>>((float4*)d_ws, n4);
    k_deg<<<(E + 255) / 256, 256, 0, stream>>>(col, deg, E);
    k_dinv<<<(n + 255) / 256, 256, 0, stream>>>(deg, dinv, n);
    k_gcn1_scatter<<<(E * 8 + 255) / 256, 256, 0, stream>>>(row, col, x, dinv, agg1, E);
    k_node_pre<<<n, 64, 0, stream>>>(agg1, x, dinv, g1w, g1b, ew1, eb1, atab, btab, n);
    int nwaves = (E + 7) / 8;
    k_edge_mlp<<<(nwaves + 3) / 4, 256, 0, stream>>>(row, col, atab, btab, ew2, eb2,
                                                     (unsigned int*)hmax, E);
    k_gcn2_node<<<(n * 16 + 255) / 256, 256, 0, stream>>>(hmax, g2w, g2b, dinv, h2, out, n);
    k_gcn2_scatter<<<(E * 4 + 255) / 256, 256, 0, stream>>>(row, col, h2, dinv, out, E);
}

// Round 4
// 823.263 us; speedup vs baseline: 1.4968x; 1.4968x over previous
//
#include <hip/hip_runtime.h>

// Pipeline:
//   deg/dinv -> scatter norm*x into agg1 (GCN1 aggregate BEFORE matmul, 32 dims)
//   node_pre: h1 = tanh(agg1 @ Wg1 + b); atab/btab = h1 @ split(W1)  (EdgeConv algebra:
//             [x_i, x_j-x_i]@W1 = x_i@(W1a-W1b) + x_j@W1b)
//   edge_mlp (MFMA): u = relu(atab[c]+btab[r]); m = u@W2+b2; hmax[c] = max(hmax[c], relu(m))
//   gcn2:     h2 = hmax@Wg2; out = bg2 + dinv^2*h2 + scatter(norm*h2[row])

typedef __attribute__((ext_vector_type(8))) short short8;
typedef __attribute__((ext_vector_type(4))) float f32x4;

__device__ __forceinline__ unsigned short f2bf(float x) {   // RNE f32->bf16
    unsigned int u = __float_as_uint(x);
    return (unsigned short)((u + 0x7FFFu + ((u >> 16) & 1u)) >> 16);
}
__device__ __forceinline__ float bf2f(unsigned short h) {
    return __uint_as_float(((unsigned int)h) << 16);
}

__global__ void k_zero4(float4* p, int n4) {
    int i = blockIdx.x * blockDim.x + threadIdx.x;
    if (i < n4) p[i] = make_float4(0.f, 0.f, 0.f, 0.f);
}

__global__ void k_deg(const int* __restrict__ col, int* __restrict__ deg, int E) {
    int e = blockIdx.x * blockDim.x + threadIdx.x;
    if (e < E) atomicAdd(&deg[col[e]], 1);
}

__global__ void k_dinv(const int* __restrict__ deg, float* __restrict__ dinv, int n) {
    int v = blockIdx.x * blockDim.x + threadIdx.x;
    if (v < n) dinv[v] = rsqrtf((float)(deg[v] + 1));   // +1 self loop
}

__global__ void k_gcn1_scatter(const int* __restrict__ row, const int* __restrict__ col,
                               const float* __restrict__ x, const float* __restrict__ dinv,
                               float* __restrict__ agg1, int E) {
    int t = blockIdx.x * blockDim.x + threadIdx.x;
    int e = t >> 3, g = t & 7;       // 8 threads/edge, 4 floats each
    if (e >= E) return;
    int r = row[e], c = col[e];
    float norm = dinv[r] * dinv[c];
    const float4* x4 = (const float4*)x;
    float4 xv = x4[r * 8 + g];
    float* dst = agg1 + c * 32 + g * 4;
    atomicAdd(dst + 0, norm * xv.x);
    atomicAdd(dst + 1, norm * xv.y);
    atomicAdd(dst + 2, norm * xv.z);
    atomicAdd(dst + 3, norm * xv.w);
}

// fused GCN1-finish + EdgeConv-layer1 tables; one node per wave (64 threads)
__global__ void k_node_pre(const float* __restrict__ agg1, const float* __restrict__ x,
                           const float* __restrict__ dinv,
                           const float* __restrict__ gw, const float* __restrict__ gb,
                           const float* __restrict__ w1, const float* __restrict__ b1,
                           float* __restrict__ atab, float* __restrict__ btab, int n) {
    int v = blockIdx.x;
    int j = threadIdx.x;             // 64
    float dv = dinv[v], d2 = dv * dv;
    float acc = gb[j];
#pragma unroll
    for (int d = 0; d < 32; ++d) {
        float s = agg1[v * 32 + d] + d2 * x[v * 32 + d];
        acc = fmaf(s, gw[d * 64 + j], acc);
    }
    float hj = tanhf(acc);
    float acca = b1[j], accb = 0.f;
#pragma unroll 8
    for (int d = 0; d < 64; ++d) {
        float hd = __shfl(hj, d, 64);
        float wt = w1[d * 64 + j];
        float wb = w1[(64 + d) * 64 + j];
        acca = fmaf(hd, wt - wb, acca);
        accb = fmaf(hd, wb, accb);
    }
    atab[v * 64 + j] = acca;
    btab[v * 64 + j] = accb;
}

// MFMA edge MLP: one 16-edge tile per wave, GEMM 16x64x64 via mfma_f32_16x16x32_bf16.
// A (u) built directly in frag layout: lane(m=lane&15,q=lane>>4) holds k=8q+j (chunk0)
// and k=32+8q+j (chunk1). 3-term hi/lo split for ~fp32 accuracy.
__global__ __launch_bounds__(256) void k_edge_mlp(
        const int* __restrict__ row, const int* __restrict__ col,
        const float* __restrict__ atab, const float* __restrict__ btab,
        const float* __restrict__ w2, const float* __restrict__ b2,
        unsigned int* __restrict__ hmax, int E) {
    int lane = threadIdx.x & 63;
    int n16 = lane & 15, q = lane >> 4;

    // preload W2 B-frags (hi/lo) + bias; B[k][n]: lane holds n=lane&15, k=8q+j
    short8 bh[4][2], bl[4][2];
    float bias[4];
#pragma unroll
    for (int t = 0; t < 4; ++t) {
        bias[t] = b2[t * 16 + n16];
#pragma unroll
        for (int ck = 0; ck < 2; ++ck) {
            short8 hh, ll;
#pragma unroll
            for (int j = 0; j < 8; ++j) {
                float w = w2[(ck * 32 + q * 8 + j) * 64 + t * 16 + n16];
                unsigned short wh = f2bf(w);
                hh[j] = (short)wh;
                ll[j] = (short)f2bf(w - bf2f(wh));
            }
            bh[t][ck] = hh; bl[t][ck] = ll;
        }
    }

    int ntiles = E >> 4;             // E divisible by 16 (800000)
    int wid = blockIdx.x * 4 + (threadIdx.x >> 6);
    int wstride = gridDim.x * 4;
    for (int tile = wid; tile < ntiles; tile += wstride) {
        int e0 = tile << 4;
        int e  = e0 + n16;
        int r = row[e], c = col[e];
        const float4* a4 = (const float4*)(atab + (size_t)c * 64);
        const float4* b4 = (const float4*)(btab + (size_t)r * 64);
        float4 a0 = a4[2 * q],     a1 = a4[2 * q + 1];
        float4 a2 = a4[8 + 2 * q], a3 = a4[8 + 2 * q + 1];
        float4 c0 = b4[2 * q],     c1 = b4[2 * q + 1];
        float4 c2 = b4[8 + 2 * q], c3 = b4[8 + 2 * q + 1];
        float u[16];
        u[0]  = fmaxf(a0.x + c0.x, 0.f); u[1]  = fmaxf(a0.y + c0.y, 0.f);
        u[2]  = fmaxf(a0.z + c0.z, 0.f); u[3]  = fmaxf(a0.w + c0.w, 0.f);
        u[4]  = fmaxf(a1.x + c1.x, 0.f); u[5]  = fmaxf(a1.y + c1.y, 0.f);
        u[6]  = fmaxf(a1.z + c1.z, 0.f); u[7]  = fmaxf(a1.w + c1.w, 0.f);
        u[8]  = fmaxf(a2.x + c2.x, 0.f); u[9]  = fmaxf(a2.y + c2.y, 0.f);
        u[10] = fmaxf(a2.z + c2.z, 0.f); u[11] = fmaxf(a2.w + c2.w, 0.f);
        u[12] = fmaxf(a3.x + c3.x, 0.f); u[13] = fmaxf(a3.y + c3.y, 0.f);
        u[14] = fmaxf(a3.z + c3.z, 0.f); u[15] = fmaxf(a3.w + c3.w, 0.f);

        short8 ah0, ah1, al0, al1;
#pragma unroll
        for (int j = 0; j < 8; ++j) {
            unsigned short h0 = f2bf(u[j]);
            ah0[j] = (short)h0;
            al0[j] = (short)f2bf(u[j] - bf2f(h0));
            unsigned short h1 = f2bf(u[8 + j]);
            ah1[j] = (short)h1;
            al1[j] = (short)f2bf(u[8 + j] - bf2f(h1));
        }

        f32x4 acc[4];
#pragma unroll
        for (int t = 0; t < 4; ++t) {
            acc[t] = (f32x4){bias[t], bias[t], bias[t], bias[t]};
            acc[t] = __builtin_amdgcn_mfma_f32_16x16x32_bf16(ah0, bh[t][0], acc[t], 0, 0, 0);
            acc[t] = __builtin_amdgcn_mfma_f32_16x16x32_bf16(ah1, bh[t][1], acc[t], 0, 0, 0);
            acc[t] = __builtin_amdgcn_mfma_f32_16x16x32_bf16(al0, bh[t][0], acc[t], 0, 0, 0);
            acc[t] = __builtin_amdgcn_mfma_f32_16x16x32_bf16(al1, bh[t][1], acc[t], 0, 0, 0);
            acc[t] = __builtin_amdgcn_mfma_f32_16x16x32_bf16(ah0, bl[t][0], acc[t], 0, 0, 0);
            acc[t] = __builtin_amdgcn_mfma_f32_16x16x32_bf16(ah1, bl[t][1], acc[t], 0, 0, 0);
        }

        // C/D layout: col = lane&15 (feature n16), row = q*4 + reg (edge within tile)
        int ce[4];
#pragma unroll
        for (int i = 0; i < 4; ++i) ce[i] = col[e0 + q * 4 + i];
#pragma unroll
        for (int t = 0; t < 4; ++t)
#pragma unroll
            for (int i = 0; i < 4; ++i) {
                float mm = fmaxf(acc[t][i], 0.f);   // fold relu + empty-segment-0
                atomicMax(&hmax[(size_t)ce[i] * 64 + t * 16 + n16], __float_as_uint(mm));
            }
    }
}

// h2 = hmax @ Wg2 (64->16); out = bg2 + dinv^2 * h2  (fully initializes d_out)
__global__ void k_gcn2_node(const float* __restrict__ hmax_f,
                            const float* __restrict__ wg, const float* __restrict__ bg,
                            const float* __restrict__ dinv,
                            float* __restrict__ h2, float* __restrict__ out, int n) {
    int t = blockIdx.x * blockDim.x + threadIdx.x;
    int v = t >> 4, j = t & 15;
    if (v >= n) return;
    float acc = 0.f;
#pragma unroll 8
    for (int d = 0; d < 64; ++d)
        acc = fmaf(hmax_f[v * 64 + d], wg[d * 16 + j], acc);
    h2[v * 16 + j] = acc;
    float dv = dinv[v];
    out[v * 16 + j] = bg[j] + dv * dv * acc;
}

__global__ void k_gcn2_scatter(const int* __restrict__ row, const int* __restrict__ col,
                               const float* __restrict__ h2, const float* __restrict__ dinv,
                               float* __restrict__ out, int E) {
    int t = blockIdx.x * blockDim.x + threadIdx.x;
    int e = t >> 2, g = t & 3;       // 4 threads/edge, 4 floats each
    if (e >= E) return;
    int r = row[e], c = col[e];
    float norm = dinv[r] * dinv[c];
    const float4* h24 = (const float4*)h2;
    float4 hv = h24[r * 4 + g];
    float* dst = out + c * 16 + g * 4;
    atomicAdd(dst + 0, norm * hv.x);
    atomicAdd(dst + 1, norm * hv.y);
    atomicAdd(dst + 2, norm * hv.z);
    atomicAdd(dst + 3, norm * hv.w);
}

extern "C" void kernel_launch(void* const* d_in, const int* in_sizes, int n_in,
                              void* d_out, int out_size, void* d_ws, size_t ws_size,
                              hipStream_t stream) {
    const float* x   = (const float*)d_in[0];
    const int*   ei  = (const int*)d_in[1];
    const float* g1w = (const float*)d_in[2];
    const float* g1b = (const float*)d_in[3];
    const float* ew1 = (const float*)d_in[4];
    const float* eb1 = (const float*)d_in[5];
    const float* ew2 = (const float*)d_in[6];
    const float* eb2 = (const float*)d_in[7];
    const float* g2w = (const float*)d_in[8];
    const float* g2b = (const float*)d_in[9];
    float* out = (float*)d_out;
    float* ws  = (float*)d_ws;

    const int n = in_sizes[0] / 32;      // 50000
    const int E = in_sizes[1] / 2;       // 800000
    const int* row = ei;
    const int* col = ei + E;

    size_t npad   = ((size_t)n + 63) & ~(size_t)63;
    size_t o_deg  = 0;
    size_t o_dinv = npad;
    size_t o_agg1 = o_dinv + npad;            // n*32 (reused for h2 later)
    size_t o_hmax = o_agg1 + (size_t)n * 32;  // n*64
    size_t o_atab = o_hmax + (size_t)n * 64;  // n*64
    size_t o_btab = o_atab + (size_t)n * 64;  // n*64

    int*   deg  = (int*)(ws + o_deg);
    float* dinv = ws + o_dinv;
    float* agg1 = ws + o_agg1;
    float* hmax = ws + o_hmax;
    float* atab = ws + o_atab;
    float* btab = ws + o_btab;
    float* h2   = ws + o_agg1;               // overlay: agg1 dead after k_node_pre

    int n4 = (int)(o_atab / 4);
    k_zero4<<<(n4 + 255) / 256, 256, 0, stream>>>((float4*)d_ws, n4);
    k_deg<<<(E + 255) / 256, 256, 0, stream>>>(col, deg, E);
    k_dinv<<<(n + 255) / 256, 256, 0, stream>>>(deg, dinv, n);
    k_gcn1_scatter<<<(E * 8 + 255) / 256, 256, 0, stream>>>(row, col, x, dinv, agg1, E);
    k_node_pre<<<n, 64, 0, stream>>>(agg1, x, dinv, g1w, g1b, ew1, eb1, atab, btab, n);
    k_edge_mlp<<<4096, 256, 0, stream>>>(row, col, atab, btab, ew2, eb2,
                                         (unsigned int*)hmax, E);
    k_gcn2_node<<<(n * 16 + 255) / 256, 256, 0, stream>>>(hmax, g2w, g2b, dinv, h2, out, n);
    k_gcn2_scatter<<<(E * 4 + 255) / 256, 256, 0, stream>>>(row, col, h2, dinv, out, E);
}

// Round 5
// 502.654 us; speedup vs baseline: 2.4515x; 1.6378x over previous
//
#include <hip/hip_runtime.h>

// CSR-gather pipeline (no float atomics):
//   deg -> scan(ptr) -> fill csr_row (edges sorted by col)
//   node_pre (wave/node): gather agg = sum dinv[r]*x[r]; h1 = tanh((dv*agg + dv^2*x)@Wg1 + b);
//                         atab = h1@(W1a-W1b)+b1 ; btab = h1@W1b
//   edge_mlp (wave/node, MFMA 16x64x64 tiles): u = relu(atab[c]+btab[r]); m = u@W2+b2;
//                         hmax[c] = max over edges (in regs), relu+empty folded via init 0
//   gcn2: h2 = hmax@Wg2 ; out[c] = bg + dv*(dv*h2[c] + gather sum dinv[r]*h2[r])

typedef __attribute__((ext_vector_type(8))) short short8;
typedef __attribute__((ext_vector_type(4))) float f32x4;

__device__ __forceinline__ unsigned short f2bf(float x) {   // RNE f32->bf16
    unsigned int u = __float_as_uint(x);
    return (unsigned short)((u + 0x7FFFu + ((u >> 16) & 1u)) >> 16);
}
__device__ __forceinline__ float bf2f(unsigned short h) {
    return __uint_as_float(((unsigned int)h) << 16);
}

__global__ void k_zero4(float4* p, int n4) {
    int i = blockIdx.x * blockDim.x + threadIdx.x;
    if (i < n4) p[i] = make_float4(0.f, 0.f, 0.f, 0.f);
}

__global__ void k_deg(const int* __restrict__ col, int* __restrict__ deg, int E) {
    int e = blockIdx.x * blockDim.x + threadIdx.x;
    if (e < E) atomicAdd(&deg[col[e]], 1);
}

__global__ void k_dinv(const int* __restrict__ deg, float* __restrict__ dinv, int n) {
    int v = blockIdx.x * blockDim.x + threadIdx.x;
    if (v < n) dinv[v] = rsqrtf((float)(deg[v] + 1));   // +1 self loop
}

// single-block exclusive scan of deg -> ptr (n+1 entries) and cursor copy
__global__ __launch_bounds__(1024) void k_scan(const int* __restrict__ deg,
                                               int* __restrict__ ptr, int* __restrict__ cursor,
                                               int n, int E) {
    const int CH = 50;               // 1024*50 = 51200 >= n
    __shared__ int ssum[1024];
    int tid = threadIdx.x;
    int base = tid * CH;
    int s = 0;
    for (int i = 0; i < CH; ++i) { int idx = base + i; if (idx < n) s += deg[idx]; }
    ssum[tid] = s;
    __syncthreads();
    for (int off = 1; off < 1024; off <<= 1) {
        int v = ssum[tid];
        int u = (tid >= off) ? ssum[tid - off] : 0;
        __syncthreads();
        ssum[tid] = v + u;
        __syncthreads();
    }
    int run = (tid > 0) ? ssum[tid - 1] : 0;
    for (int i = 0; i < CH; ++i) {
        int idx = base + i;
        if (idx < n) {
            ptr[idx] = run; cursor[idx] = run;
            run += deg[idx];
        }
    }
    if (tid == 0) ptr[n] = E;
}

__global__ void k_fill(const int* __restrict__ row, const int* __restrict__ col,
                       int* __restrict__ cursor, int* __restrict__ csr_row, int E) {
    int e = blockIdx.x * blockDim.x + threadIdx.x;
    if (e >= E) return;
    int pos = atomicAdd(&cursor[col[e]], 1);
    csr_row[pos] = row[e];
}

// one wave per node: gather + GCN1 matmul + tanh + EdgeConv layer-1 tables
__global__ __launch_bounds__(256) void k_node_pre(
        const int* __restrict__ ptr, const int* __restrict__ csr_row,
        const float* __restrict__ x, const float* __restrict__ dinv,
        const float* __restrict__ gw, const float* __restrict__ gb,
        const float* __restrict__ w1, const float* __restrict__ b1,
        float* __restrict__ atab, float* __restrict__ btab, int n) {
    int wid = blockIdx.x * 4 + (threadIdx.x >> 6);
    if (wid >= n) return;
    int lane = threadIdx.x & 63;
    int f = lane & 31, half = lane >> 5;
    int v = wid;
    int start = ptr[v], end = ptr[v + 1];
    float s = 0.f;
    for (int p = start + half; p < end; p += 2) {
        int r = csr_row[p];
        s += dinv[r] * x[r * 32 + f];
    }
    s += __shfl_xor(s, 32);
    float dv = dinv[v];
    float sf = dv * s + dv * dv * x[v * 32 + f];   // GCN1 pre-activation input, feature f
    float acc = gb[lane];
#pragma unroll
    for (int d = 0; d < 32; ++d) {
        float sd = __shfl(sf, d, 64);
        acc = fmaf(sd, gw[d * 64 + lane], acc);
    }
    float hj = tanhf(acc);
    float acca = b1[lane], accb = 0.f;
#pragma unroll 8
    for (int d = 0; d < 64; ++d) {
        float hd = __shfl(hj, d, 64);
        float wt = w1[d * 64 + lane];
        float wb = w1[(64 + d) * 64 + lane];
        acca = fmaf(hd, wt - wb, acca);
        accb = fmaf(hd, wb, accb);
    }
    atab[v * 64 + lane] = acca;
    btab[v * 64 + lane] = accb;
}

// one wave per node; MFMA 16-edge tiles; segment max in registers; no atomics
__global__ __launch_bounds__(256) void k_edge_mlp(
        const int* __restrict__ ptr, const int* __restrict__ csr_row,
        const float* __restrict__ atab, const float* __restrict__ btab,
        const float* __restrict__ w2, const float* __restrict__ b2,
        float* __restrict__ hmax, int n) {
    int lane = threadIdx.x & 63;
    int n16 = lane & 15, q = lane >> 4;

    int wid = blockIdx.x * 4 + (threadIdx.x >> 6);
    if (wid >= n) return;

    // preload W2 B-frags (hi/lo) + bias; B[k][nn]: lane holds nn=n16, k=ck*32+8q+j
    short8 bh[4][2], bl[4][2];
    float bias[4];
#pragma unroll
    for (int t = 0; t < 4; ++t) {
        bias[t] = b2[t * 16 + n16];
#pragma unroll
        for (int ck = 0; ck < 2; ++ck) {
            short8 hh, ll;
#pragma unroll
            for (int j = 0; j < 8; ++j) {
                float w = w2[(ck * 32 + q * 8 + j) * 64 + t * 16 + n16];
                unsigned short wh = f2bf(w);
                hh[j] = (short)wh;
                ll[j] = (short)f2bf(w - bf2f(wh));
            }
            bh[t][ck] = hh; bl[t][ck] = ll;
        }
    }

    int c = wid;
    int start = ptr[c], end = ptr[c + 1];
    const float4* at4 = (const float4*)(atab + (size_t)c * 64);
    float4 A0 = at4[2 * q], A1 = at4[2 * q + 1];
    float4 A2 = at4[8 + 2 * q], A3 = at4[8 + 2 * q + 1];
    float ak[16] = {A0.x, A0.y, A0.z, A0.w, A1.x, A1.y, A1.z, A1.w,
                    A2.x, A2.y, A2.z, A2.w, A3.x, A3.y, A3.z, A3.w};

    float red[4] = {0.f, 0.f, 0.f, 0.f};   // init 0 folds relu + empty-segment-0

    for (int p0 = start; p0 < end; p0 += 16) {
        int kt = end - p0;                  // valid rows this tile (may exceed 16)
        int p = p0 + n16;
        float u[16];
        if (p < end) {
            int r = csr_row[p];
            const float4* bt4 = (const float4*)(btab + (size_t)r * 64);
            float4 B0 = bt4[2 * q], B1 = bt4[2 * q + 1];
            float4 B2 = bt4[8 + 2 * q], B3 = bt4[8 + 2 * q + 1];
            float bk[16] = {B0.x, B0.y, B0.z, B0.w, B1.x, B1.y, B1.z, B1.w,
                            B2.x, B2.y, B2.z, B2.w, B3.x, B3.y, B3.z, B3.w};
#pragma unroll
            for (int j = 0; j < 16; ++j) u[j] = fmaxf(ak[j] + bk[j], 0.f);
        } else {
#pragma unroll
            for (int j = 0; j < 16; ++j) u[j] = 0.f;
        }

        short8 ah0, ah1, al0, al1;
#pragma unroll
        for (int j = 0; j < 8; ++j) {
            unsigned short h0 = f2bf(u[j]);
            ah0[j] = (short)h0;
            al0[j] = (short)f2bf(u[j] - bf2f(h0));
            unsigned short h1 = f2bf(u[8 + j]);
            ah1[j] = (short)h1;
            al1[j] = (short)f2bf(u[8 + j] - bf2f(h1));
        }

#pragma unroll
        for (int t = 0; t < 4; ++t) {
            f32x4 acc = (f32x4){bias[t], bias[t], bias[t], bias[t]};
            acc = __builtin_amdgcn_mfma_f32_16x16x32_bf16(ah0, bh[t][0], acc, 0, 0, 0);
            acc = __builtin_amdgcn_mfma_f32_16x16x32_bf16(ah1, bh[t][1], acc, 0, 0, 0);
            acc = __builtin_amdgcn_mfma_f32_16x16x32_bf16(al0, bh[t][0], acc, 0, 0, 0);
            acc = __builtin_amdgcn_mfma_f32_16x16x32_bf16(al1, bh[t][1], acc, 0, 0, 0);
            acc = __builtin_amdgcn_mfma_f32_16x16x32_bf16(ah0, bl[t][0], acc, 0, 0, 0);
            acc = __builtin_amdgcn_mfma_f32_16x16x32_bf16(ah1, bl[t][1], acc, 0, 0, 0);
            // rows: q*4+i; mask rows beyond kt
#pragma unroll
            for (int i = 0; i < 4; ++i) {
                if (q * 4 + i < kt) red[t] = fmaxf(red[t], acc[i]);
            }
        }
    }
#pragma unroll
    for (int t = 0; t < 4; ++t) {
        red[t] = fmaxf(red[t], __shfl_xor(red[t], 16));
        red[t] = fmaxf(red[t], __shfl_xor(red[t], 32));
    }
    if (q == 0) {
#pragma unroll
        for (int t = 0; t < 4; ++t)
            hmax[(size_t)c * 64 + t * 16 + n16] = red[t];
    }
}

// h2 = hmax @ Wg2 (64->16)
__global__ void k_gcn2_node(const float* __restrict__ hmax,
                            const float* __restrict__ wg,
                            float* __restrict__ h2, int n) {
    int t = blockIdx.x * blockDim.x + threadIdx.x;
    int v = t >> 4, j = t & 15;
    if (v >= n) return;
    float acc = 0.f;
#pragma unroll 8
    for (int d = 0; d < 64; ++d)
        acc = fmaf(hmax[v * 64 + d], wg[d * 16 + j], acc);
    h2[v * 16 + j] = acc;
}

// out[c] = bg + dv*(dv*h2[c] + sum_in dinv[r]*h2[r]) ; fully writes d_out
__global__ __launch_bounds__(256) void k_gcn2_gather(
        const int* __restrict__ ptr, const int* __restrict__ csr_row,
        const float* __restrict__ h2, const float* __restrict__ dinv,
        const float* __restrict__ bg, float* __restrict__ out, int n) {
    int wid = blockIdx.x * 4 + (threadIdx.x >> 6);
    if (wid >= n) return;
    int lane = threadIdx.x & 63;
    int f = lane & 15, es = lane >> 4;
    int c = wid;
    int start = ptr[c], end = ptr[c + 1];
    float s = 0.f;
    for (int p = start + es; p < end; p += 4) {
        int r = csr_row[p];
        s += dinv[r] * h2[r * 16 + f];
    }
    s += __shfl_xor(s, 16);
    s += __shfl_xor(s, 32);
    if (es == 0) {
        float dv = dinv[c];
        out[c * 16 + f] = bg[f] + dv * (dv * h2[c * 16 + f] + s);
    }
}

extern "C" void kernel_launch(void* const* d_in, const int* in_sizes, int n_in,
                              void* d_out, int out_size, void* d_ws, size_t ws_size,
                              hipStream_t stream) {
    const float* x   = (const float*)d_in[0];
    const int*   ei  = (const int*)d_in[1];
    const float* g1w = (const float*)d_in[2];
    const float* g1b = (const float*)d_in[3];
    const float* ew1 = (const float*)d_in[4];
    const float* eb1 = (const float*)d_in[5];
    const float* ew2 = (const float*)d_in[6];
    const float* eb2 = (const float*)d_in[7];
    const float* g2w = (const float*)d_in[8];
    const float* g2b = (const float*)d_in[9];
    float* out = (float*)d_out;
    float* ws  = (float*)d_ws;

    const int n = in_sizes[0] / 32;      // 50000
    const int E = in_sizes[1] / 2;       // 800000
    const int* row = ei;
    const int* col = ei + E;

    size_t npad    = ((size_t)n + 63) & ~(size_t)63;
    size_t o_deg   = 0;
    size_t o_ptr   = npad;               // n+1 (+pad)
    size_t o_cur   = o_ptr + npad + 64;
    size_t o_csr   = o_cur + npad;       // E ints
    size_t o_dinv  = o_csr + (size_t)E;
    size_t o_hmax  = o_dinv + npad;      // n*64
    size_t o_atab  = o_hmax + (size_t)n * 64;
    size_t o_btab  = o_atab + (size_t)n * 64;
    size_t o_h2    = o_btab + (size_t)n * 64;   // n*16
    // total ~ (4*npad + E + n*208)*4B  ~= 46 MB

    int*   deg    = (int*)(ws + o_deg);
    int*   ptr    = (int*)(ws + o_ptr);
    int*   cursor = (int*)(ws + o_cur);
    int*   csr    = (int*)(ws + o_csr);
    float* dinv   = ws + o_dinv;
    float* hmax   = ws + o_hmax;
    float* atab   = ws + o_atab;
    float* btab   = ws + o_btab;
    float* h2     = ws + o_h2;

    int nblk = (n + 3) / 4;   // wave-per-node kernels, 4 waves/block

    k_zero4<<<(int)((npad / 4 + 255) / 256), 256, 0, stream>>>((float4*)deg, (int)(npad / 4));
    k_deg<<<(E + 255) / 256, 256, 0, stream>>>(col, deg, E);
    k_dinv<<<(n + 255) / 256, 256, 0, stream>>>(deg, dinv, n);
    k_scan<<<1, 1024, 0, stream>>>(deg, ptr, cursor, n, E);
    k_fill<<<(E + 255) / 256, 256, 0, stream>>>(row, col, cursor, csr, E);
    k_node_pre<<<nblk, 256, 0, stream>>>(ptr, csr, x, dinv, g1w, g1b, ew1, eb1, atab, btab, n);
    k_edge_mlp<<<nblk, 256, 0, stream>>>(ptr, csr, atab, btab, ew2, eb2, hmax, n);
    k_gcn2_node<<<(n * 16 + 255) / 256, 256, 0, stream>>>(hmax, g2w, h2, n);
    k_gcn2_gather<<<nblk, 256, 0, stream>>>(ptr, csr, h2, dinv, g2b, out, n);
}

// Round 6
// 405.993 us; speedup vs baseline: 3.0352x; 1.2381x over previous
//
#include <hip/hip_runtime.h>

// CSR-gather pipeline (no float atomics):
//   deg -> multi-block scan(ptr) -> fill csr_row (edges sorted by col)
//   node_pre (wave/node): gather agg = sum dinv[r]*x[r]; h1 = tanh((dv*agg + dv^2*x)@Wg1 + b);
//                         atab = h1@(W1a-W1b)+b1 ; btab = h1@W1b
//   edge_mlp (wave/node, MFMA 16x64x64 tiles): u = relu(atab[c]+btab[r]); m = u@W2+b2;
//                         hmax[c] = max over edges (in regs), relu+empty folded via init 0
//   gcn2: h2 = hmax@Wg2 ; out[c] = bg + dv*(dv*h2[c] + gather sum dinv[r]*h2[r])

typedef __attribute__((ext_vector_type(8))) short short8;
typedef __attribute__((ext_vector_type(4))) float f32x4;

#define SCAN_CHUNK 2048   // elements per scan block (256 thr x 8)

__device__ __forceinline__ unsigned short f2bf(float x) {   // RNE f32->bf16
    unsigned int u = __float_as_uint(x);
    return (unsigned short)((u + 0x7FFFu + ((u >> 16) & 1u)) >> 16);
}
__device__ __forceinline__ float bf2f(unsigned short h) {
    return __uint_as_float(((unsigned int)h) << 16);
}

__global__ void k_zero4(float4* p, int n4) {
    int i = blockIdx.x * blockDim.x + threadIdx.x;
    if (i < n4) p[i] = make_float4(0.f, 0.f, 0.f, 0.f);
}

__global__ void k_deg(const int* __restrict__ col, int* __restrict__ deg, int E) {
    int e = blockIdx.x * blockDim.x + threadIdx.x;
    if (e < E) atomicAdd(&deg[col[e]], 1);
}

__global__ void k_dinv(const int* __restrict__ deg, float* __restrict__ dinv, int n) {
    int v = blockIdx.x * blockDim.x + threadIdx.x;
    if (v < n) dinv[v] = rsqrtf((float)(deg[v] + 1));   // +1 self loop
}

// phase 1: per-block sum of deg over SCAN_CHUNK elements
__global__ __launch_bounds__(256) void k_scan_partial(const int* __restrict__ deg,
                                                      int* __restrict__ part, int n) {
    __shared__ int wtot[4];
    int tid = threadIdx.x;
    int base = blockIdx.x * SCAN_CHUNK + tid * 8;
    int s = 0;
#pragma unroll
    for (int i = 0; i < 8; ++i) { int idx = base + i; if (idx < n) s += deg[idx]; }
    for (int off = 1; off < 64; off <<= 1) s += __shfl_xor(s, off);
    if ((tid & 63) == 0) wtot[tid >> 6] = s;
    __syncthreads();
    if (tid == 0) part[blockIdx.x] = wtot[0] + wtot[1] + wtot[2] + wtot[3];
}

// phase 2: one wave exclusive-scans <=64 partials
__global__ __launch_bounds__(64) void k_scan_offsets(const int* __restrict__ part,
                                                     int* __restrict__ offs,
                                                     int* __restrict__ ptr, int nb, int n, int E) {
    int lane = threadIdx.x;
    int p = (lane < nb) ? part[lane] : 0;
    int s = p;
    for (int off = 1; off < 64; off <<= 1) {
        int t = __shfl_up(s, off, 64);
        if (lane >= off) s += t;
    }
    if (lane < nb) offs[lane] = s - p;     // exclusive
    if (lane == 0) ptr[n] = E;
}

// phase 3: block-local exclusive scan + global offset -> ptr, cursor
__global__ __launch_bounds__(256) void k_scan_final(const int* __restrict__ deg,
                                                    const int* __restrict__ offs,
                                                    int* __restrict__ ptr, int* __restrict__ cursor,
                                                    int n) {
    __shared__ int wtot[4];
    int tid = threadIdx.x;
    int lane = tid & 63, wv = tid >> 6;
    int base = blockIdx.x * SCAN_CHUNK + tid * 8;
    int d[8];
    int t8 = 0;
#pragma unroll
    for (int i = 0; i < 8; ++i) {
        int idx = base + i;
        d[i] = (idx < n) ? deg[idx] : 0;
        t8 += d[i];
    }
    // wave inclusive scan of per-thread totals
    int s = t8;
    for (int off = 1; off < 64; off <<= 1) {
        int t = __shfl_up(s, off, 64);
        if (lane >= off) s += t;
    }
    if (lane == 63) wtot[wv] = s;
    __syncthreads();
    int wpre = 0;
    for (int w = 0; w < 4; ++w) if (w < wv) wpre += wtot[w];
    int run = offs[blockIdx.x] + wpre + (s - t8);
#pragma unroll
    for (int i = 0; i < 8; ++i) {
        int idx = base + i;
        if (idx < n) { ptr[idx] = run; cursor[idx] = run; run += d[i]; }
    }
}

__global__ void k_fill(const int* __restrict__ row, const int* __restrict__ col,
                       int* __restrict__ cursor, int* __restrict__ csr_row, int E) {
    int e = blockIdx.x * blockDim.x + threadIdx.x;
    if (e >= E) return;
    int pos = atomicAdd(&cursor[col[e]], 1);
    csr_row[pos] = row[e];
}

// one wave per node: gather + GCN1 matmul + tanh + EdgeConv layer-1 tables
__global__ __launch_bounds__(256) void k_node_pre(
        const int* __restrict__ ptr, const int* __restrict__ csr_row,
        const float* __restrict__ x, const float* __restrict__ dinv,
        const float* __restrict__ gw, const float* __restrict__ gb,
        const float* __restrict__ w1, const float* __restrict__ b1,
        float* __restrict__ atab, float* __restrict__ btab, int n) {
    int wid = blockIdx.x * 4 + (threadIdx.x >> 6);
    if (wid >= n) return;
    int lane = threadIdx.x & 63;
    int f = lane & 31, half = lane >> 5;
    int v = wid;
    int start = ptr[v], end = ptr[v + 1];
    float s = 0.f;
    for (int p = start + half; p < end; p += 2) {
        int r = csr_row[p];
        s += dinv[r] * x[r * 32 + f];
    }
    s += __shfl_xor(s, 32);
    float dv = dinv[v];
    float sf = dv * s + dv * dv * x[v * 32 + f];   // GCN1 pre-activation input, feature f
    float acc = gb[lane];
#pragma unroll
    for (int d = 0; d < 32; ++d) {
        float sd = __shfl(sf, d, 64);
        acc = fmaf(sd, gw[d * 64 + lane], acc);
    }
    float hj = tanhf(acc);
    float acca = b1[lane], accb = 0.f;
#pragma unroll 8
    for (int d = 0; d < 64; ++d) {
        float hd = __shfl(hj, d, 64);
        float wt = w1[d * 64 + lane];
        float wb = w1[(64 + d) * 64 + lane];
        acca = fmaf(hd, wt - wb, acca);
        accb = fmaf(hd, wb, accb);
    }
    atab[v * 64 + lane] = acca;
    btab[v * 64 + lane] = accb;
}

// one wave per node; MFMA 16-edge tiles; segment max in registers; no atomics
__global__ __launch_bounds__(256) void k_edge_mlp(
        const int* __restrict__ ptr, const int* __restrict__ csr_row,
        const float* __restrict__ atab, const float* __restrict__ btab,
        const float* __restrict__ w2, const float* __restrict__ b2,
        float* __restrict__ hmax, int n) {
    int lane = threadIdx.x & 63;
    int n16 = lane & 15, q = lane >> 4;

    int wid = blockIdx.x * 4 + (threadIdx.x >> 6);
    if (wid >= n) return;

    // preload W2 B-frags (hi/lo) + bias; B[k][nn]: lane holds nn=n16, k=ck*32+8q+j
    short8 bh[4][2], bl[4][2];
    float bias[4];
#pragma unroll
    for (int t = 0; t < 4; ++t) {
        bias[t] = b2[t * 16 + n16];
#pragma unroll
        for (int ck = 0; ck < 2; ++ck) {
            short8 hh, ll;
#pragma unroll
            for (int j = 0; j < 8; ++j) {
                float w = w2[(ck * 32 + q * 8 + j) * 64 + t * 16 + n16];
                unsigned short wh = f2bf(w);
                hh[j] = (short)wh;
                ll[j] = (short)f2bf(w - bf2f(wh));
            }
            bh[t][ck] = hh; bl[t][ck] = ll;
        }
    }

    int c = wid;
    int start = ptr[c], end = ptr[c + 1];
    const float4* at4 = (const float4*)(atab + (size_t)c * 64);
    float4 A0 = at4[2 * q], A1 = at4[2 * q + 1];
    float4 A2 = at4[8 + 2 * q], A3 = at4[8 + 2 * q + 1];
    float ak[16] = {A0.x, A0.y, A0.z, A0.w, A1.x, A1.y, A1.z, A1.w,
                    A2.x, A2.y, A2.z, A2.w, A3.x, A3.y, A3.z, A3.w};

    float red[4] = {0.f, 0.f, 0.f, 0.f};   // init 0 folds relu + empty-segment-0

    for (int p0 = start; p0 < end; p0 += 16) {
        int kt = end - p0;                  // valid rows this tile (may exceed 16)
        int p = p0 + n16;
        float u[16];
        if (p < end) {
            int r = csr_row[p];
            const float4* bt4 = (const float4*)(btab + (size_t)r * 64);
            float4 B0 = bt4[2 * q], B1 = bt4[2 * q + 1];
            float4 B2 = bt4[8 + 2 * q], B3 = bt4[8 + 2 * q + 1];
            float bk[16] = {B0.x, B0.y, B0.z, B0.w, B1.x, B1.y, B1.z, B1.w,
                            B2.x, B2.y, B2.z, B2.w, B3.x, B3.y, B3.z, B3.w};
#pragma unroll
            for (int j = 0; j < 16; ++j) u[j] = fmaxf(ak[j] + bk[j], 0.f);
        } else {
#pragma unroll
            for (int j = 0; j < 16; ++j) u[j] = 0.f;
        }

        short8 ah0, ah1, al0, al1;
#pragma unroll
        for (int j = 0; j < 8; ++j) {
            unsigned short h0 = f2bf(u[j]);
            ah0[j] = (short)h0;
            al0[j] = (short)f2bf(u[j] - bf2f(h0));
            unsigned short h1 = f2bf(u[8 + j]);
            ah1[j] = (short)h1;
            al1[j] = (short)f2bf(u[8 + j] - bf2f(h1));
        }

#pragma unroll
        for (int t = 0; t < 4; ++t) {
            f32x4 acc = (f32x4){bias[t], bias[t], bias[t], bias[t]};
            acc = __builtin_amdgcn_mfma_f32_16x16x32_bf16(ah0, bh[t][0], acc, 0, 0, 0);
            acc = __builtin_amdgcn_mfma_f32_16x16x32_bf16(ah1, bh[t][1], acc, 0, 0, 0);
            acc = __builtin_amdgcn_mfma_f32_16x16x32_bf16(al0, bh[t][0], acc, 0, 0, 0);
            acc = __builtin_amdgcn_mfma_f32_16x16x32_bf16(al1, bh[t][1], acc, 0, 0, 0);
            acc = __builtin_amdgcn_mfma_f32_16x16x32_bf16(ah0, bl[t][0], acc, 0, 0, 0);
            acc = __builtin_amdgcn_mfma_f32_16x16x32_bf16(ah1, bl[t][1], acc, 0, 0, 0);
            // rows: q*4+i; mask rows beyond kt
#pragma unroll
            for (int i = 0; i < 4; ++i) {
                if (q * 4 + i < kt) red[t] = fmaxf(red[t], acc[i]);
            }
        }
    }
#pragma unroll
    for (int t = 0; t < 4; ++t) {
        red[t] = fmaxf(red[t], __shfl_xor(red[t], 16));
        red[t] = fmaxf(red[t], __shfl_xor(red[t], 32));
    }
    if (q == 0) {
#pragma unroll
        for (int t = 0; t < 4; ++t)
            hmax[(size_t)c * 64 + t * 16 + n16] = red[t];
    }
}

// h2 = hmax @ Wg2 (64->16)
__global__ void k_gcn2_node(const float* __restrict__ hmax,
                            const float* __restrict__ wg,
                            float* __restrict__ h2, int n) {
    int t = blockIdx.x * blockDim.x + threadIdx.x;
    int v = t >> 4, j = t & 15;
    if (v >= n) return;
    float acc = 0.f;
#pragma unroll 8
    for (int d = 0; d < 64; ++d)
        acc = fmaf(hmax[v * 64 + d], wg[d * 16 + j], acc);
    h2[v * 16 + j] = acc;
}

// out[c] = bg + dv*(dv*h2[c] + sum_in dinv[r]*h2[r]) ; fully writes d_out
__global__ __launch_bounds__(256) void k_gcn2_gather(
        const int* __restrict__ ptr, const int* __restrict__ csr_row,
        const float* __restrict__ h2, const float* __restrict__ dinv,
        const float* __restrict__ bg, float* __restrict__ out, int n) {
    int wid = blockIdx.x * 4 + (threadIdx.x >> 6);
    if (wid >= n) return;
    int lane = threadIdx.x & 63;
    int f = lane & 15, es = lane >> 4;
    int c = wid;
    int start = ptr[c], end = ptr[c + 1];
    float s = 0.f;
    for (int p = start + es; p < end; p += 4) {
        int r = csr_row[p];
        s += dinv[r] * h2[r * 16 + f];
    }
    s += __shfl_xor(s, 16);
    s += __shfl_xor(s, 32);
    if (es == 0) {
        float dv = dinv[c];
        out[c * 16 + f] = bg[f] + dv * (dv * h2[c * 16 + f] + s);
    }
}

extern "C" void kernel_launch(void* const* d_in, const int* in_sizes, int n_in,
                              void* d_out, int out_size, void* d_ws, size_t ws_size,
                              hipStream_t stream) {
    const float* x   = (const float*)d_in[0];
    const int*   ei  = (const int*)d_in[1];
    const float* g1w = (const float*)d_in[2];
    const float* g1b = (const float*)d_in[3];
    const float* ew1 = (const float*)d_in[4];
    const float* eb1 = (const float*)d_in[5];
    const float* ew2 = (const float*)d_in[6];
    const float* eb2 = (const float*)d_in[7];
    const float* g2w = (const float*)d_in[8];
    const float* g2b = (const float*)d_in[9];
    float* out = (float*)d_out;
    float* ws  = (float*)d_ws;

    const int n = in_sizes[0] / 32;      // 50000
    const int E = in_sizes[1] / 2;       // 800000
    const int* row = ei;
    const int* col = ei + E;

    size_t npad    = ((size_t)n + 63) & ~(size_t)63;
    size_t o_deg   = 0;
    size_t o_ptr   = npad;               // n+1 (+pad)
    size_t o_cur   = o_ptr + npad + 64;
    size_t o_csr   = o_cur + npad;       // E ints
    size_t o_dinv  = o_csr + (size_t)E;
    size_t o_hmax  = o_dinv + npad;      // n*64
    size_t o_atab  = o_hmax + (size_t)n * 64;
    size_t o_btab  = o_atab + (size_t)n * 64;
    size_t o_h2    = o_btab + (size_t)n * 64;   // n*16
    size_t o_part  = o_h2 + (size_t)n * 16;     // 64 ints
    size_t o_offs  = o_part + 64;               // 64 ints

    int*   deg    = (int*)(ws + o_deg);
    int*   ptr    = (int*)(ws + o_ptr);
    int*   cursor = (int*)(ws + o_cur);
    int*   csr    = (int*)(ws + o_csr);
    float* dinv   = ws + o_dinv;
    float* hmax   = ws + o_hmax;
    float* atab   = ws + o_atab;
    float* btab   = ws + o_btab;
    float* h2     = ws + o_h2;
    int*   part   = (int*)(ws + o_part);
    int*   offs   = (int*)(ws + o_offs);

    int nblk = (n + 3) / 4;                      // wave-per-node kernels, 4 waves/block
    int scan_nb = (n + SCAN_CHUNK - 1) / SCAN_CHUNK;   // 25 <= 64

    k_zero4<<<(int)((npad / 4 + 255) / 256), 256, 0, stream>>>((float4*)deg, (int)(npad / 4));
    k_deg<<<(E + 255) / 256, 256, 0, stream>>>(col, deg, E);
    k_dinv<<<(n + 255) / 256, 256, 0, stream>>>(deg, dinv, n);
    k_scan_partial<<<scan_nb, 256, 0, stream>>>(deg, part, n);
    k_scan_offsets<<<1, 64, 0, stream>>>(part, offs, ptr, scan_nb, n, E);
    k_scan_final<<<scan_nb, 256, 0, stream>>>(deg, offs, ptr, cursor, n);
    k_fill<<<(E + 255) / 256, 256, 0, stream>>>(row, col, cursor, csr, E);
    k_node_pre<<<nblk, 256, 0, stream>>>(ptr, csr, x, dinv, g1w, g1b, ew1, eb1, atab, btab, n);
    k_edge_mlp<<<nblk, 256, 0, stream>>>(ptr, csr, atab, btab, ew2, eb2, hmax, n);
    k_gcn2_node<<<(n * 16 + 255) / 256, 256, 0, stream>>>(hmax, g2w, h2, n);
    k_gcn2_gather<<<nblk, 256, 0, stream>>>(ptr, csr, h2, dinv, g2b, out, n);
}

// Round 7
// 375.146 us; speedup vs baseline: 3.2848x; 1.0822x over previous
//
#include <hip/hip_runtime.h>

// CSR-gather pipeline (no float atomics):
//   deg -> multi-block scan(ptr) -> fill csr_row (edges sorted by col)
//   node_pre (wave/node): gather agg = sum dinv[r]*x[r]; h1 = tanh((dv*agg + dv^2*x)@Wg1 + b);
//                         atab = h1@(W1a-W1b)+b1 ; btab = h1@W1b
//   edge_mlp (persistent waves, MFMA 16x64x64 tiles): u = relu(atab[c]+btab[r]); m = u@W2+b2;
//                         hmax[c] = max over edges (in regs), relu+empty folded via init 0
//   gcn2: h2 = hmax@Wg2 ; out[c] = bg + dv*(dv*h2[c] + gather sum dinv[r]*h2[r])

typedef __attribute__((ext_vector_type(8))) short short8;
typedef __attribute__((ext_vector_type(4))) float f32x4;

#define SCAN_CHUNK 2048   // elements per scan block (256 thr x 8)

__device__ __forceinline__ unsigned short f2bf(float x) {   // RNE f32->bf16 (cold paths only)
    unsigned int u = __float_as_uint(x);
    return (unsigned short)((u + 0x7FFFu + ((u >> 16) & 1u)) >> 16);
}
__device__ __forceinline__ float bf2f(unsigned short h) {
    return __uint_as_float(((unsigned int)h) << 16);
}
// cheap truncation split: u ~= hi + lo with |err| ~ 2^-16 |u|
__device__ __forceinline__ void splitT(float u, short& hi, short& lo) {
    unsigned int ub = __float_as_uint(u);
    hi = (short)(ub >> 16);
    float r = u - __uint_as_float(ub & 0xFFFF0000u);
    lo = (short)(__float_as_uint(r) >> 16);
}

__global__ void k_zero4(float4* p, int n4) {
    int i = blockIdx.x * blockDim.x + threadIdx.x;
    if (i < n4) p[i] = make_float4(0.f, 0.f, 0.f, 0.f);
}

__global__ void k_deg(const int* __restrict__ col, int* __restrict__ deg, int E) {
    int e = blockIdx.x * blockDim.x + threadIdx.x;
    if (e < E) atomicAdd(&deg[col[e]], 1);
}

__global__ void k_dinv(const int* __restrict__ deg, float* __restrict__ dinv, int n) {
    int v = blockIdx.x * blockDim.x + threadIdx.x;
    if (v < n) dinv[v] = rsqrtf((float)(deg[v] + 1));   // +1 self loop
}

__global__ __launch_bounds__(256) void k_scan_partial(const int* __restrict__ deg,
                                                      int* __restrict__ part, int n) {
    __shared__ int wtot[4];
    int tid = threadIdx.x;
    int base = blockIdx.x * SCAN_CHUNK + tid * 8;
    int s = 0;
#pragma unroll
    for (int i = 0; i < 8; ++i) { int idx = base + i; if (idx < n) s += deg[idx]; }
    for (int off = 1; off < 64; off <<= 1) s += __shfl_xor(s, off);
    if ((tid & 63) == 0) wtot[tid >> 6] = s;
    __syncthreads();
    if (tid == 0) part[blockIdx.x] = wtot[0] + wtot[1] + wtot[2] + wtot[3];
}

__global__ __launch_bounds__(64) void k_scan_offsets(const int* __restrict__ part,
                                                     int* __restrict__ offs,
                                                     int* __restrict__ ptr, int nb, int n, int E) {
    int lane = threadIdx.x;
    int p = (lane < nb) ? part[lane] : 0;
    int s = p;
    for (int off = 1; off < 64; off <<= 1) {
        int t = __shfl_up(s, off, 64);
        if (lane >= off) s += t;
    }
    if (lane < nb) offs[lane] = s - p;     // exclusive
    if (lane == 0) ptr[n] = E;
}

__global__ __launch_bounds__(256) void k_scan_final(const int* __restrict__ deg,
                                                    const int* __restrict__ offs,
                                                    int* __restrict__ ptr, int* __restrict__ cursor,
                                                    int n) {
    __shared__ int wtot[4];
    int tid = threadIdx.x;
    int lane = tid & 63, wv = tid >> 6;
    int base = blockIdx.x * SCAN_CHUNK + tid * 8;
    int d[8];
    int t8 = 0;
#pragma unroll
    for (int i = 0; i < 8; ++i) {
        int idx = base + i;
        d[i] = (idx < n) ? deg[idx] : 0;
        t8 += d[i];
    }
    int s = t8;
    for (int off = 1; off < 64; off <<= 1) {
        int t = __shfl_up(s, off, 64);
        if (lane >= off) s += t;
    }
    if (lane == 63) wtot[wv] = s;
    __syncthreads();
    int wpre = 0;
    for (int w = 0; w < 4; ++w) if (w < wv) wpre += wtot[w];
    int run = offs[blockIdx.x] + wpre + (s - t8);
#pragma unroll
    for (int i = 0; i < 8; ++i) {
        int idx = base + i;
        if (idx < n) { ptr[idx] = run; cursor[idx] = run; run += d[i]; }
    }
}

__global__ void k_fill(const int* __restrict__ row, const int* __restrict__ col,
                       int* __restrict__ cursor, int* __restrict__ csr_row, int E) {
    int e = blockIdx.x * blockDim.x + threadIdx.x;
    if (e >= E) return;
    int pos = atomicAdd(&cursor[col[e]], 1);
    csr_row[pos] = row[e];
}

// one wave per node: gather + GCN1 matmul + tanh + EdgeConv layer-1 tables
__global__ __launch_bounds__(256) void k_node_pre(
        const int* __restrict__ ptr, const int* __restrict__ csr_row,
        const float* __restrict__ x, const float* __restrict__ dinv,
        const float* __restrict__ gw, const float* __restrict__ gb,
        const float* __restrict__ w1, const float* __restrict__ b1,
        float* __restrict__ atab, float* __restrict__ btab, int n) {
    int wid = blockIdx.x * 4 + (threadIdx.x >> 6);
    if (wid >= n) return;
    int lane = threadIdx.x & 63;
    int f = lane & 31, half = lane >> 5;
    int v = wid;
    int start = ptr[v], end = ptr[v + 1];
    float s = 0.f;
    for (int p = start + half; p < end; p += 2) {
        int r = csr_row[p];
        s += dinv[r] * x[r * 32 + f];
    }
    s += __shfl_xor(s, 32);
    float dv = dinv[v];
    float sf = dv * s + dv * dv * x[v * 32 + f];   // GCN1 pre-activation input, feature f
    float acc = gb[lane];
#pragma unroll
    for (int d = 0; d < 32; ++d) {
        float sd = __shfl(sf, d, 64);
        acc = fmaf(sd, gw[d * 64 + lane], acc);
    }
    float hj = tanhf(acc);
    float acca = b1[lane], accb = 0.f;
#pragma unroll 8
    for (int d = 0; d < 64; ++d) {
        float hd = __shfl(hj, d, 64);
        float wt = w1[d * 64 + lane];
        float wb = w1[(64 + d) * 64 + lane];
        acca = fmaf(hd, wt - wb, acca);
        accb = fmaf(hd, wb, accb);
    }
    atab[v * 64 + lane] = acca;
    btab[v * 64 + lane] = accb;
}

// persistent waves: grid-stride over nodes; W2 frags preloaded once per wave;
// MFMA 16-edge tiles; segment max in registers; no atomics
__global__ __launch_bounds__(256) void k_edge_mlp(
        const int* __restrict__ ptr, const int* __restrict__ csr_row,
        const float* __restrict__ atab, const float* __restrict__ btab,
        const float* __restrict__ w2, const float* __restrict__ b2,
        float* __restrict__ hmax, int n) {
    int lane = threadIdx.x & 63;
    int n16 = lane & 15, q = lane >> 4;

    // preload W2 B-frags (hi/lo, RNE) + bias; B[k][nn]: lane holds nn=n16, k=ck*32+8q+j
    short8 bh[4][2], bl[4][2];
    float bias[4];
#pragma unroll
    for (int t = 0; t < 4; ++t) {
        bias[t] = b2[t * 16 + n16];
#pragma unroll
        for (int ck = 0; ck < 2; ++ck) {
            short8 hh, ll;
#pragma unroll
            for (int j = 0; j < 8; ++j) {
                float w = w2[(ck * 32 + q * 8 + j) * 64 + t * 16 + n16];
                unsigned short wh = f2bf(w);
                hh[j] = (short)wh;
                ll[j] = (short)f2bf(w - bf2f(wh));
            }
            bh[t][ck] = hh; bl[t][ck] = ll;
        }
    }

    int nwaves = gridDim.x * 4;
    int wid = blockIdx.x * 4 + (threadIdx.x >> 6);

    for (int c = wid; c < n; c += nwaves) {
        int start = ptr[c], end = ptr[c + 1];
        const float4* at4 = (const float4*)(atab + (size_t)c * 64);
        float4 A0 = at4[2 * q], A1 = at4[2 * q + 1];
        float4 A2 = at4[8 + 2 * q], A3 = at4[8 + 2 * q + 1];
        float ak[16] = {A0.x, A0.y, A0.z, A0.w, A1.x, A1.y, A1.z, A1.w,
                        A2.x, A2.y, A2.z, A2.w, A3.x, A3.y, A3.z, A3.w};

        float red[4] = {0.f, 0.f, 0.f, 0.f};   // init 0 folds relu + empty-segment-0

        for (int p0 = start; p0 < end; p0 += 16) {
            int kt = end - p0;
            int p = p0 + n16;
            float u[16];
            if (p < end) {
                int r = csr_row[p];
                const float4* bt4 = (const float4*)(btab + (size_t)r * 64);
                float4 B0 = bt4[2 * q], B1 = bt4[2 * q + 1];
                float4 B2 = bt4[8 + 2 * q], B3 = bt4[8 + 2 * q + 1];
                float bk[16] = {B0.x, B0.y, B0.z, B0.w, B1.x, B1.y, B1.z, B1.w,
                                B2.x, B2.y, B2.z, B2.w, B3.x, B3.y, B3.z, B3.w};
#pragma unroll
                for (int j = 0; j < 16; ++j) u[j] = fmaxf(ak[j] + bk[j], 0.f);
            } else {
#pragma unroll
                for (int j = 0; j < 16; ++j) u[j] = 0.f;
            }

            short8 ah0, ah1, al0, al1;
#pragma unroll
            for (int j = 0; j < 8; ++j) {
                short h, l;
                splitT(u[j], h, l);      ah0[j] = h; al0[j] = l;
                splitT(u[8 + j], h, l);  ah1[j] = h; al1[j] = l;
            }

#pragma unroll
            for (int t = 0; t < 4; ++t) {
                f32x4 acc = (f32x4){bias[t], bias[t], bias[t], bias[t]};
                acc = __builtin_amdgcn_mfma_f32_16x16x32_bf16(ah0, bh[t][0], acc, 0, 0, 0);
                acc = __builtin_amdgcn_mfma_f32_16x16x32_bf16(ah1, bh[t][1], acc, 0, 0, 0);
                acc = __builtin_amdgcn_mfma_f32_16x16x32_bf16(al0, bh[t][0], acc, 0, 0, 0);
                acc = __builtin_amdgcn_mfma_f32_16x16x32_bf16(al1, bh[t][1], acc, 0, 0, 0);
                acc = __builtin_amdgcn_mfma_f32_16x16x32_bf16(ah0, bl[t][0], acc, 0, 0, 0);
                acc = __builtin_amdgcn_mfma_f32_16x16x32_bf16(ah1, bl[t][1], acc, 0, 0, 0);
#pragma unroll
                for (int i = 0; i < 4; ++i) {
                    if (q * 4 + i < kt) red[t] = fmaxf(red[t], acc[i]);
                }
            }
        }
#pragma unroll
        for (int t = 0; t < 4; ++t) {
            red[t] = fmaxf(red[t], __shfl_xor(red[t], 16));
            red[t] = fmaxf(red[t], __shfl_xor(red[t], 32));
        }
        if (q == 0) {
#pragma unroll
            for (int t = 0; t < 4; ++t)
                hmax[(size_t)c * 64 + t * 16 + n16] = red[t];
        }
    }
}

// h2 = hmax @ Wg2 (64->16)
__global__ void k_gcn2_node(const float* __restrict__ hmax,
                            const float* __restrict__ wg,
                            float* __restrict__ h2, int n) {
    int t = blockIdx.x * blockDim.x + threadIdx.x;
    int v = t >> 4, j = t & 15;
    if (v >= n) return;
    float acc = 0.f;
#pragma unroll 8
    for (int d = 0; d < 64; ++d)
        acc = fmaf(hmax[v * 64 + d], wg[d * 16 + j], acc);
    h2[v * 16 + j] = acc;
}

// out[c] = bg + dv*(dv*h2[c] + sum_in dinv[r]*h2[r]) ; fully writes d_out
__global__ __launch_bounds__(256) void k_gcn2_gather(
        const int* __restrict__ ptr, const int* __restrict__ csr_row,
        const float* __restrict__ h2, const float* __restrict__ dinv,
        const float* __restrict__ bg, float* __restrict__ out, int n) {
    int wid = blockIdx.x * 4 + (threadIdx.x >> 6);
    if (wid >= n) return;
    int lane = threadIdx.x & 63;
    int f = lane & 15, es = lane >> 4;
    int c = wid;
    int start = ptr[c], end = ptr[c + 1];
    float s = 0.f;
    for (int p = start + es; p < end; p += 4) {
        int r = csr_row[p];
        s += dinv[r] * h2[r * 16 + f];
    }
    s += __shfl_xor(s, 16);
    s += __shfl_xor(s, 32);
    if (es == 0) {
        float dv = dinv[c];
        out[c * 16 + f] = bg[f] + dv * (dv * h2[c * 16 + f] + s);
    }
}

extern "C" void kernel_launch(void* const* d_in, const int* in_sizes, int n_in,
                              void* d_out, int out_size, void* d_ws, size_t ws_size,
                              hipStream_t stream) {
    const float* x   = (const float*)d_in[0];
    const int*   ei  = (const int*)d_in[1];
    const float* g1w = (const float*)d_in[2];
    const float* g1b = (const float*)d_in[3];
    const float* ew1 = (const float*)d_in[4];
    const float* eb1 = (const float*)d_in[5];
    const float* ew2 = (const float*)d_in[6];
    const float* eb2 = (const float*)d_in[7];
    const float* g2w = (const float*)d_in[8];
    const float* g2b = (const float*)d_in[9];
    float* out = (float*)d_out;
    float* ws  = (float*)d_ws;

    const int n = in_sizes[0] / 32;      // 50000
    const int E = in_sizes[1] / 2;       // 800000
    const int* row = ei;
    const int* col = ei + E;

    size_t npad    = ((size_t)n + 63) & ~(size_t)63;
    size_t o_deg   = 0;
    size_t o_ptr   = npad;               // n+1 (+pad)
    size_t o_cur   = o_ptr + npad + 64;
    size_t o_csr   = o_cur + npad;       // E ints
    size_t o_dinv  = o_csr + (size_t)E;
    size_t o_hmax  = o_dinv + npad;      // n*64
    size_t o_atab  = o_hmax + (size_t)n * 64;
    size_t o_btab  = o_atab + (size_t)n * 64;
    size_t o_h2    = o_btab + (size_t)n * 64;   // n*16
    size_t o_part  = o_h2 + (size_t)n * 16;     // 64 ints
    size_t o_offs  = o_part + 64;               // 64 ints

    int*   deg    = (int*)(ws + o_deg);
    int*   ptr    = (int*)(ws + o_ptr);
    int*   cursor = (int*)(ws + o_cur);
    int*   csr    = (int*)(ws + o_csr);
    float* dinv   = ws + o_dinv;
    float* hmax   = ws + o_hmax;
    float* atab   = ws + o_atab;
    float* btab   = ws + o_btab;
    float* h2     = ws + o_h2;
    int*   part   = (int*)(ws + o_part);
    int*   offs   = (int*)(ws + o_offs);

    int nblk = (n + 3) / 4;                      // wave-per-node kernels, 4 waves/block
    int scan_nb = (n + SCAN_CHUNK - 1) / SCAN_CHUNK;   // 25 <= 64

    k_zero4<<<(int)((npad / 4 + 255) / 256), 256, 0, stream>>>((float4*)deg, (int)(npad / 4));
    k_deg<<<(E + 255) / 256, 256, 0, stream>>>(col, deg, E);
    k_dinv<<<(n + 255) / 256, 256, 0, stream>>>(deg, dinv, n);
    k_scan_partial<<<scan_nb, 256, 0, stream>>>(deg, part, n);
    k_scan_offsets<<<1, 64, 0, stream>>>(part, offs, ptr, scan_nb, n, E);
    k_scan_final<<<scan_nb, 256, 0, stream>>>(deg, offs, ptr, cursor, n);
    k_fill<<<(E + 255) / 256, 256, 0, stream>>>(row, col, cursor, csr, E);
    k_node_pre<<<nblk, 256, 0, stream>>>(ptr, csr, x, dinv, g1w, g1b, ew1, eb1, atab, btab, n);
    k_edge_mlp<<<1024, 256, 0, stream>>>(ptr, csr, atab, btab, ew2, eb2, hmax, n);
    k_gcn2_node<<<(n * 16 + 255) / 256, 256, 0, stream>>>(hmax, g2w, h2, n);
    k_gcn2_gather<<<nblk, 256, 0, stream>>>(ptr, csr, h2, dinv, g2b, out, n);
}

// Round 8
// 348.055 us; speedup vs baseline: 3.5404x; 1.0778x over previous
//
#include <hip/hip_runtime.h>

// CSR-gather pipeline (no float atomics):
//   deg -> multi-block scan(ptr) -> fill csr_row (edges sorted by col)
//   gather32: agg[v] = dv*sum(dinv[r]*x[r]) + dv^2*x[v]      (irregular, 32 dims)
//   h1 (MFMA dense): h1 = tanh(agg @ Wg1 + gb)               (50k x 32 x 64)
//   w1tab (MFMA dense): atab = h1@(W1a-W1b)+b1 ; btab = h1@W1b
//   edge_mlp (persistent waves, MFMA): u = relu(atab[c]+btab[r]); m = u@W2+b2;
//                         hmax[c] = max over edges (in regs)
//   gcn2: h2 = hmax@Wg2 ; out[c] = bg + dv*(dv*h2[c] + gather sum dinv[r]*h2[r])

typedef __attribute__((ext_vector_type(8))) short short8;
typedef __attribute__((ext_vector_type(4))) float f32x4;

#define SCAN_CHUNK 2048   // elements per scan block (256 thr x 8)

__device__ __forceinline__ unsigned short f2bf(float x) {   // RNE f32->bf16 (cold paths only)
    unsigned int u = __float_as_uint(x);
    return (unsigned short)((u + 0x7FFFu + ((u >> 16) & 1u)) >> 16);
}
__device__ __forceinline__ float bf2f(unsigned short h) {
    return __uint_as_float(((unsigned int)h) << 16);
}
// cheap truncation split: u ~= hi + lo with |err| ~ 2^-16 |u|
__device__ __forceinline__ void splitT(float u, short& hi, short& lo) {
    unsigned int ub = __float_as_uint(u);
    hi = (short)(ub >> 16);
    float r = u - __uint_as_float(ub & 0xFFFF0000u);
    lo = (short)(__float_as_uint(r) >> 16);
}

__global__ void k_zero4(float4* p, int n4) {
    int i = blockIdx.x * blockDim.x + threadIdx.x;
    if (i < n4) p[i] = make_float4(0.f, 0.f, 0.f, 0.f);
}

__global__ void k_deg(const int* __restrict__ col, int* __restrict__ deg, int E) {
    int e = blockIdx.x * blockDim.x + threadIdx.x;
    if (e < E) atomicAdd(&deg[col[e]], 1);
}

__global__ void k_dinv(const int* __restrict__ deg, float* __restrict__ dinv, int n) {
    int v = blockIdx.x * blockDim.x + threadIdx.x;
    if (v < n) dinv[v] = rsqrtf((float)(deg[v] + 1));   // +1 self loop
}

__global__ __launch_bounds__(256) void k_scan_partial(const int* __restrict__ deg,
                                                      int* __restrict__ part, int n) {
    __shared__ int wtot[4];
    int tid = threadIdx.x;
    int base = blockIdx.x * SCAN_CHUNK + tid * 8;
    int s = 0;
#pragma unroll
    for (int i = 0; i < 8; ++i) { int idx = base + i; if (idx < n) s += deg[idx]; }
    for (int off = 1; off < 64; off <<= 1) s += __shfl_xor(s, off);
    if ((tid & 63) == 0) wtot[tid >> 6] = s;
    __syncthreads();
    if (tid == 0) part[blockIdx.x] = wtot[0] + wtot[1] + wtot[2] + wtot[3];
}

__global__ __launch_bounds__(64) void k_scan_offsets(const int* __restrict__ part,
                                                     int* __restrict__ offs,
                                                     int* __restrict__ ptr, int nb, int n, int E) {
    int lane = threadIdx.x;
    int p = (lane < nb) ? part[lane] : 0;
    int s = p;
    for (int off = 1; off < 64; off <<= 1) {
        int t = __shfl_up(s, off, 64);
        if (lane >= off) s += t;
    }
    if (lane < nb) offs[lane] = s - p;     // exclusive
    if (lane == 0) ptr[n] = E;
}

__global__ __launch_bounds__(256) void k_scan_final(const int* __restrict__ deg,
                                                    const int* __restrict__ offs,
                                                    int* __restrict__ ptr, int* __restrict__ cursor,
                                                    int n) {
    __shared__ int wtot[4];
    int tid = threadIdx.x;
    int lane = tid & 63, wv = tid >> 6;
    int base = blockIdx.x * SCAN_CHUNK + tid * 8;
    int d[8];
    int t8 = 0;
#pragma unroll
    for (int i = 0; i < 8; ++i) {
        int idx = base + i;
        d[i] = (idx < n) ? deg[idx] : 0;
        t8 += d[i];
    }
    int s = t8;
    for (int off = 1; off < 64; off <<= 1) {
        int t = __shfl_up(s, off, 64);
        if (lane >= off) s += t;
    }
    if (lane == 63) wtot[wv] = s;
    __syncthreads();
    int wpre = 0;
    for (int w = 0; w < 4; ++w) if (w < wv) wpre += wtot[w];
    int run = offs[blockIdx.x] + wpre + (s - t8);
#pragma unroll
    for (int i = 0; i < 8; ++i) {
        int idx = base + i;
        if (idx < n) { ptr[idx] = run; cursor[idx] = run; run += d[i]; }
    }
}

__global__ void k_fill(const int* __restrict__ row, const int* __restrict__ col,
                       int* __restrict__ cursor, int* __restrict__ csr_row, int E) {
    int e = blockIdx.x * blockDim.x + threadIdx.x;
    if (e >= E) return;
    int pos = atomicAdd(&cursor[col[e]], 1);
    csr_row[pos] = row[e];
}

// irregular gather only: agg[v][f] = dv*(sum dinv[r]*x[r][f]) + dv^2*x[v][f]
__global__ __launch_bounds__(256) void k_gather32(
        const int* __restrict__ ptr, const int* __restrict__ csr_row,
        const float* __restrict__ x, const float* __restrict__ dinv,
        float* __restrict__ agg, int n) {
    int wid = blockIdx.x * 4 + (threadIdx.x >> 6);
    if (wid >= n) return;
    int lane = threadIdx.x & 63;
    int f = lane & 31, half = lane >> 5;
    int v = wid;
    int start = ptr[v], end = ptr[v + 1];
    float s = 0.f;
    for (int p = start + half; p < end; p += 2) {
        int r = csr_row[p];
        s += dinv[r] * x[r * 32 + f];
    }
    s += __shfl_xor(s, 32);
    if (half == 0) {
        float dv = dinv[v];
        agg[v * 32 + f] = dv * s + dv * dv * x[v * 32 + f];
    }
}

// dense MFMA: h1 = tanh(agg @ Wg1 + gb), tiles of 16 nodes, one wave/tile
__global__ __launch_bounds__(256) void k_h1(
        const float* __restrict__ agg, const float* __restrict__ gw,
        const float* __restrict__ gb, float* __restrict__ h1, int ntiles) {
    int wid = blockIdx.x * 4 + (threadIdx.x >> 6);
    if (wid >= ntiles) return;
    int lane = threadIdx.x & 63;
    int n16 = lane & 15, q = lane >> 4;

    short8 bh[4], bl[4];
    float bias[4];
#pragma unroll
    for (int t = 0; t < 4; ++t) {
        bias[t] = gb[t * 16 + n16];
        short8 hh, ll;
#pragma unroll
        for (int j = 0; j < 8; ++j) {
            float w = gw[(q * 8 + j) * 64 + t * 16 + n16];
            unsigned short wh = f2bf(w);
            hh[j] = (short)wh;
            ll[j] = (short)f2bf(w - bf2f(wh));
        }
        bh[t] = hh; bl[t] = ll;
    }

    int v0 = wid * 16;
    const float4* a4 = (const float4*)(agg + (size_t)(v0 + n16) * 32);
    float4 A0 = a4[2 * q], A1 = a4[2 * q + 1];
    float a[8] = {A0.x, A0.y, A0.z, A0.w, A1.x, A1.y, A1.z, A1.w};
    short8 ah, al;
#pragma unroll
    for (int j = 0; j < 8; ++j) { short h, l; splitT(a[j], h, l); ah[j] = h; al[j] = l; }

#pragma unroll
    for (int t = 0; t < 4; ++t) {
        f32x4 acc = (f32x4){bias[t], bias[t], bias[t], bias[t]};
        acc = __builtin_amdgcn_mfma_f32_16x16x32_bf16(ah, bh[t], acc, 0, 0, 0);
        acc = __builtin_amdgcn_mfma_f32_16x16x32_bf16(al, bh[t], acc, 0, 0, 0);
        acc = __builtin_amdgcn_mfma_f32_16x16x32_bf16(ah, bl[t], acc, 0, 0, 0);
#pragma unroll
        for (int i = 0; i < 4; ++i)
            h1[(size_t)(v0 + q * 4 + i) * 64 + t * 16 + n16] = tanhf(acc[i]);
    }
}

// dense MFMA: atab = h1@(W1a-W1b)+b1 ; btab = h1@W1b ; persistent waves
__global__ __launch_bounds__(256, 1) void k_w1tab(
        const float* __restrict__ h1, const float* __restrict__ w1,
        const float* __restrict__ b1,
        float* __restrict__ atab, float* __restrict__ btab, int ntiles) {
    int lane = threadIdx.x & 63;
    int n16 = lane & 15, q = lane >> 4;

    short8 th[4][2], tl[4][2], uh[4][2], ul[4][2];   // wt=W1a-W1b, wb=W1b frags
    float bias[4];
#pragma unroll
    for (int t = 0; t < 4; ++t) {
        bias[t] = b1[t * 16 + n16];
#pragma unroll
        for (int ck = 0; ck < 2; ++ck) {
            short8 h1v, l1v, h2v, l2v;
#pragma unroll
            for (int j = 0; j < 8; ++j) {
                int d = ck * 32 + q * 8 + j;
                float wbv = w1[(64 + d) * 64 + t * 16 + n16];
                float wtv = w1[d * 64 + t * 16 + n16] - wbv;
                unsigned short x1 = f2bf(wtv);
                h1v[j] = (short)x1; l1v[j] = (short)f2bf(wtv - bf2f(x1));
                unsigned short x2 = f2bf(wbv);
                h2v[j] = (short)x2; l2v[j] = (short)f2bf(wbv - bf2f(x2));
            }
            th[t][ck] = h1v; tl[t][ck] = l1v;
            uh[t][ck] = h2v; ul[t][ck] = l2v;
        }
    }

    int nwaves = gridDim.x * 4;
    int wid = blockIdx.x * 4 + (threadIdx.x >> 6);
    for (int tile = wid; tile < ntiles; tile += nwaves) {
        int v0 = tile * 16;
        const float4* a4 = (const float4*)(h1 + (size_t)(v0 + n16) * 64);
        float4 A0 = a4[2 * q], A1 = a4[2 * q + 1];
        float4 A2 = a4[8 + 2 * q], A3 = a4[8 + 2 * q + 1];
        float a[16] = {A0.x, A0.y, A0.z, A0.w, A1.x, A1.y, A1.z, A1.w,
                       A2.x, A2.y, A2.z, A2.w, A3.x, A3.y, A3.z, A3.w};
        short8 ah0, ah1, al0, al1;
#pragma unroll
        for (int j = 0; j < 8; ++j) {
            short h, l;
            splitT(a[j], h, l);      ah0[j] = h; al0[j] = l;
            splitT(a[8 + j], h, l);  ah1[j] = h; al1[j] = l;
        }
#pragma unroll
        for (int t = 0; t < 4; ++t) {
            f32x4 aa = (f32x4){bias[t], bias[t], bias[t], bias[t]};
            aa = __builtin_amdgcn_mfma_f32_16x16x32_bf16(ah0, th[t][0], aa, 0, 0, 0);
            aa = __builtin_amdgcn_mfma_f32_16x16x32_bf16(ah1, th[t][1], aa, 0, 0, 0);
            aa = __builtin_amdgcn_mfma_f32_16x16x32_bf16(al0, th[t][0], aa, 0, 0, 0);
            aa = __builtin_amdgcn_mfma_f32_16x16x32_bf16(al1, th[t][1], aa, 0, 0, 0);
            aa = __builtin_amdgcn_mfma_f32_16x16x32_bf16(ah0, tl[t][0], aa, 0, 0, 0);
            aa = __builtin_amdgcn_mfma_f32_16x16x32_bf16(ah1, tl[t][1], aa, 0, 0, 0);
            f32x4 bb = (f32x4){0.f, 0.f, 0.f, 0.f};
            bb = __builtin_amdgcn_mfma_f32_16x16x32_bf16(ah0, uh[t][0], bb, 0, 0, 0);
            bb = __builtin_amdgcn_mfma_f32_16x16x32_bf16(ah1, uh[t][1], bb, 0, 0, 0);
            bb = __builtin_amdgcn_mfma_f32_16x16x32_bf16(al0, uh[t][0], bb, 0, 0, 0);
            bb = __builtin_amdgcn_mfma_f32_16x16x32_bf16(al1, uh[t][1], bb, 0, 0, 0);
            bb = __builtin_amdgcn_mfma_f32_16x16x32_bf16(ah0, ul[t][0], bb, 0, 0, 0);
            bb = __builtin_amdgcn_mfma_f32_16x16x32_bf16(ah1, ul[t][1], bb, 0, 0, 0);
#pragma unroll
            for (int i = 0; i < 4; ++i) {
                size_t off = (size_t)(v0 + q * 4 + i) * 64 + t * 16 + n16;
                atab[off] = aa[i];
                btab[off] = bb[i];
            }
        }
    }
}

// persistent waves: grid-stride over nodes; W2 frags preloaded once per wave;
// MFMA 16-edge tiles; segment max in registers; no atomics
__global__ __launch_bounds__(256) void k_edge_mlp(
        const int* __restrict__ ptr, const int* __restrict__ csr_row,
        const float* __restrict__ atab, const float* __restrict__ btab,
        const float* __restrict__ w2, const float* __restrict__ b2,
        float* __restrict__ hmax, int n) {
    int lane = threadIdx.x & 63;
    int n16 = lane & 15, q = lane >> 4;

    short8 bh[4][2], bl[4][2];
    float bias[4];
#pragma unroll
    for (int t = 0; t < 4; ++t) {
        bias[t] = b2[t * 16 + n16];
#pragma unroll
        for (int ck = 0; ck < 2; ++ck) {
            short8 hh, ll;
#pragma unroll
            for (int j = 0; j < 8; ++j) {
                float w = w2[(ck * 32 + q * 8 + j) * 64 + t * 16 + n16];
                unsigned short wh = f2bf(w);
                hh[j] = (short)wh;
                ll[j] = (short)f2bf(w - bf2f(wh));
            }
            bh[t][ck] = hh; bl[t][ck] = ll;
        }
    }

    int nwaves = gridDim.x * 4;
    int wid = blockIdx.x * 4 + (threadIdx.x >> 6);

    for (int c = wid; c < n; c += nwaves) {
        int start = ptr[c], end = ptr[c + 1];
        const float4* at4 = (const float4*)(atab + (size_t)c * 64);
        float4 A0 = at4[2 * q], A1 = at4[2 * q + 1];
        float4 A2 = at4[8 + 2 * q], A3 = at4[8 + 2 * q + 1];
        float ak[16] = {A0.x, A0.y, A0.z, A0.w, A1.x, A1.y, A1.z, A1.w,
                        A2.x, A2.y, A2.z, A2.w, A3.x, A3.y, A3.z, A3.w};

        float red[4] = {0.f, 0.f, 0.f, 0.f};   // init 0 folds relu + empty-segment-0

        for (int p0 = start; p0 < end; p0 += 16) {
            int kt = end - p0;
            int p = p0 + n16;
            float u[16];
            if (p < end) {
                int r = csr_row[p];
                const float4* bt4 = (const float4*)(btab + (size_t)r * 64);
                float4 B0 = bt4[2 * q], B1 = bt4[2 * q + 1];
                float4 B2 = bt4[8 + 2 * q], B3 = bt4[8 + 2 * q + 1];
                float bk[16] = {B0.x, B0.y, B0.z, B0.w, B1.x, B1.y, B1.z, B1.w,
                                B2.x, B2.y, B2.z, B2.w, B3.x, B3.y, B3.z, B3.w};
#pragma unroll
                for (int j = 0; j < 16; ++j) u[j] = fmaxf(ak[j] + bk[j], 0.f);
            } else {
#pragma unroll
                for (int j = 0; j < 16; ++j) u[j] = 0.f;
            }

            short8 ah0, ah1, al0, al1;
#pragma unroll
            for (int j = 0; j < 8; ++j) {
                short h, l;
                splitT(u[j], h, l);      ah0[j] = h; al0[j] = l;
                splitT(u[8 + j], h, l);  ah1[j] = h; al1[j] = l;
            }

#pragma unroll
            for (int t = 0; t < 4; ++t) {
                f32x4 acc = (f32x4){bias[t], bias[t], bias[t], bias[t]};
                acc = __builtin_amdgcn_mfma_f32_16x16x32_bf16(ah0, bh[t][0], acc, 0, 0, 0);
                acc = __builtin_amdgcn_mfma_f32_16x16x32_bf16(ah1, bh[t][1], acc, 0, 0, 0);
                acc = __builtin_amdgcn_mfma_f32_16x16x32_bf16(al0, bh[t][0], acc, 0, 0, 0);
                acc = __builtin_amdgcn_mfma_f32_16x16x32_bf16(al1, bh[t][1], acc, 0, 0, 0);
                acc = __builtin_amdgcn_mfma_f32_16x16x32_bf16(ah0, bl[t][0], acc, 0, 0, 0);
                acc = __builtin_amdgcn_mfma_f32_16x16x32_bf16(ah1, bl[t][1], acc, 0, 0, 0);
#pragma unroll
                for (int i = 0; i < 4; ++i) {
                    if (q * 4 + i < kt) red[t] = fmaxf(red[t], acc[i]);
                }
            }
        }
#pragma unroll
        for (int t = 0; t < 4; ++t) {
            red[t] = fmaxf(red[t], __shfl_xor(red[t], 16));
            red[t] = fmaxf(red[t], __shfl_xor(red[t], 32));
        }
        if (q == 0) {
#pragma unroll
            for (int t = 0; t < 4; ++t)
                hmax[(size_t)c * 64 + t * 16 + n16] = red[t];
        }
    }
}

// h2 = hmax @ Wg2 (64->16)
__global__ void k_gcn2_node(const float* __restrict__ hmax,
                            const float* __restrict__ wg,
                            float* __restrict__ h2, int n) {
    int t = blockIdx.x * blockDim.x + threadIdx.x;
    int v = t >> 4, j = t & 15;
    if (v >= n) return;
    float acc = 0.f;
#pragma unroll 8
    for (int d = 0; d < 64; ++d)
        acc = fmaf(hmax[v * 64 + d], wg[d * 16 + j], acc);
    h2[v * 16 + j] = acc;
}

// out[c] = bg + dv*(dv*h2[c] + sum_in dinv[r]*h2[r]) ; fully writes d_out
__global__ __launch_bounds__(256) void k_gcn2_gather(
        const int* __restrict__ ptr, const int* __restrict__ csr_row,
        const float* __restrict__ h2, const float* __restrict__ dinv,
        const float* __restrict__ bg, float* __restrict__ out, int n) {
    int wid = blockIdx.x * 4 + (threadIdx.x >> 6);
    if (wid >= n) return;
    int lane = threadIdx.x & 63;
    int f = lane & 15, es = lane >> 4;
    int c = wid;
    int start = ptr[c], end = ptr[c + 1];
    float s = 0.f;
    for (int p = start + es; p < end; p += 4) {
        int r = csr_row[p];
        s += dinv[r] * h2[r * 16 + f];
    }
    s += __shfl_xor(s, 16);
    s += __shfl_xor(s, 32);
    if (es == 0) {
        float dv = dinv[c];
        out[c * 16 + f] = bg[f] + dv * (dv * h2[c * 16 + f] + s);
    }
}

extern "C" void kernel_launch(void* const* d_in, const int* in_sizes, int n_in,
                              void* d_out, int out_size, void* d_ws, size_t ws_size,
                              hipStream_t stream) {
    const float* x   = (const float*)d_in[0];
    const int*   ei  = (const int*)d_in[1];
    const float* g1w = (const float*)d_in[2];
    const float* g1b = (const float*)d_in[3];
    const float* ew1 = (const float*)d_in[4];
    const float* eb1 = (const float*)d_in[5];
    const float* ew2 = (const float*)d_in[6];
    const float* eb2 = (const float*)d_in[7];
    const float* g2w = (const float*)d_in[8];
    const float* g2b = (const float*)d_in[9];
    float* out = (float*)d_out;
    float* ws  = (float*)d_ws;

    const int n = in_sizes[0] / 32;      // 50000
    const int E = in_sizes[1] / 2;       // 800000
    const int* row = ei;
    const int* col = ei + E;
    const int ntiles = (n + 15) / 16;    // 3125

    size_t npad    = ((size_t)n + 63) & ~(size_t)63;
    size_t o_deg   = 0;
    size_t o_ptr   = npad;               // n+1 (+pad)
    size_t o_cur   = o_ptr + npad + 64;
    size_t o_csr   = o_cur + npad;       // E ints
    size_t o_dinv  = o_csr + (size_t)E;
    size_t o_hmax  = o_dinv + npad;      // n*64 ; h1 overlays (dead before edge_mlp)
    size_t o_atab  = o_hmax + (size_t)n * 64;
    size_t o_btab  = o_atab + (size_t)n * 64;
    size_t o_agg   = o_btab + (size_t)n * 64;   // n*32 ; h2 (n*16) overlays front
    size_t o_part  = o_agg + (size_t)n * 32;    // 64 ints
    size_t o_offs  = o_part + 64;               // 64 ints

    int*   deg    = (int*)(ws + o_deg);
    int*   ptr    = (int*)(ws + o_ptr);
    int*   cursor = (int*)(ws + o_cur);
    int*   csr    = (int*)(ws + o_csr);
    float* dinv   = ws + o_dinv;
    float* hmax   = ws + o_hmax;
    float* h1     = ws + o_hmax;         // overlay
    float* atab   = ws + o_atab;
    float* btab   = ws + o_btab;
    float* agg    = ws + o_agg;
    float* h2     = ws + o_agg;          // overlay (agg dead after k_h1)
    int*   part   = (int*)(ws + o_part);
    int*   offs   = (int*)(ws + o_offs);

    int nblk = (n + 3) / 4;                      // wave-per-node kernels, 4 waves/block
    int tblk = (ntiles + 3) / 4;
    int scan_nb = (n + SCAN_CHUNK - 1) / SCAN_CHUNK;   // 25 <= 64

    k_zero4<<<(int)((npad / 4 + 255) / 256), 256, 0, stream>>>((float4*)deg, (int)(npad / 4));
    k_deg<<<(E + 255) / 256, 256, 0, stream>>>(col, deg, E);
    k_dinv<<<(n + 255) / 256, 256, 0, stream>>>(deg, dinv, n);
    k_scan_partial<<<scan_nb, 256, 0, stream>>>(deg, part, n);
    k_scan_offsets<<<1, 64, 0, stream>>>(part, offs, ptr, scan_nb, n, E);
    k_scan_final<<<scan_nb, 256, 0, stream>>>(deg, offs, ptr, cursor, n);
    k_fill<<<(E + 255) / 256, 256, 0, stream>>>(row, col, cursor, csr, E);
    k_gather32<<<nblk, 256, 0, stream>>>(ptr, csr, x, dinv, agg, n);
    k_h1<<<tblk, 256, 0, stream>>>(agg, g1w, g1b, h1, ntiles);
    k_w1tab<<<256, 256, 0, stream>>>(h1, ew1, eb1, atab, btab, ntiles);
    k_edge_mlp<<<1024, 256, 0, stream>>>(ptr, csr, atab, btab, ew2, eb2, hmax, n);
    k_gcn2_node<<<(n * 16 + 255) / 256, 256, 0, stream>>>(hmax, g2w, h2, n);
    k_gcn2_gather<<<nblk, 256, 0, stream>>>(ptr, csr, h2, dinv, g2b, out, n);
}

// Round 9
// 317.743 us; speedup vs baseline: 3.8782x; 1.0954x over previous
//
#include <hip/hip_runtime.h>

// CSR-gather pipeline (no float atomics):
//   deg -> multi-block scan(ptr) -> fill csr_row (edges sorted by col)
//   gather32: agg[v] = dv*sum(dinv[r]*x[r]) + dv^2*x[v]      (irregular, 32 dims)
//   h1 (MFMA dense): h1 = tanh(agg @ Wg1 + gb)               (50k x 32 x 64)
//   w1tab (MFMA dense): atab = h1@(W1a-W1b)+b1 ; btab = h1@W1b
//   edge_mlp (persistent waves, MFMA, node-ahead prefetch): u = relu(atab[c]+btab[r]);
//                         m = u@W2+b2; hmax[c] = max over edges (in regs)
//   gcn2: h2 = hmax@Wg2 ; out[c] = bg + dv*(dv*h2[c] + gather sum dinv[r]*h2[r])

typedef __attribute__((ext_vector_type(8))) short short8;
typedef __attribute__((ext_vector_type(4))) float f32x4;

#define SCAN_CHUNK 2048   // elements per scan block (256 thr x 8)

__device__ __forceinline__ unsigned short f2bf(float x) {   // RNE f32->bf16 (cold paths only)
    unsigned int u = __float_as_uint(x);
    return (unsigned short)((u + 0x7FFFu + ((u >> 16) & 1u)) >> 16);
}
__device__ __forceinline__ float bf2f(unsigned short h) {
    return __uint_as_float(((unsigned int)h) << 16);
}
// cheap truncation split: u ~= hi + lo with |err| ~ 2^-16 |u|
__device__ __forceinline__ void splitT(float u, short& hi, short& lo) {
    unsigned int ub = __float_as_uint(u);
    hi = (short)(ub >> 16);
    float r = u - __uint_as_float(ub & 0xFFFF0000u);
    lo = (short)(__float_as_uint(r) >> 16);
}

__global__ void k_zero4(float4* p, int n4) {
    int i = blockIdx.x * blockDim.x + threadIdx.x;
    if (i < n4) p[i] = make_float4(0.f, 0.f, 0.f, 0.f);
}

__global__ void k_deg(const int* __restrict__ col, int* __restrict__ deg, int E) {
    int e = blockIdx.x * blockDim.x + threadIdx.x;
    if (e < E) atomicAdd(&deg[col[e]], 1);
}

__global__ void k_dinv(const int* __restrict__ deg, float* __restrict__ dinv, int n) {
    int v = blockIdx.x * blockDim.x + threadIdx.x;
    if (v < n) dinv[v] = rsqrtf((float)(deg[v] + 1));   // +1 self loop
}

__global__ __launch_bounds__(256) void k_scan_partial(const int* __restrict__ deg,
                                                      int* __restrict__ part, int n) {
    __shared__ int wtot[4];
    int tid = threadIdx.x;
    int base = blockIdx.x * SCAN_CHUNK + tid * 8;
    int s = 0;
#pragma unroll
    for (int i = 0; i < 8; ++i) { int idx = base + i; if (idx < n) s += deg[idx]; }
    for (int off = 1; off < 64; off <<= 1) s += __shfl_xor(s, off);
    if ((tid & 63) == 0) wtot[tid >> 6] = s;
    __syncthreads();
    if (tid == 0) part[blockIdx.x] = wtot[0] + wtot[1] + wtot[2] + wtot[3];
}

__global__ __launch_bounds__(64) void k_scan_offsets(const int* __restrict__ part,
                                                     int* __restrict__ offs,
                                                     int* __restrict__ ptr, int nb, int n, int E) {
    int lane = threadIdx.x;
    int p = (lane < nb) ? part[lane] : 0;
    int s = p;
    for (int off = 1; off < 64; off <<= 1) {
        int t = __shfl_up(s, off, 64);
        if (lane >= off) s += t;
    }
    if (lane < nb) offs[lane] = s - p;     // exclusive
    if (lane == 0) ptr[n] = E;
}

__global__ __launch_bounds__(256) void k_scan_final(const int* __restrict__ deg,
                                                    const int* __restrict__ offs,
                                                    int* __restrict__ ptr, int* __restrict__ cursor,
                                                    int n) {
    __shared__ int wtot[4];
    int tid = threadIdx.x;
    int lane = tid & 63, wv = tid >> 6;
    int base = blockIdx.x * SCAN_CHUNK + tid * 8;
    int d[8];
    int t8 = 0;
#pragma unroll
    for (int i = 0; i < 8; ++i) {
        int idx = base + i;
        d[i] = (idx < n) ? deg[idx] : 0;
        t8 += d[i];
    }
    int s = t8;
    for (int off = 1; off < 64; off <<= 1) {
        int t = __shfl_up(s, off, 64);
        if (lane >= off) s += t;
    }
    if (lane == 63) wtot[wv] = s;
    __syncthreads();
    int wpre = 0;
    for (int w = 0; w < 4; ++w) if (w < wv) wpre += wtot[w];
    int run = offs[blockIdx.x] + wpre + (s - t8);
#pragma unroll
    for (int i = 0; i < 8; ++i) {
        int idx = base + i;
        if (idx < n) { ptr[idx] = run; cursor[idx] = run; run += d[i]; }
    }
}

__global__ void k_fill(const int* __restrict__ row, const int* __restrict__ col,
                       int* __restrict__ cursor, int* __restrict__ csr_row, int E) {
    int e = blockIdx.x * blockDim.x + threadIdx.x;
    if (e >= E) return;
    int pos = atomicAdd(&cursor[col[e]], 1);
    csr_row[pos] = row[e];
}

// irregular gather: agg[v][f] = dv*(sum dinv[r]*x[r][f]) + dv^2*x[v][f]
// 4 edge slots x 16 lanes x float2; one-ahead index prefetch
__global__ __launch_bounds__(256) void k_gather32(
        const int* __restrict__ ptr, const int* __restrict__ csr_row,
        const float* __restrict__ x, const float* __restrict__ dinv,
        float* __restrict__ agg, int n) {
    int wid = blockIdx.x * 4 + (threadIdx.x >> 6);
    if (wid >= n) return;
    int lane = threadIdx.x & 63;
    int f2 = lane & 15, slot = lane >> 4;
    int v = wid;
    int start = ptr[v], end = ptr[v + 1];
    const float2* x2 = (const float2*)x;
    float sx = 0.f, sy = 0.f;
    int p = start + slot;
    int r = (p < end) ? csr_row[p] : 0;
    while (p < end) {
        int rcur = r;
        int pn = p + 4;
        if (pn < end) r = csr_row[pn];
        float dr = dinv[rcur];
        float2 xv = x2[(size_t)rcur * 16 + f2];
        sx = fmaf(dr, xv.x, sx);
        sy = fmaf(dr, xv.y, sy);
        p = pn;
    }
    sx += __shfl_xor(sx, 16); sy += __shfl_xor(sy, 16);
    sx += __shfl_xor(sx, 32); sy += __shfl_xor(sy, 32);
    if (slot == 0) {
        float dv = dinv[v];
        float2 xv = x2[(size_t)v * 16 + f2];
        agg[(size_t)v * 32 + 2 * f2]     = dv * sx + dv * dv * xv.x;
        agg[(size_t)v * 32 + 2 * f2 + 1] = dv * sy + dv * dv * xv.y;
    }
}

// dense MFMA: h1 = tanh(agg @ Wg1 + gb), tiles of 16 nodes, one wave/tile
__global__ __launch_bounds__(256) void k_h1(
        const float* __restrict__ agg, const float* __restrict__ gw,
        const float* __restrict__ gb, float* __restrict__ h1, int ntiles) {
    int wid = blockIdx.x * 4 + (threadIdx.x >> 6);
    if (wid >= ntiles) return;
    int lane = threadIdx.x & 63;
    int n16 = lane & 15, q = lane >> 4;

    short8 bh[4], bl[4];
    float bias[4];
#pragma unroll
    for (int t = 0; t < 4; ++t) {
        bias[t] = gb[t * 16 + n16];
        short8 hh, ll;
#pragma unroll
        for (int j = 0; j < 8; ++j) {
            float w = gw[(q * 8 + j) * 64 + t * 16 + n16];
            unsigned short wh = f2bf(w);
            hh[j] = (short)wh;
            ll[j] = (short)f2bf(w - bf2f(wh));
        }
        bh[t] = hh; bl[t] = ll;
    }

    int v0 = wid * 16;
    const float4* a4 = (const float4*)(agg + (size_t)(v0 + n16) * 32);
    float4 A0 = a4[2 * q], A1 = a4[2 * q + 1];
    float a[8] = {A0.x, A0.y, A0.z, A0.w, A1.x, A1.y, A1.z, A1.w};
    short8 ah, al;
#pragma unroll
    for (int j = 0; j < 8; ++j) { short h, l; splitT(a[j], h, l); ah[j] = h; al[j] = l; }

#pragma unroll
    for (int t = 0; t < 4; ++t) {
        f32x4 acc = (f32x4){bias[t], bias[t], bias[t], bias[t]};
        acc = __builtin_amdgcn_mfma_f32_16x16x32_bf16(ah, bh[t], acc, 0, 0, 0);
        acc = __builtin_amdgcn_mfma_f32_16x16x32_bf16(al, bh[t], acc, 0, 0, 0);
        acc = __builtin_amdgcn_mfma_f32_16x16x32_bf16(ah, bl[t], acc, 0, 0, 0);
#pragma unroll
        for (int i = 0; i < 4; ++i)
            h1[(size_t)(v0 + q * 4 + i) * 64 + t * 16 + n16] = tanhf(acc[i]);
    }
}

// dense MFMA: atab = h1@(W1a-W1b)+b1 ; btab = h1@W1b ; persistent waves
__global__ __launch_bounds__(256, 1) void k_w1tab(
        const float* __restrict__ h1, const float* __restrict__ w1,
        const float* __restrict__ b1,
        float* __restrict__ atab, float* __restrict__ btab, int ntiles) {
    int lane = threadIdx.x & 63;
    int n16 = lane & 15, q = lane >> 4;

    short8 th[4][2], tl[4][2], uh[4][2], ul[4][2];   // wt=W1a-W1b, wb=W1b frags
    float bias[4];
#pragma unroll
    for (int t = 0; t < 4; ++t) {
        bias[t] = b1[t * 16 + n16];
#pragma unroll
        for (int ck = 0; ck < 2; ++ck) {
            short8 h1v, l1v, h2v, l2v;
#pragma unroll
            for (int j = 0; j < 8; ++j) {
                int d = ck * 32 + q * 8 + j;
                float wbv = w1[(64 + d) * 64 + t * 16 + n16];
                float wtv = w1[d * 64 + t * 16 + n16] - wbv;
                unsigned short x1 = f2bf(wtv);
                h1v[j] = (short)x1; l1v[j] = (short)f2bf(wtv - bf2f(x1));
                unsigned short x2 = f2bf(wbv);
                h2v[j] = (short)x2; l2v[j] = (short)f2bf(wbv - bf2f(x2));
            }
            th[t][ck] = h1v; tl[t][ck] = l1v;
            uh[t][ck] = h2v; ul[t][ck] = l2v;
        }
    }

    int nwaves = gridDim.x * 4;
    int wid = blockIdx.x * 4 + (threadIdx.x >> 6);
    for (int tile = wid; tile < ntiles; tile += nwaves) {
        int v0 = tile * 16;
        const float4* a4 = (const float4*)(h1 + (size_t)(v0 + n16) * 64);
        float4 A0 = a4[2 * q], A1 = a4[2 * q + 1];
        float4 A2 = a4[8 + 2 * q], A3 = a4[8 + 2 * q + 1];
        float a[16] = {A0.x, A0.y, A0.z, A0.w, A1.x, A1.y, A1.z, A1.w,
                       A2.x, A2.y, A2.z, A2.w, A3.x, A3.y, A3.z, A3.w};
        short8 ah0, ah1, al0, al1;
#pragma unroll
        for (int j = 0; j < 8; ++j) {
            short h, l;
            splitT(a[j], h, l);      ah0[j] = h; al0[j] = l;
            splitT(a[8 + j], h, l);  ah1[j] = h; al1[j] = l;
        }
#pragma unroll
        for (int t = 0; t < 4; ++t) {
            f32x4 aa = (f32x4){bias[t], bias[t], bias[t], bias[t]};
            aa = __builtin_amdgcn_mfma_f32_16x16x32_bf16(ah0, th[t][0], aa, 0, 0, 0);
            aa = __builtin_amdgcn_mfma_f32_16x16x32_bf16(ah1, th[t][1], aa, 0, 0, 0);
            aa = __builtin_amdgcn_mfma_f32_16x16x32_bf16(al0, th[t][0], aa, 0, 0, 0);
            aa = __builtin_amdgcn_mfma_f32_16x16x32_bf16(al1, th[t][1], aa, 0, 0, 0);
            aa = __builtin_amdgcn_mfma_f32_16x16x32_bf16(ah0, tl[t][0], aa, 0, 0, 0);
            aa = __builtin_amdgcn_mfma_f32_16x16x32_bf16(ah1, tl[t][1], aa, 0, 0, 0);
            f32x4 bb = (f32x4){0.f, 0.f, 0.f, 0.f};
            bb = __builtin_amdgcn_mfma_f32_16x16x32_bf16(ah0, uh[t][0], bb, 0, 0, 0);
            bb = __builtin_amdgcn_mfma_f32_16x16x32_bf16(ah1, uh[t][1], bb, 0, 0, 0);
            bb = __builtin_amdgcn_mfma_f32_16x16x32_bf16(al0, uh[t][0], bb, 0, 0, 0);
            bb = __builtin_amdgcn_mfma_f32_16x16x32_bf16(al1, uh[t][1], bb, 0, 0, 0);
            bb = __builtin_amdgcn_mfma_f32_16x16x32_bf16(ah0, ul[t][0], bb, 0, 0, 0);
            bb = __builtin_amdgcn_mfma_f32_16x16x32_bf16(ah1, ul[t][1], bb, 0, 0, 0);
#pragma unroll
            for (int i = 0; i < 4; ++i) {
                size_t off = (size_t)(v0 + q * 4 + i) * 64 + t * 16 + n16;
                atab[off] = aa[i];
                btab[off] = bb[i];
            }
        }
    }
}

// persistent waves, one-node-ahead software pipeline; MFMA 16-edge tiles;
// segment max in registers; no atomics
__global__ __launch_bounds__(256) void k_edge_mlp(
        const int* __restrict__ ptr, const int* __restrict__ csr_row,
        const float* __restrict__ atab, const float* __restrict__ btab,
        const float* __restrict__ w2, const float* __restrict__ b2,
        float* __restrict__ hmax, int n) {
    int lane = threadIdx.x & 63;
    int n16 = lane & 15, q = lane >> 4;

    short8 bh[4][2], bl[4][2];
    float bias[4];
#pragma unroll
    for (int t = 0; t < 4; ++t) {
        bias[t] = b2[t * 16 + n16];
#pragma unroll
        for (int ck = 0; ck < 2; ++ck) {
            short8 hh, ll;
#pragma unroll
            for (int j = 0; j < 8; ++j) {
                float w = w2[(ck * 32 + q * 8 + j) * 64 + t * 16 + n16];
                unsigned short wh = f2bf(w);
                hh[j] = (short)wh;
                ll[j] = (short)f2bf(w - bf2f(wh));
            }
            bh[t][ck] = hh; bl[t][ck] = ll;
        }
    }

    int nwaves = gridDim.x * 4;
    int wid = blockIdx.x * 4 + (threadIdx.x >> 6);
    if (wid >= n) return;

    // pipeline prologue: node c, next node cn
    int c = wid;
    int start = ptr[c], end = ptr[c + 1];
    const float4* at4 = (const float4*)(atab + (size_t)c * 64);
    float4 A0 = at4[2 * q], A1 = at4[2 * q + 1];
    float4 A2 = at4[8 + 2 * q], A3 = at4[8 + 2 * q + 1];
    int cn = c + nwaves;
    int sn = 0, en = 0;
    if (cn < n) { sn = ptr[cn]; en = ptr[cn + 1]; }
    int rf = (start + n16 < end) ? csr_row[start + n16] : 0;

    while (true) {
        // capture current node into locals
        int cc = c, st = start, ed = end, rfirst = rf;
        float ak[16] = {A0.x, A0.y, A0.z, A0.w, A1.x, A1.y, A1.z, A1.w,
                        A2.x, A2.y, A2.z, A2.w, A3.x, A3.y, A3.z, A3.w};
        // shift pipeline and issue prefetches for the node after next / next
        c = cn; start = sn; end = en;
        bool more = (c < n);
        if (more) {
            cn = c + nwaves;
            if (cn < n) { sn = ptr[cn]; en = ptr[cn + 1]; }
            const float4* at4n = (const float4*)(atab + (size_t)c * 64);
            A0 = at4n[2 * q]; A1 = at4n[2 * q + 1];
            A2 = at4n[8 + 2 * q]; A3 = at4n[8 + 2 * q + 1];
            rf = (start + n16 < end) ? csr_row[start + n16] : 0;
        }

        float red[4] = {0.f, 0.f, 0.f, 0.f};   // init 0 folds relu + empty-segment-0
        int r = rfirst;
        for (int p0 = st; p0 < ed; p0 += 16) {
            int kt = ed - p0;
            int rcur = r;
            int pn = p0 + 16 + n16;
            if (pn < ed) r = csr_row[pn];     // next-tile index prefetch
            float u[16];
            if (p0 + n16 < ed) {
                const float4* bt4 = (const float4*)(btab + (size_t)rcur * 64);
                float4 B0 = bt4[2 * q], B1 = bt4[2 * q + 1];
                float4 B2 = bt4[8 + 2 * q], B3 = bt4[8 + 2 * q + 1];
                float bk[16] = {B0.x, B0.y, B0.z, B0.w, B1.x, B1.y, B1.z, B1.w,
                                B2.x, B2.y, B2.z, B2.w, B3.x, B3.y, B3.z, B3.w};
#pragma unroll
                for (int j = 0; j < 16; ++j) u[j] = fmaxf(ak[j] + bk[j], 0.f);
            } else {
#pragma unroll
                for (int j = 0; j < 16; ++j) u[j] = 0.f;
            }

            short8 ah0, ah1, al0, al1;
#pragma unroll
            for (int j = 0; j < 8; ++j) {
                short h, l;
                splitT(u[j], h, l);      ah0[j] = h; al0[j] = l;
                splitT(u[8 + j], h, l);  ah1[j] = h; al1[j] = l;
            }

#pragma unroll
            for (int t = 0; t < 4; ++t) {
                f32x4 acc = (f32x4){bias[t], bias[t], bias[t], bias[t]};
                acc = __builtin_amdgcn_mfma_f32_16x16x32_bf16(ah0, bh[t][0], acc, 0, 0, 0);
                acc = __builtin_amdgcn_mfma_f32_16x16x32_bf16(ah1, bh[t][1], acc, 0, 0, 0);
                acc = __builtin_amdgcn_mfma_f32_16x16x32_bf16(al0, bh[t][0], acc, 0, 0, 0);
                acc = __builtin_amdgcn_mfma_f32_16x16x32_bf16(al1, bh[t][1], acc, 0, 0, 0);
                acc = __builtin_amdgcn_mfma_f32_16x16x32_bf16(ah0, bl[t][0], acc, 0, 0, 0);
                acc = __builtin_amdgcn_mfma_f32_16x16x32_bf16(ah1, bl[t][1], acc, 0, 0, 0);
#pragma unroll
                for (int i = 0; i < 4; ++i) {
                    if (q * 4 + i < kt) red[t] = fmaxf(red[t], acc[i]);
                }
            }
        }
#pragma unroll
        for (int t = 0; t < 4; ++t) {
            red[t] = fmaxf(red[t], __shfl_xor(red[t], 16));
            red[t] = fmaxf(red[t], __shfl_xor(red[t], 32));
        }
        if (q == 0) {
#pragma unroll
            for (int t = 0; t < 4; ++t)
                hmax[(size_t)cc * 64 + t * 16 + n16] = red[t];
        }
        if (!more) break;
    }
}

// h2 = hmax @ Wg2 (64->16)
__global__ void k_gcn2_node(const float* __restrict__ hmax,
                            const float* __restrict__ wg,
                            float* __restrict__ h2, int n) {
    int t = blockIdx.x * blockDim.x + threadIdx.x;
    int v = t >> 4, j = t & 15;
    if (v >= n) return;
    float acc = 0.f;
#pragma unroll 8
    for (int d = 0; d < 64; ++d)
        acc = fmaf(hmax[v * 64 + d], wg[d * 16 + j], acc);
    h2[v * 16 + j] = acc;
}

// out[c] = bg + dv*(dv*h2[c] + sum_in dinv[r]*h2[r]) ; fully writes d_out
__global__ __launch_bounds__(256) void k_gcn2_gather(
        const int* __restrict__ ptr, const int* __restrict__ csr_row,
        const float* __restrict__ h2, const float* __restrict__ dinv,
        const float* __restrict__ bg, float* __restrict__ out, int n) {
    int wid = blockIdx.x * 4 + (threadIdx.x >> 6);
    if (wid >= n) return;
    int lane = threadIdx.x & 63;
    int f = lane & 15, es = lane >> 4;
    int c = wid;
    int start = ptr[c], end = ptr[c + 1];
    float s = 0.f;
    int p = start + es;
    int r = (p < end) ? csr_row[p] : 0;
    while (p < end) {
        int rcur = r;
        int pn = p + 4;
        if (pn < end) r = csr_row[pn];
        s = fmaf(dinv[rcur], h2[(size_t)rcur * 16 + f], s);
        p = pn;
    }
    s += __shfl_xor(s, 16);
    s += __shfl_xor(s, 32);
    if (es == 0) {
        float dv = dinv[c];
        out[c * 16 + f] = bg[f] + dv * (dv * h2[(size_t)c * 16 + f] + s);
    }
}

extern "C" void kernel_launch(void* const* d_in, const int* in_sizes, int n_in,
                              void* d_out, int out_size, void* d_ws, size_t ws_size,
                              hipStream_t stream) {
    const float* x   = (const float*)d_in[0];
    const int*   ei  = (const int*)d_in[1];
    const float* g1w = (const float*)d_in[2];
    const float* g1b = (const float*)d_in[3];
    const float* ew1 = (const float*)d_in[4];
    const float* eb1 = (const float*)d_in[5];
    const float* ew2 = (const float*)d_in[6];
    const float* eb2 = (const float*)d_in[7];
    const float* g2w = (const float*)d_in[8];
    const float* g2b = (const float*)d_in[9];
    float* out = (float*)d_out;
    float* ws  = (float*)d_ws;

    const int n = in_sizes[0] / 32;      // 50000
    const int E = in_sizes[1] / 2;       // 800000
    const int* row = ei;
    const int* col = ei + E;
    const int ntiles = (n + 15) / 16;    // 3125

    size_t npad    = ((size_t)n + 63) & ~(size_t)63;
    size_t o_deg   = 0;
    size_t o_ptr   = npad;               // n+1 (+pad)
    size_t o_cur   = o_ptr + npad + 64;
    size_t o_csr   = o_cur + npad;       // E ints
    size_t o_dinv  = o_csr + (size_t)E;
    size_t o_hmax  = o_dinv + npad;      // n*64 ; h1 overlays (dead before edge_mlp)
    size_t o_atab  = o_hmax + (size_t)n * 64;
    size_t o_btab  = o_atab + (size_t)n * 64;
    size_t o_agg   = o_btab + (size_t)n * 64;   // n*32 ; h2 (n*16) overlays front
    size_t o_part  = o_agg + (size_t)n * 32;    // 64 ints
    size_t o_offs  = o_part + 64;               // 64 ints

    int*   deg    = (int*)(ws + o_deg);
    int*   ptr    = (int*)(ws + o_ptr);
    int*   cursor = (int*)(ws + o_cur);
    int*   csr    = (int*)(ws + o_csr);
    float* dinv   = ws + o_dinv;
    float* hmax   = ws + o_hmax;
    float* h1     = ws + o_hmax;         // overlay
    float* atab   = ws + o_atab;
    float* btab   = ws + o_btab;
    float* agg    = ws + o_agg;
    float* h2     = ws + o_agg;          // overlay (agg dead after k_h1)
    int*   part   = (int*)(ws + o_part);
    int*   offs   = (int*)(ws + o_offs);

    int nblk = (n + 3) / 4;                      // wave-per-node kernels, 4 waves/block
    int tblk = (ntiles + 3) / 4;
    int scan_nb = (n + SCAN_CHUNK - 1) / SCAN_CHUNK;   // 25 <= 64

    k_zero4<<<(int)((npad / 4 + 255) / 256), 256, 0, stream>>>((float4*)deg, (int)(npad / 4));
    k_deg<<<(E + 255) / 256, 256, 0, stream>>>(col, deg, E);
    k_dinv<<<(n + 255) / 256, 256, 0, stream>>>(deg, dinv, n);
    k_scan_partial<<<scan_nb, 256, 0, stream>>>(deg, part, n);
    k_scan_offsets<<<1, 64, 0, stream>>>(part, offs, ptr, scan_nb, n, E);
    k_scan_final<<<scan_nb, 256, 0, stream>>>(deg, offs, ptr, cursor, n);
    k_fill<<<(E + 255) / 256, 256, 0, stream>>>(row, col, cursor, csr, E);
    k_gather32<<<nblk, 256, 0, stream>>>(ptr, csr, x, dinv, agg, n);
    k_h1<<<tblk, 256, 0, stream>>>(agg, g1w, g1b, h1, ntiles);
    k_w1tab<<<256, 256, 0, stream>>>(h1, ew1, eb1, atab, btab, ntiles);
    k_edge_mlp<<<2048, 256, 0, stream>>>(ptr, csr, atab, btab, ew2, eb2, hmax, n);
    k_gcn2_node<<<(n * 16 + 255) / 256, 256, 0, stream>>>(hmax, g2w, h2, n);
    k_gcn2_gather<<<nblk, 256, 0, stream>>>(ptr, csr, h2, dinv, g2b, out, n);
}

// Round 10
// 306.760 us; speedup vs baseline: 4.0170x; 1.0358x over previous
//
#include <hip/hip_runtime.h>

// CSR-gather pipeline (no float atomics):
//   deg -> multi-block scan(ptr, + fused dinv) -> fill csr_row (edges sorted by col)
//   gather32: agg[v] = dv*sum(dinv[r]*x[r]) + dv^2*x[v]      (irregular, 32 dims)
//   h1 (MFMA dense): h1 = tanh(agg @ Wg1 + gb)               (50k x 32 x 64)
//   w1tab (MFMA dense): atab = h1@(W1a-W1b)+b1 ; btab = h1@W1b
//   edge_mlp (persistent waves, MFMA, node-ahead prefetch, full/partial tile split):
//                         u = relu(atab[c]+btab[r]); m = u@W2+b2; hmax[c] = max (in regs)
//   gcn2: h2 = hmax@Wg2 ; out[c] = bg + dv*(dv*h2[c] + gather sum dinv[r]*h2[r])

typedef __attribute__((ext_vector_type(8))) short short8;
typedef __attribute__((ext_vector_type(4))) float f32x4;

#define SCAN_CHUNK 2048   // elements per scan block (256 thr x 8)

__device__ __forceinline__ unsigned short f2bf(float x) {   // RNE f32->bf16 (cold paths only)
    unsigned int u = __float_as_uint(x);
    return (unsigned short)((u + 0x7FFFu + ((u >> 16) & 1u)) >> 16);
}
__device__ __forceinline__ float bf2f(unsigned short h) {
    return __uint_as_float(((unsigned int)h) << 16);
}
// cheap truncation split: u ~= hi + lo with |err| ~ 2^-16 |u|
__device__ __forceinline__ void splitT(float u, short& hi, short& lo) {
    unsigned int ub = __float_as_uint(u);
    hi = (short)(ub >> 16);
    float r = u - __uint_as_float(ub & 0xFFFF0000u);
    lo = (short)(__float_as_uint(r) >> 16);
}

__global__ void k_zero4(float4* p, int n4) {
    int i = blockIdx.x * blockDim.x + threadIdx.x;
    if (i < n4) p[i] = make_float4(0.f, 0.f, 0.f, 0.f);
}

__global__ void k_deg(const int* __restrict__ col, int* __restrict__ deg, int E) {
    int e = blockIdx.x * blockDim.x + threadIdx.x;
    if (e < E) atomicAdd(&deg[col[e]], 1);
}

__global__ __launch_bounds__(256) void k_scan_partial(const int* __restrict__ deg,
                                                      int* __restrict__ part, int n) {
    __shared__ int wtot[4];
    int tid = threadIdx.x;
    int base = blockIdx.x * SCAN_CHUNK + tid * 8;
    int s = 0;
#pragma unroll
    for (int i = 0; i < 8; ++i) { int idx = base + i; if (idx < n) s += deg[idx]; }
    for (int off = 1; off < 64; off <<= 1) s += __shfl_xor(s, off);
    if ((tid & 63) == 0) wtot[tid >> 6] = s;
    __syncthreads();
    if (tid == 0) part[blockIdx.x] = wtot[0] + wtot[1] + wtot[2] + wtot[3];
}

__global__ __launch_bounds__(64) void k_scan_offsets(const int* __restrict__ part,
                                                     int* __restrict__ offs,
                                                     int* __restrict__ ptr, int nb, int n, int E) {
    int lane = threadIdx.x;
    int p = (lane < nb) ? part[lane] : 0;
    int s = p;
    for (int off = 1; off < 64; off <<= 1) {
        int t = __shfl_up(s, off, 64);
        if (lane >= off) s += t;
    }
    if (lane < nb) offs[lane] = s - p;     // exclusive
    if (lane == 0) ptr[n] = E;
}

// block-local exclusive scan + global offset -> ptr, cursor ; fused dinv
__global__ __launch_bounds__(256) void k_scan_final(const int* __restrict__ deg,
                                                    const int* __restrict__ offs,
                                                    int* __restrict__ ptr, int* __restrict__ cursor,
                                                    float* __restrict__ dinv, int n) {
    __shared__ int wtot[4];
    int tid = threadIdx.x;
    int lane = tid & 63, wv = tid >> 6;
    int base = blockIdx.x * SCAN_CHUNK + tid * 8;
    int d[8];
    int t8 = 0;
#pragma unroll
    for (int i = 0; i < 8; ++i) {
        int idx = base + i;
        d[i] = (idx < n) ? deg[idx] : 0;
        t8 += d[i];
    }
    int s = t8;
    for (int off = 1; off < 64; off <<= 1) {
        int t = __shfl_up(s, off, 64);
        if (lane >= off) s += t;
    }
    if (lane == 63) wtot[wv] = s;
    __syncthreads();
    int wpre = 0;
    for (int w = 0; w < 4; ++w) if (w < wv) wpre += wtot[w];
    int run = offs[blockIdx.x] + wpre + (s - t8);
#pragma unroll
    for (int i = 0; i < 8; ++i) {
        int idx = base + i;
        if (idx < n) {
            ptr[idx] = run; cursor[idx] = run;
            dinv[idx] = rsqrtf((float)(d[i] + 1));   // +1 self loop
            run += d[i];
        }
    }
}

__global__ void k_fill(const int* __restrict__ row, const int* __restrict__ col,
                       int* __restrict__ cursor, int* __restrict__ csr_row, int E) {
    int e = blockIdx.x * blockDim.x + threadIdx.x;
    if (e >= E) return;
    int pos = atomicAdd(&cursor[col[e]], 1);
    csr_row[pos] = row[e];
}

// irregular gather: agg[v] = dv*(sum dinv[r]*x[r]) + dv^2*x[v]
// 8 edge slots x 8 lanes x float4; one-ahead index prefetch
__global__ __launch_bounds__(256) void k_gather32(
        const int* __restrict__ ptr, const int* __restrict__ csr_row,
        const float* __restrict__ x, const float* __restrict__ dinv,
        float* __restrict__ agg, int n) {
    int wid = blockIdx.x * 4 + (threadIdx.x >> 6);
    if (wid >= n) return;
    int lane = threadIdx.x & 63;
    int f4 = lane & 7, slot = lane >> 3;
    int v = wid;
    int start = ptr[v], end = ptr[v + 1];
    const float4* x4 = (const float4*)x;
    float sx = 0.f, sy = 0.f, sz = 0.f, sw = 0.f;
    int p = start + slot;
    int r = (p < end) ? csr_row[p] : 0;
    while (p < end) {
        int rcur = r;
        int pn = p + 8;
        if (pn < end) r = csr_row[pn];
        float dr = dinv[rcur];
        float4 xv = x4[(size_t)rcur * 8 + f4];
        sx = fmaf(dr, xv.x, sx);
        sy = fmaf(dr, xv.y, sy);
        sz = fmaf(dr, xv.z, sz);
        sw = fmaf(dr, xv.w, sw);
        p = pn;
    }
#pragma unroll
    for (int off = 8; off < 64; off <<= 1) {
        sx += __shfl_xor(sx, off); sy += __shfl_xor(sy, off);
        sz += __shfl_xor(sz, off); sw += __shfl_xor(sw, off);
    }
    if (slot == 0) {
        float dv = dinv[v], d2 = dv * dv;
        float4 xv = x4[(size_t)v * 8 + f4];
        float4 o;
        o.x = dv * sx + d2 * xv.x;
        o.y = dv * sy + d2 * xv.y;
        o.z = dv * sz + d2 * xv.z;
        o.w = dv * sw + d2 * xv.w;
        ((float4*)agg)[(size_t)v * 8 + f4] = o;
    }
}

// dense MFMA: h1 = tanh(agg @ Wg1 + gb), tiles of 16 nodes, one wave/tile
__global__ __launch_bounds__(256) void k_h1(
        const float* __restrict__ agg, const float* __restrict__ gw,
        const float* __restrict__ gb, float* __restrict__ h1, int ntiles) {
    int wid = blockIdx.x * 4 + (threadIdx.x >> 6);
    if (wid >= ntiles) return;
    int lane = threadIdx.x & 63;
    int n16 = lane & 15, q = lane >> 4;

    short8 bh[4], bl[4];
    float bias[4];
#pragma unroll
    for (int t = 0; t < 4; ++t) {
        bias[t] = gb[t * 16 + n16];
        short8 hh, ll;
#pragma unroll
        for (int j = 0; j < 8; ++j) {
            float w = gw[(q * 8 + j) * 64 + t * 16 + n16];
            unsigned short wh = f2bf(w);
            hh[j] = (short)wh;
            ll[j] = (short)f2bf(w - bf2f(wh));
        }
        bh[t] = hh; bl[t] = ll;
    }

    int v0 = wid * 16;
    const float4* a4 = (const float4*)(agg + (size_t)(v0 + n16) * 32);
    float4 A0 = a4[2 * q], A1 = a4[2 * q + 1];
    float a[8] = {A0.x, A0.y, A0.z, A0.w, A1.x, A1.y, A1.z, A1.w};
    short8 ah, al;
#pragma unroll
    for (int j = 0; j < 8; ++j) { short h, l; splitT(a[j], h, l); ah[j] = h; al[j] = l; }

#pragma unroll
    for (int t = 0; t < 4; ++t) {
        f32x4 acc = (f32x4){bias[t], bias[t], bias[t], bias[t]};
        acc = __builtin_amdgcn_mfma_f32_16x16x32_bf16(ah, bh[t], acc, 0, 0, 0);
        acc = __builtin_amdgcn_mfma_f32_16x16x32_bf16(al, bh[t], acc, 0, 0, 0);
        acc = __builtin_amdgcn_mfma_f32_16x16x32_bf16(ah, bl[t], acc, 0, 0, 0);
#pragma unroll
        for (int i = 0; i < 4; ++i)
            h1[(size_t)(v0 + q * 4 + i) * 64 + t * 16 + n16] = tanhf(acc[i]);
    }
}

// dense MFMA: atab = h1@(W1a-W1b)+b1 ; btab = h1@W1b ; persistent waves
__global__ __launch_bounds__(256, 1) void k_w1tab(
        const float* __restrict__ h1, const float* __restrict__ w1,
        const float* __restrict__ b1,
        float* __restrict__ atab, float* __restrict__ btab, int ntiles) {
    int lane = threadIdx.x & 63;
    int n16 = lane & 15, q = lane >> 4;

    short8 th[4][2], tl[4][2], uh[4][2], ul[4][2];   // wt=W1a-W1b, wb=W1b frags
    float bias[4];
#pragma unroll
    for (int t = 0; t < 4; ++t) {
        bias[t] = b1[t * 16 + n16];
#pragma unroll
        for (int ck = 0; ck < 2; ++ck) {
            short8 h1v, l1v, h2v, l2v;
#pragma unroll
            for (int j = 0; j < 8; ++j) {
                int d = ck * 32 + q * 8 + j;
                float wbv = w1[(64 + d) * 64 + t * 16 + n16];
                float wtv = w1[d * 64 + t * 16 + n16] - wbv;
                unsigned short x1 = f2bf(wtv);
                h1v[j] = (short)x1; l1v[j] = (short)f2bf(wtv - bf2f(x1));
                unsigned short x2 = f2bf(wbv);
                h2v[j] = (short)x2; l2v[j] = (short)f2bf(wbv - bf2f(x2));
            }
            th[t][ck] = h1v; tl[t][ck] = l1v;
            uh[t][ck] = h2v; ul[t][ck] = l2v;
        }
    }

    int nwaves = gridDim.x * 4;
    int wid = blockIdx.x * 4 + (threadIdx.x >> 6);
    for (int tile = wid; tile < ntiles; tile += nwaves) {
        int v0 = tile * 16;
        const float4* a4 = (const float4*)(h1 + (size_t)(v0 + n16) * 64);
        float4 A0 = a4[2 * q], A1 = a4[2 * q + 1];
        float4 A2 = a4[8 + 2 * q], A3 = a4[8 + 2 * q + 1];
        float a[16] = {A0.x, A0.y, A0.z, A0.w, A1.x, A1.y, A1.z, A1.w,
                       A2.x, A2.y, A2.z, A2.w, A3.x, A3.y, A3.z, A3.w};
        short8 ah0, ah1, al0, al1;
#pragma unroll
        for (int j = 0; j < 8; ++j) {
            short h, l;
            splitT(a[j], h, l);      ah0[j] = h; al0[j] = l;
            splitT(a[8 + j], h, l);  ah1[j] = h; al1[j] = l;
        }
#pragma unroll
        for (int t = 0; t < 4; ++t) {
            f32x4 aa = (f32x4){bias[t], bias[t], bias[t], bias[t]};
            aa = __builtin_amdgcn_mfma_f32_16x16x32_bf16(ah0, th[t][0], aa, 0, 0, 0);
            aa = __builtin_amdgcn_mfma_f32_16x16x32_bf16(ah1, th[t][1], aa, 0, 0, 0);
            aa = __builtin_amdgcn_mfma_f32_16x16x32_bf16(al0, th[t][0], aa, 0, 0, 0);
            aa = __builtin_amdgcn_mfma_f32_16x16x32_bf16(al1, th[t][1], aa, 0, 0, 0);
            aa = __builtin_amdgcn_mfma_f32_16x16x32_bf16(ah0, tl[t][0], aa, 0, 0, 0);
            aa = __builtin_amdgcn_mfma_f32_16x16x32_bf16(ah1, tl[t][1], aa, 0, 0, 0);
            f32x4 bb = (f32x4){0.f, 0.f, 0.f, 0.f};
            bb = __builtin_amdgcn_mfma_f32_16x16x32_bf16(ah0, uh[t][0], bb, 0, 0, 0);
            bb = __builtin_amdgcn_mfma_f32_16x16x32_bf16(ah1, uh[t][1], bb, 0, 0, 0);
            bb = __builtin_amdgcn_mfma_f32_16x16x32_bf16(al0, uh[t][0], bb, 0, 0, 0);
            bb = __builtin_amdgcn_mfma_f32_16x16x32_bf16(al1, uh[t][1], bb, 0, 0, 0);
            bb = __builtin_amdgcn_mfma_f32_16x16x32_bf16(ah0, ul[t][0], bb, 0, 0, 0);
            bb = __builtin_amdgcn_mfma_f32_16x16x32_bf16(ah1, ul[t][1], bb, 0, 0, 0);
#pragma unroll
            for (int i = 0; i < 4; ++i) {
                size_t off = (size_t)(v0 + q * 4 + i) * 64 + t * 16 + n16;
                atab[off] = aa[i];
                btab[off] = bb[i];
            }
        }
    }
}

// persistent waves, one-node-ahead pipeline; MFMA 16-edge tiles;
// full-tile fast path + masked partial epilogue; segment max in regs; no atomics
__global__ __launch_bounds__(256) void k_edge_mlp(
        const int* __restrict__ ptr, const int* __restrict__ csr_row,
        const float* __restrict__ atab, const float* __restrict__ btab,
        const float* __restrict__ w2, const float* __restrict__ b2,
        float* __restrict__ hmax, int n) {
    int lane = threadIdx.x & 63;
    int n16 = lane & 15, q = lane >> 4;

    short8 bh[4][2], bl[4][2];
    float bias[4];
#pragma unroll
    for (int t = 0; t < 4; ++t) {
        bias[t] = b2[t * 16 + n16];
#pragma unroll
        for (int ck = 0; ck < 2; ++ck) {
            short8 hh, ll;
#pragma unroll
            for (int j = 0; j < 8; ++j) {
                float w = w2[(ck * 32 + q * 8 + j) * 64 + t * 16 + n16];
                unsigned short wh = f2bf(w);
                hh[j] = (short)wh;
                ll[j] = (short)f2bf(w - bf2f(wh));
            }
            bh[t][ck] = hh; bl[t][ck] = ll;
        }
    }

    int nwaves = gridDim.x * 4;
    int wid = blockIdx.x * 4 + (threadIdx.x >> 6);
    if (wid >= n) return;

    int c = wid;
    int start = ptr[c], end = ptr[c + 1];
    const float4* at4 = (const float4*)(atab + (size_t)c * 64);
    float4 A0 = at4[2 * q], A1 = at4[2 * q + 1];
    float4 A2 = at4[8 + 2 * q], A3 = at4[8 + 2 * q + 1];
    int cn = c + nwaves;
    int sn = 0, en = 0;
    if (cn < n) { sn = ptr[cn]; en = ptr[cn + 1]; }
    int rf = (start + n16 < end) ? csr_row[start + n16] : 0;

    while (true) {
        int cc = c, st = start, ed = end, rfirst = rf;
        float ak[16] = {A0.x, A0.y, A0.z, A0.w, A1.x, A1.y, A1.z, A1.w,
                        A2.x, A2.y, A2.z, A2.w, A3.x, A3.y, A3.z, A3.w};
        c = cn; start = sn; end = en;
        bool more = (c < n);
        if (more) {
            cn = c + nwaves;
            if (cn < n) { sn = ptr[cn]; en = ptr[cn + 1]; }
            const float4* at4n = (const float4*)(atab + (size_t)c * 64);
            A0 = at4n[2 * q]; A1 = at4n[2 * q + 1];
            A2 = at4n[8 + 2 * q]; A3 = at4n[8 + 2 * q + 1];
            rf = (start + n16 < end) ? csr_row[start + n16] : 0;
        }

        float red[4] = {0.f, 0.f, 0.f, 0.f};   // init 0 folds relu + empty-segment-0
        int r = rfirst;
        int p0 = st;
        int nfull = (ed - st) >> 4;
        // full tiles: no masking, unconditional loads
        for (int ft = 0; ft < nfull; ++ft, p0 += 16) {
            int rcur = r;
            int pn = p0 + 16 + n16;
            if (pn < ed) r = csr_row[pn];
            const float4* bt4 = (const float4*)(btab + (size_t)rcur * 64);
            float4 B0 = bt4[2 * q], B1 = bt4[2 * q + 1];
            float4 B2 = bt4[8 + 2 * q], B3 = bt4[8 + 2 * q + 1];
            float u[16];
            u[0]  = fmaxf(ak[0]  + B0.x, 0.f); u[1]  = fmaxf(ak[1]  + B0.y, 0.f);
            u[2]  = fmaxf(ak[2]  + B0.z, 0.f); u[3]  = fmaxf(ak[3]  + B0.w, 0.f);
            u[4]  = fmaxf(ak[4]  + B1.x, 0.f); u[5]  = fmaxf(ak[5]  + B1.y, 0.f);
            u[6]  = fmaxf(ak[6]  + B1.z, 0.f); u[7]  = fmaxf(ak[7]  + B1.w, 0.f);
            u[8]  = fmaxf(ak[8]  + B2.x, 0.f); u[9]  = fmaxf(ak[9]  + B2.y, 0.f);
            u[10] = fmaxf(ak[10] + B2.z, 0.f); u[11] = fmaxf(ak[11] + B2.w, 0.f);
            u[12] = fmaxf(ak[12] + B3.x, 0.f); u[13] = fmaxf(ak[13] + B3.y, 0.f);
            u[14] = fmaxf(ak[14] + B3.z, 0.f); u[15] = fmaxf(ak[15] + B3.w, 0.f);

            short8 ah0, ah1, al0, al1;
#pragma unroll
            for (int j = 0; j < 8; ++j) {
                short h, l;
                splitT(u[j], h, l);      ah0[j] = h; al0[j] = l;
                splitT(u[8 + j], h, l);  ah1[j] = h; al1[j] = l;
            }
#pragma unroll
            for (int t = 0; t < 4; ++t) {
                f32x4 acc = (f32x4){bias[t], bias[t], bias[t], bias[t]};
                acc = __builtin_amdgcn_mfma_f32_16x16x32_bf16(ah0, bh[t][0], acc, 0, 0, 0);
                acc = __builtin_amdgcn_mfma_f32_16x16x32_bf16(ah1, bh[t][1], acc, 0, 0, 0);
                acc = __builtin_amdgcn_mfma_f32_16x16x32_bf16(al0, bh[t][0], acc, 0, 0, 0);
                acc = __builtin_amdgcn_mfma_f32_16x16x32_bf16(al1, bh[t][1], acc, 0, 0, 0);
                acc = __builtin_amdgcn_mfma_f32_16x16x32_bf16(ah0, bl[t][0], acc, 0, 0, 0);
                acc = __builtin_amdgcn_mfma_f32_16x16x32_bf16(ah1, bl[t][1], acc, 0, 0, 0);
                red[t] = fmaxf(red[t], fmaxf(fmaxf(acc[0], acc[1]), fmaxf(acc[2], acc[3])));
            }
        }
        // partial epilogue tile
        int rem = ed - p0;
        if (rem > 0) {
            float u[16];
            if (n16 < rem) {
                const float4* bt4 = (const float4*)(btab + (size_t)r * 64);
                float4 B0 = bt4[2 * q], B1 = bt4[2 * q + 1];
                float4 B2 = bt4[8 + 2 * q], B3 = bt4[8 + 2 * q + 1];
                float bk[16] = {B0.x, B0.y, B0.z, B0.w, B1.x, B1.y, B1.z, B1.w,
                                B2.x, B2.y, B2.z, B2.w, B3.x, B3.y, B3.z, B3.w};
#pragma unroll
                for (int j = 0; j < 16; ++j) u[j] = fmaxf(ak[j] + bk[j], 0.f);
            } else {
#pragma unroll
                for (int j = 0; j < 16; ++j) u[j] = 0.f;
            }
            short8 ah0, ah1, al0, al1;
#pragma unroll
            for (int j = 0; j < 8; ++j) {
                short h, l;
                splitT(u[j], h, l);      ah0[j] = h; al0[j] = l;
                splitT(u[8 + j], h, l);  ah1[j] = h; al1[j] = l;
            }
#pragma unroll
            for (int t = 0; t < 4; ++t) {
                f32x4 acc = (f32x4){bias[t], bias[t], bias[t], bias[t]};
                acc = __builtin_amdgcn_mfma_f32_16x16x32_bf16(ah0, bh[t][0], acc, 0, 0, 0);
                acc = __builtin_amdgcn_mfma_f32_16x16x32_bf16(ah1, bh[t][1], acc, 0, 0, 0);
                acc = __builtin_amdgcn_mfma_f32_16x16x32_bf16(al0, bh[t][0], acc, 0, 0, 0);
                acc = __builtin_amdgcn_mfma_f32_16x16x32_bf16(al1, bh[t][1], acc, 0, 0, 0);
                acc = __builtin_amdgcn_mfma_f32_16x16x32_bf16(ah0, bl[t][0], acc, 0, 0, 0);
                acc = __builtin_amdgcn_mfma_f32_16x16x32_bf16(ah1, bl[t][1], acc, 0, 0, 0);
#pragma unroll
                for (int i = 0; i < 4; ++i)
                    if (q * 4 + i < rem) red[t] = fmaxf(red[t], acc[i]);
            }
        }
#pragma unroll
        for (int t = 0; t < 4; ++t) {
            red[t] = fmaxf(red[t], __shfl_xor(red[t], 16));
            red[t] = fmaxf(red[t], __shfl_xor(red[t], 32));
        }
        if (q == 0) {
#pragma unroll
            for (int t = 0; t < 4; ++t)
                hmax[(size_t)cc * 64 + t * 16 + n16] = red[t];
        }
        if (!more) break;
    }
}

// h2 = hmax @ Wg2 (64->16)
__global__ void k_gcn2_node(const float* __restrict__ hmax,
                            const float* __restrict__ wg,
                            float* __restrict__ h2, int n) {
    int t = blockIdx.x * blockDim.x + threadIdx.x;
    int v = t >> 4, j = t & 15;
    if (v >= n) return;
    float acc = 0.f;
#pragma unroll 8
    for (int d = 0; d < 64; ++d)
        acc = fmaf(hmax[v * 64 + d], wg[d * 16 + j], acc);
    h2[v * 16 + j] = acc;
}

// out[c] = bg + dv*(dv*h2[c] + sum_in dinv[r]*h2[r]) ; fully writes d_out
// 8 edge slots x 8 lanes x float2
__global__ __launch_bounds__(256) void k_gcn2_gather(
        const int* __restrict__ ptr, const int* __restrict__ csr_row,
        const float* __restrict__ h2, const float* __restrict__ dinv,
        const float* __restrict__ bg, float* __restrict__ out, int n) {
    int wid = blockIdx.x * 4 + (threadIdx.x >> 6);
    if (wid >= n) return;
    int lane = threadIdx.x & 63;
    int f2 = lane & 7, slot = lane >> 3;
    int c = wid;
    int start = ptr[c], end = ptr[c + 1];
    const float2* h22 = (const float2*)h2;
    float sx = 0.f, sy = 0.f;
    int p = start + slot;
    int r = (p < end) ? csr_row[p] : 0;
    while (p < end) {
        int rcur = r;
        int pn = p + 8;
        if (pn < end) r = csr_row[pn];
        float dr = dinv[rcur];
        float2 hv = h22[(size_t)rcur * 8 + f2];
        sx = fmaf(dr, hv.x, sx);
        sy = fmaf(dr, hv.y, sy);
        p = pn;
    }
#pragma unroll
    for (int off = 8; off < 64; off <<= 1) {
        sx += __shfl_xor(sx, off);
        sy += __shfl_xor(sy, off);
    }
    if (slot == 0) {
        float dv = dinv[c];
        float2 hv = h22[(size_t)c * 8 + f2];
        float2 o;
        o.x = bg[2 * f2]     + dv * (dv * hv.x + sx);
        o.y = bg[2 * f2 + 1] + dv * (dv * hv.y + sy);
        ((float2*)out)[(size_t)c * 8 + f2] = o;
    }
}

extern "C" void kernel_launch(void* const* d_in, const int* in_sizes, int n_in,
                              void* d_out, int out_size, void* d_ws, size_t ws_size,
                              hipStream_t stream) {
    const float* x   = (const float*)d_in[0];
    const int*   ei  = (const int*)d_in[1];
    const float* g1w = (const float*)d_in[2];
    const float* g1b = (const float*)d_in[3];
    const float* ew1 = (const float*)d_in[4];
    const float* eb1 = (const float*)d_in[5];
    const float* ew2 = (const float*)d_in[6];
    const float* eb2 = (const float*)d_in[7];
    const float* g2w = (const float*)d_in[8];
    const float* g2b = (const float*)d_in[9];
    float* out = (float*)d_out;
    float* ws  = (float*)d_ws;

    const int n = in_sizes[0] / 32;      // 50000
    const int E = in_sizes[1] / 2;       // 800000
    const int* row = ei;
    const int* col = ei + E;
    const int ntiles = (n + 15) / 16;    // 3125

    size_t npad    = ((size_t)n + 63) & ~(size_t)63;
    size_t o_deg   = 0;
    size_t o_ptr   = npad;               // n+1 (+pad)
    size_t o_cur   = o_ptr + npad + 64;
    size_t o_csr   = o_cur + npad;       // E ints
    size_t o_dinv  = o_csr + (size_t)E;
    size_t o_hmax  = o_dinv + npad;      // n*64 ; h1 overlays (dead before edge_mlp)
    size_t o_atab  = o_hmax + (size_t)n * 64;
    size_t o_btab  = o_atab + (size_t)n * 64;
    size_t o_agg   = o_btab + (size_t)n * 64;   // n*32 ; h2 (n*16) overlays front
    size_t o_part  = o_agg + (size_t)n * 32;    // 64 ints
    size_t o_offs  = o_part + 64;               // 64 ints

    int*   deg    = (int*)(ws + o_deg);
    int*   ptr    = (int*)(ws + o_ptr);
    int*   cursor = (int*)(ws + o_cur);
    int*   csr    = (int*)(ws + o_csr);
    float* dinv   = ws + o_dinv;
    float* hmax   = ws + o_hmax;
    float* h1     = ws + o_hmax;         // overlay
    float* atab   = ws + o_atab;
    float* btab   = ws + o_btab;
    float* agg    = ws + o_agg;
    float* h2     = ws + o_agg;          // overlay (agg dead after k_h1)
    int*   part   = (int*)(ws + o_part);
    int*   offs   = (int*)(ws + o_offs);

    int nblk = (n + 3) / 4;                      // wave-per-node kernels, 4 waves/block
    int tblk = (ntiles + 3) / 4;
    int scan_nb = (n + SCAN_CHUNK - 1) / SCAN_CHUNK;   // 25 <= 64

    k_zero4<<<(int)((npad / 4 + 255) / 256), 256, 0, stream>>>((float4*)deg, (int)(npad / 4));
    k_deg<<<(E + 255) / 256, 256, 0, stream>>>(col, deg, E);
    k_scan_partial<<<scan_nb, 256, 0, stream>>>(deg, part, n);
    k_scan_offsets<<<1, 64, 0, stream>>>(part, offs, ptr, scan_nb, n, E);
    k_scan_final<<<scan_nb, 256, 0, stream>>>(deg, offs, ptr, cursor, dinv, n);
    k_fill<<<(E + 255) / 256, 256, 0, stream>>>(row, col, cursor, csr, E);
    k_gather32<<<nblk, 256, 0, stream>>>(ptr, csr, x, dinv, agg, n);
    k_h1<<<tblk, 256, 0, stream>>>(agg, g1w, g1b, h1, ntiles);
    k_w1tab<<<256, 256, 0, stream>>>(h1, ew1, eb1, atab, btab, ntiles);
    k_edge_mlp<<<2048, 256, 0, stream>>>(ptr, csr, atab, btab, ew2, eb2, hmax, n);
    k_gcn2_node<<<(n * 16 + 255) / 256, 256, 0, stream>>>(hmax, g2w, h2, n);
    k_gcn2_gather<<<nblk, 256, 0, stream>>>(ptr, csr, h2, dinv, g2b, out, n);
}

// Round 11
// 280.719 us; speedup vs baseline: 4.3897x; 1.0928x over previous
//
#include <hip/hip_runtime.h>

// CSR-gather pipeline (no float atomics):
//   deg -> multi-block scan(ptr, + fused dinv) -> fill csr_row (edges sorted by col)
//   gather32: agg[v] = dv*sum(dinv[r]*x[r]) + dv^2*x[v]      (irregular, 32 dims)
//   h1 (MFMA dense, bf16 3-term ~fp32): h1 = tanh(agg @ Wg1 + gb)
//   w1tab (MFMA dense, bf16 3-term): atab/btab = h1@{W1a-W1b,W1b} stored as FP16 (RNE)
//   edge_mlp (persistent waves, fp16 single-term MFMA): u = relu(atab[c]+btab[r]) in
//             packed fp16; m = u@W2+b2 (fp32 acc); hmax[c] = max (in regs)
//   gcn2 (fp32): h2 = hmax@Wg2 ; out[c] = bg + dv*(dv*h2[c] + gather sum dinv[r]*h2[r])

typedef __attribute__((ext_vector_type(8))) short short8;
typedef __attribute__((ext_vector_type(4))) float f32x4;
typedef __attribute__((ext_vector_type(8))) _Float16 f16x8;

#define SCAN_CHUNK 2048   // elements per scan block (256 thr x 8)

__device__ __forceinline__ unsigned short f2bf(float x) {   // RNE f32->bf16 (cold paths only)
    unsigned int u = __float_as_uint(x);
    return (unsigned short)((u + 0x7FFFu + ((u >> 16) & 1u)) >> 16);
}
__device__ __forceinline__ float bf2f(unsigned short h) {
    return __uint_as_float(((unsigned int)h) << 16);
}
// cheap truncation split: u ~= hi + lo with |err| ~ 2^-16 |u|
__device__ __forceinline__ void splitT(float u, short& hi, short& lo) {
    unsigned int ub = __float_as_uint(u);
    hi = (short)(ub >> 16);
    float r = u - __uint_as_float(ub & 0xFFFF0000u);
    lo = (short)(__float_as_uint(r) >> 16);
}
__device__ __forceinline__ f16x8 relu8(f16x8 v) {
    f16x8 z = {0, 0, 0, 0, 0, 0, 0, 0};
#if __has_builtin(__builtin_elementwise_max)
    return __builtin_elementwise_max(v, z);
#else
    f16x8 o;
#pragma unroll
    for (int j = 0; j < 8; ++j) o[j] = v[j] > (_Float16)0 ? v[j] : (_Float16)0;
    return o;
#endif
}

__global__ void k_zero4(float4* p, int n4) {
    int i = blockIdx.x * blockDim.x + threadIdx.x;
    if (i < n4) p[i] = make_float4(0.f, 0.f, 0.f, 0.f);
}

__global__ void k_deg(const int* __restrict__ col, int* __restrict__ deg, int E) {
    int e = blockIdx.x * blockDim.x + threadIdx.x;
    if (e < E) atomicAdd(&deg[col[e]], 1);
}

__global__ __launch_bounds__(256) void k_scan_partial(const int* __restrict__ deg,
                                                      int* __restrict__ part, int n) {
    __shared__ int wtot[4];
    int tid = threadIdx.x;
    int base = blockIdx.x * SCAN_CHUNK + tid * 8;
    int s = 0;
#pragma unroll
    for (int i = 0; i < 8; ++i) { int idx = base + i; if (idx < n) s += deg[idx]; }
    for (int off = 1; off < 64; off <<= 1) s += __shfl_xor(s, off);
    if ((tid & 63) == 0) wtot[tid >> 6] = s;
    __syncthreads();
    if (tid == 0) part[blockIdx.x] = wtot[0] + wtot[1] + wtot[2] + wtot[3];
}

__global__ __launch_bounds__(64) void k_scan_offsets(const int* __restrict__ part,
                                                     int* __restrict__ offs,
                                                     int* __restrict__ ptr, int nb, int n, int E) {
    int lane = threadIdx.x;
    int p = (lane < nb) ? part[lane] : 0;
    int s = p;
    for (int off = 1; off < 64; off <<= 1) {
        int t = __shfl_up(s, off, 64);
        if (lane >= off) s += t;
    }
    if (lane < nb) offs[lane] = s - p;     // exclusive
    if (lane == 0) ptr[n] = E;
}

// block-local exclusive scan + global offset -> ptr, cursor ; fused dinv
__global__ __launch_bounds__(256) void k_scan_final(const int* __restrict__ deg,
                                                    const int* __restrict__ offs,
                                                    int* __restrict__ ptr, int* __restrict__ cursor,
                                                    float* __restrict__ dinv, int n) {
    __shared__ int wtot[4];
    int tid = threadIdx.x;
    int lane = tid & 63, wv = tid >> 6;
    int base = blockIdx.x * SCAN_CHUNK + tid * 8;
    int d[8];
    int t8 = 0;
#pragma unroll
    for (int i = 0; i < 8; ++i) {
        int idx = base + i;
        d[i] = (idx < n) ? deg[idx] : 0;
        t8 += d[i];
    }
    int s = t8;
    for (int off = 1; off < 64; off <<= 1) {
        int t = __shfl_up(s, off, 64);
        if (lane >= off) s += t;
    }
    if (lane == 63) wtot[wv] = s;
    __syncthreads();
    int wpre = 0;
    for (int w = 0; w < 4; ++w) if (w < wv) wpre += wtot[w];
    int run = offs[blockIdx.x] + wpre + (s - t8);
#pragma unroll
    for (int i = 0; i < 8; ++i) {
        int idx = base + i;
        if (idx < n) {
            ptr[idx] = run; cursor[idx] = run;
            dinv[idx] = rsqrtf((float)(d[i] + 1));   // +1 self loop
            run += d[i];
        }
    }
}

__global__ void k_fill(const int* __restrict__ row, const int* __restrict__ col,
                       int* __restrict__ cursor, int* __restrict__ csr_row, int E) {
    int e = blockIdx.x * blockDim.x + threadIdx.x;
    if (e >= E) return;
    int pos = atomicAdd(&cursor[col[e]], 1);
    csr_row[pos] = row[e];
}

// irregular gather: agg[v] = dv*(sum dinv[r]*x[r]) + dv^2*x[v]
// 8 edge slots x 8 lanes x float4; one-ahead index prefetch
__global__ __launch_bounds__(256) void k_gather32(
        const int* __restrict__ ptr, const int* __restrict__ csr_row,
        const float* __restrict__ x, const float* __restrict__ dinv,
        float* __restrict__ agg, int n) {
    int wid = blockIdx.x * 4 + (threadIdx.x >> 6);
    if (wid >= n) return;
    int lane = threadIdx.x & 63;
    int f4 = lane & 7, slot = lane >> 3;
    int v = wid;
    int start = ptr[v], end = ptr[v + 1];
    const float4* x4 = (const float4*)x;
    float sx = 0.f, sy = 0.f, sz = 0.f, sw = 0.f;
    int p = start + slot;
    int r = (p < end) ? csr_row[p] : 0;
    while (p < end) {
        int rcur = r;
        int pn = p + 8;
        if (pn < end) r = csr_row[pn];
        float dr = dinv[rcur];
        float4 xv = x4[(size_t)rcur * 8 + f4];
        sx = fmaf(dr, xv.x, sx);
        sy = fmaf(dr, xv.y, sy);
        sz = fmaf(dr, xv.z, sz);
        sw = fmaf(dr, xv.w, sw);
        p = pn;
    }
#pragma unroll
    for (int off = 8; off < 64; off <<= 1) {
        sx += __shfl_xor(sx, off); sy += __shfl_xor(sy, off);
        sz += __shfl_xor(sz, off); sw += __shfl_xor(sw, off);
    }
    if (slot == 0) {
        float dv = dinv[v], d2 = dv * dv;
        float4 xv = x4[(size_t)v * 8 + f4];
        float4 o;
        o.x = dv * sx + d2 * xv.x;
        o.y = dv * sy + d2 * xv.y;
        o.z = dv * sz + d2 * xv.z;
        o.w = dv * sw + d2 * xv.w;
        ((float4*)agg)[(size_t)v * 8 + f4] = o;
    }
}

// dense MFMA: h1 = tanh(agg @ Wg1 + gb), tiles of 16 nodes, one wave/tile
__global__ __launch_bounds__(256) void k_h1(
        const float* __restrict__ agg, const float* __restrict__ gw,
        const float* __restrict__ gb, float* __restrict__ h1, int ntiles) {
    int wid = blockIdx.x * 4 + (threadIdx.x >> 6);
    if (wid >= ntiles) return;
    int lane = threadIdx.x & 63;
    int n16 = lane & 15, q = lane >> 4;

    short8 bh[4], bl[4];
    float bias[4];
#pragma unroll
    for (int t = 0; t < 4; ++t) {
        bias[t] = gb[t * 16 + n16];
        short8 hh, ll;
#pragma unroll
        for (int j = 0; j < 8; ++j) {
            float w = gw[(q * 8 + j) * 64 + t * 16 + n16];
            unsigned short wh = f2bf(w);
            hh[j] = (short)wh;
            ll[j] = (short)f2bf(w - bf2f(wh));
        }
        bh[t] = hh; bl[t] = ll;
    }

    int v0 = wid * 16;
    const float4* a4 = (const float4*)(agg + (size_t)(v0 + n16) * 32);
    float4 A0 = a4[2 * q], A1 = a4[2 * q + 1];
    float a[8] = {A0.x, A0.y, A0.z, A0.w, A1.x, A1.y, A1.z, A1.w};
    short8 ah, al;
#pragma unroll
    for (int j = 0; j < 8; ++j) { short h, l; splitT(a[j], h, l); ah[j] = h; al[j] = l; }

#pragma unroll
    for (int t = 0; t < 4; ++t) {
        f32x4 acc = (f32x4){bias[t], bias[t], bias[t], bias[t]};
        acc = __builtin_amdgcn_mfma_f32_16x16x32_bf16(ah, bh[t], acc, 0, 0, 0);
        acc = __builtin_amdgcn_mfma_f32_16x16x32_bf16(al, bh[t], acc, 0, 0, 0);
        acc = __builtin_amdgcn_mfma_f32_16x16x32_bf16(ah, bl[t], acc, 0, 0, 0);
#pragma unroll
        for (int i = 0; i < 4; ++i)
            h1[(size_t)(v0 + q * 4 + i) * 64 + t * 16 + n16] = tanhf(acc[i]);
    }
}

// dense MFMA (bf16 3-term ~fp32 internally): atab = h1@(W1a-W1b)+b1 ; btab = h1@W1b
// outputs stored as FP16 (RNE) for the fp16 edge MLP
__global__ __launch_bounds__(256, 1) void k_w1tab(
        const float* __restrict__ h1, const float* __restrict__ w1,
        const float* __restrict__ b1,
        _Float16* __restrict__ atab, _Float16* __restrict__ btab, int ntiles) {
    int lane = threadIdx.x & 63;
    int n16 = lane & 15, q = lane >> 4;

    short8 th[4][2], tl[4][2], uh[4][2], ul[4][2];   // wt=W1a-W1b, wb=W1b frags
    float bias[4];
#pragma unroll
    for (int t = 0; t < 4; ++t) {
        bias[t] = b1[t * 16 + n16];
#pragma unroll
        for (int ck = 0; ck < 2; ++ck) {
            short8 h1v, l1v, h2v, l2v;
#pragma unroll
            for (int j = 0; j < 8; ++j) {
                int d = ck * 32 + q * 8 + j;
                float wbv = w1[(64 + d) * 64 + t * 16 + n16];
                float wtv = w1[d * 64 + t * 16 + n16] - wbv;
                unsigned short x1 = f2bf(wtv);
                h1v[j] = (short)x1; l1v[j] = (short)f2bf(wtv - bf2f(x1));
                unsigned short x2 = f2bf(wbv);
                h2v[j] = (short)x2; l2v[j] = (short)f2bf(wbv - bf2f(x2));
            }
            th[t][ck] = h1v; tl[t][ck] = l1v;
            uh[t][ck] = h2v; ul[t][ck] = l2v;
        }
    }

    int nwaves = gridDim.x * 4;
    int wid = blockIdx.x * 4 + (threadIdx.x >> 6);
    for (int tile = wid; tile < ntiles; tile += nwaves) {
        int v0 = tile * 16;
        const float4* a4 = (const float4*)(h1 + (size_t)(v0 + n16) * 64);
        float4 A0 = a4[2 * q], A1 = a4[2 * q + 1];
        float4 A2 = a4[8 + 2 * q], A3 = a4[8 + 2 * q + 1];
        float a[16] = {A0.x, A0.y, A0.z, A0.w, A1.x, A1.y, A1.z, A1.w,
                       A2.x, A2.y, A2.z, A2.w, A3.x, A3.y, A3.z, A3.w};
        short8 ah0, ah1, al0, al1;
#pragma unroll
        for (int j = 0; j < 8; ++j) {
            short h, l;
            splitT(a[j], h, l);      ah0[j] = h; al0[j] = l;
            splitT(a[8 + j], h, l);  ah1[j] = h; al1[j] = l;
        }
#pragma unroll
        for (int t = 0; t < 4; ++t) {
            f32x4 aa = (f32x4){bias[t], bias[t], bias[t], bias[t]};
            aa = __builtin_amdgcn_mfma_f32_16x16x32_bf16(ah0, th[t][0], aa, 0, 0, 0);
            aa = __builtin_amdgcn_mfma_f32_16x16x32_bf16(ah1, th[t][1], aa, 0, 0, 0);
            aa = __builtin_amdgcn_mfma_f32_16x16x32_bf16(al0, th[t][0], aa, 0, 0, 0);
            aa = __builtin_amdgcn_mfma_f32_16x16x32_bf16(al1, th[t][1], aa, 0, 0, 0);
            aa = __builtin_amdgcn_mfma_f32_16x16x32_bf16(ah0, tl[t][0], aa, 0, 0, 0);
            aa = __builtin_amdgcn_mfma_f32_16x16x32_bf16(ah1, tl[t][1], aa, 0, 0, 0);
            f32x4 bb = (f32x4){0.f, 0.f, 0.f, 0.f};
            bb = __builtin_amdgcn_mfma_f32_16x16x32_bf16(ah0, uh[t][0], bb, 0, 0, 0);
            bb = __builtin_amdgcn_mfma_f32_16x16x32_bf16(ah1, uh[t][1], bb, 0, 0, 0);
            bb = __builtin_amdgcn_mfma_f32_16x16x32_bf16(al0, uh[t][0], bb, 0, 0, 0);
            bb = __builtin_amdgcn_mfma_f32_16x16x32_bf16(al1, uh[t][1], bb, 0, 0, 0);
            bb = __builtin_amdgcn_mfma_f32_16x16x32_bf16(ah0, ul[t][0], bb, 0, 0, 0);
            bb = __builtin_amdgcn_mfma_f32_16x16x32_bf16(ah1, ul[t][1], bb, 0, 0, 0);
#pragma unroll
            for (int i = 0; i < 4; ++i) {
                size_t off = (size_t)(v0 + q * 4 + i) * 64 + t * 16 + n16;
                atab[off] = (_Float16)aa[i];
                btab[off] = (_Float16)bb[i];
            }
        }
    }
}

// persistent waves, one-node-ahead pipeline; fp16 single-term MFMA (fp32 acc);
// u built in packed fp16; full-tile fast path + masked epilogue; no atomics
__global__ __launch_bounds__(256) void k_edge_mlp(
        const int* __restrict__ ptr, const int* __restrict__ csr_row,
        const _Float16* __restrict__ atab, const _Float16* __restrict__ btab,
        const float* __restrict__ w2, const float* __restrict__ b2,
        float* __restrict__ hmax, int n) {
    int lane = threadIdx.x & 63;
    int n16 = lane & 15, q = lane >> 4;

    f16x8 wh[4][2];
    float bias[4];
#pragma unroll
    for (int t = 0; t < 4; ++t) {
        bias[t] = b2[t * 16 + n16];
#pragma unroll
        for (int ck = 0; ck < 2; ++ck) {
            f16x8 hh;
#pragma unroll
            for (int j = 0; j < 8; ++j)
                hh[j] = (_Float16)w2[(ck * 32 + q * 8 + j) * 64 + t * 16 + n16];
            wh[t][ck] = hh;
        }
    }

    int nwaves = gridDim.x * 4;
    int wid = blockIdx.x * 4 + (threadIdx.x >> 6);
    if (wid >= n) return;

    int c = wid;
    int start = ptr[c], end = ptr[c + 1];
    const f16x8* ah8 = (const f16x8*)(atab + (size_t)c * 64);
    f16x8 A0 = ah8[q], A1 = ah8[4 + q];
    int cn = c + nwaves;
    int sn = 0, en = 0;
    if (cn < n) { sn = ptr[cn]; en = ptr[cn + 1]; }
    int rf = (start + n16 < end) ? csr_row[start + n16] : 0;

    while (true) {
        int cc = c, st = start, ed = end, rfirst = rf;
        f16x8 Ac0 = A0, Ac1 = A1;
        c = cn; start = sn; end = en;
        bool more = (c < n);
        if (more) {
            cn = c + nwaves;
            if (cn < n) { sn = ptr[cn]; en = ptr[cn + 1]; }
            const f16x8* ah8n = (const f16x8*)(atab + (size_t)c * 64);
            A0 = ah8n[q]; A1 = ah8n[4 + q];
            rf = (start + n16 < end) ? csr_row[start + n16] : 0;
        }

        float red[4] = {0.f, 0.f, 0.f, 0.f};   // init 0 folds relu + empty-segment-0
        int r = rfirst;
        int p0 = st;
        int nfull = (ed - st) >> 4;
        // full tiles: unconditional loads, no per-row masking
        for (int ft = 0; ft < nfull; ++ft, p0 += 16) {
            int rcur = r;
            int pn = p0 + 16 + n16;
            if (pn < ed) r = csr_row[pn];
            const f16x8* bh8 = (const f16x8*)(btab + (size_t)rcur * 64);
            f16x8 u0 = relu8(Ac0 + bh8[q]);
            f16x8 u1 = relu8(Ac1 + bh8[4 + q]);
#pragma unroll
            for (int t = 0; t < 4; ++t) {
                f32x4 acc = (f32x4){bias[t], bias[t], bias[t], bias[t]};
                acc = __builtin_amdgcn_mfma_f32_16x16x32_f16(u0, wh[t][0], acc, 0, 0, 0);
                acc = __builtin_amdgcn_mfma_f32_16x16x32_f16(u1, wh[t][1], acc, 0, 0, 0);
                red[t] = fmaxf(red[t], fmaxf(fmaxf(acc[0], acc[1]), fmaxf(acc[2], acc[3])));
            }
        }
        // partial epilogue tile
        int rem = ed - p0;
        if (rem > 0) {
            f16x8 u0 = {0, 0, 0, 0, 0, 0, 0, 0};
            f16x8 u1 = {0, 0, 0, 0, 0, 0, 0, 0};
            if (n16 < rem) {
                const f16x8* bh8 = (const f16x8*)(btab + (size_t)r * 64);
                u0 = relu8(Ac0 + bh8[q]);
                u1 = relu8(Ac1 + bh8[4 + q]);
            }
#pragma unroll
            for (int t = 0; t < 4; ++t) {
                f32x4 acc = (f32x4){bias[t], bias[t], bias[t], bias[t]};
                acc = __builtin_amdgcn_mfma_f32_16x16x32_f16(u0, wh[t][0], acc, 0, 0, 0);
                acc = __builtin_amdgcn_mfma_f32_16x16x32_f16(u1, wh[t][1], acc, 0, 0, 0);
#pragma unroll
                for (int i = 0; i < 4; ++i)
                    if (q * 4 + i < rem) red[t] = fmaxf(red[t], acc[i]);
            }
        }
#pragma unroll
        for (int t = 0; t < 4; ++t) {
            red[t] = fmaxf(red[t], __shfl_xor(red[t], 16));
            red[t] = fmaxf(red[t], __shfl_xor(red[t], 32));
        }
        if (q == 0) {
#pragma unroll
            for (int t = 0; t < 4; ++t)
                hmax[(size_t)cc * 64 + t * 16 + n16] = red[t];
        }
        if (!more) break;
    }
}

// h2 = hmax @ Wg2 (64->16), fp32
__global__ void k_gcn2_node(const float* __restrict__ hmax,
                            const float* __restrict__ wg,
                            float* __restrict__ h2, int n) {
    int t = blockIdx.x * blockDim.x + threadIdx.x;
    int v = t >> 4, j = t & 15;
    if (v >= n) return;
    float acc = 0.f;
#pragma unroll 8
    for (int d = 0; d < 64; ++d)
        acc = fmaf(hmax[v * 64 + d], wg[d * 16 + j], acc);
    h2[v * 16 + j] = acc;
}

// out[c] = bg + dv*(dv*h2[c] + sum_in dinv[r]*h2[r]) ; fully writes d_out
// 8 edge slots x 8 lanes x float2
__global__ __launch_bounds__(256) void k_gcn2_gather(
        const int* __restrict__ ptr, const int* __restrict__ csr_row,
        const float* __restrict__ h2, const float* __restrict__ dinv,
        const float* __restrict__ bg, float* __restrict__ out, int n) {
    int wid = blockIdx.x * 4 + (threadIdx.x >> 6);
    if (wid >= n) return;
    int lane = threadIdx.x & 63;
    int f2 = lane & 7, slot = lane >> 3;
    int c = wid;
    int start = ptr[c], end = ptr[c + 1];
    const float2* h22 = (const float2*)h2;
    float sx = 0.f, sy = 0.f;
    int p = start + slot;
    int r = (p < end) ? csr_row[p] : 0;
    while (p < end) {
        int rcur = r;
        int pn = p + 8;
        if (pn < end) r = csr_row[pn];
        float dr = dinv[rcur];
        float2 hv = h22[(size_t)rcur * 8 + f2];
        sx = fmaf(dr, hv.x, sx);
        sy = fmaf(dr, hv.y, sy);
        p = pn;
    }
#pragma unroll
    for (int off = 8; off < 64; off <<= 1) {
        sx += __shfl_xor(sx, off);
        sy += __shfl_xor(sy, off);
    }
    if (slot == 0) {
        float dv = dinv[c];
        float2 hv = h22[(size_t)c * 8 + f2];
        float2 o;
        o.x = bg[2 * f2]     + dv * (dv * hv.x + sx);
        o.y = bg[2 * f2 + 1] + dv * (dv * hv.y + sy);
        ((float2*)out)[(size_t)c * 8 + f2] = o;
    }
}

extern "C" void kernel_launch(void* const* d_in, const int* in_sizes, int n_in,
                              void* d_out, int out_size, void* d_ws, size_t ws_size,
                              hipStream_t stream) {
    const float* x   = (const float*)d_in[0];
    const int*   ei  = (const int*)d_in[1];
    const float* g1w = (const float*)d_in[2];
    const float* g1b = (const float*)d_in[3];
    const float* ew1 = (const float*)d_in[4];
    const float* eb1 = (const float*)d_in[5];
    const float* ew2 = (const float*)d_in[6];
    const float* eb2 = (const float*)d_in[7];
    const float* g2w = (const float*)d_in[8];
    const float* g2b = (const float*)d_in[9];
    float* out = (float*)d_out;
    float* ws  = (float*)d_ws;

    const int n = in_sizes[0] / 32;      // 50000
    const int E = in_sizes[1] / 2;       // 800000
    const int* row = ei;
    const int* col = ei + E;
    const int ntiles = (n + 15) / 16;    // 3125

    size_t npad    = ((size_t)n + 63) & ~(size_t)63;
    size_t o_deg   = 0;
    size_t o_ptr   = npad;               // n+1 (+pad)
    size_t o_cur   = o_ptr + npad + 64;
    size_t o_csr   = o_cur + npad;       // E ints
    size_t o_dinv  = o_csr + (size_t)E;
    size_t o_hmax  = o_dinv + npad;      // n*64 fp32 ; h1 overlays (dead before edge_mlp)
    size_t o_atab  = o_hmax + (size_t)n * 64;   // n*64 fp16 = n*32 floats
    size_t o_btab  = o_atab + (size_t)n * 32;   // n*64 fp16
    size_t o_agg   = o_btab + (size_t)n * 32;   // n*32 fp32 ; h2 (n*16) overlays front
    size_t o_part  = o_agg + (size_t)n * 32;    // 64 ints
    size_t o_offs  = o_part + 64;               // 64 ints

    int*      deg    = (int*)(ws + o_deg);
    int*      ptr    = (int*)(ws + o_ptr);
    int*      cursor = (int*)(ws + o_cur);
    int*      csr    = (int*)(ws + o_csr);
    float*    dinv   = ws + o_dinv;
    float*    hmax   = ws + o_hmax;
    float*    h1     = ws + o_hmax;      // overlay
    _Float16* atab   = (_Float16*)(ws + o_atab);
    _Float16* btab   = (_Float16*)(ws + o_btab);
    float*    agg    = ws + o_agg;
    float*    h2     = ws + o_agg;       // overlay (agg dead after k_h1)
    int*      part   = (int*)(ws + o_part);
    int*      offs   = (int*)(ws + o_offs);

    int nblk = (n + 3) / 4;                      // wave-per-node kernels, 4 waves/block
    int tblk = (ntiles + 3) / 4;
    int scan_nb = (n + SCAN_CHUNK - 1) / SCAN_CHUNK;   // 25 <= 64

    k_zero4<<<(int)((npad / 4 + 255) / 256), 256, 0, stream>>>((float4*)deg, (int)(npad / 4));
    k_deg<<<(E + 255) / 256, 256, 0, stream>>>(col, deg, E);
    k_scan_partial<<<scan_nb, 256, 0, stream>>>(deg, part, n);
    k_scan_offsets<<<1, 64, 0, stream>>>(part, offs, ptr, scan_nb, n, E);
    k_scan_final<<<scan_nb, 256, 0, stream>>>(deg, offs, ptr, cursor, dinv, n);
    k_fill<<<(E + 255) / 256, 256, 0, stream>>>(row, col, cursor, csr, E);
    k_gather32<<<nblk, 256, 0, stream>>>(ptr, csr, x, dinv, agg, n);
    k_h1<<<tblk, 256, 0, stream>>>(agg, g1w, g1b, h1, ntiles);
    k_w1tab<<<256, 256, 0, stream>>>(h1, ew1, eb1, atab, btab, ntiles);
    k_edge_mlp<<<2048, 256, 0, stream>>>(ptr, csr, atab, btab, ew2, eb2, hmax, n);
    k_gcn2_node<<<(n * 16 + 255) / 256, 256, 0, stream>>>(hmax, g2w, h2, n);
    k_gcn2_gather<<<nblk, 256, 0, stream>>>(ptr, csr, h2, dinv, g2b, out, n);
}

// Round 12
// 246.730 us; speedup vs baseline: 4.9944x; 1.1378x over previous
//
#include <hip/hip_runtime.h>

// CSR-gather pipeline (no float atomics):
//   deg -> multi-block scan(ptr, fused dinv + bucket bases) -> two-phase bucketed fill
//   gather32: agg[v] = dv*sum(dinv[r]*x[r]) + dv^2*x[v]      (irregular, 32 dims)
//   h1 (MFMA dense, bf16 3-term ~fp32): h1 = tanh(agg @ Wg1 + gb)
//   w1tab (MFMA dense, bf16 3-term): atab/btab = h1@{W1a-W1b,W1b} stored as FP16 (RNE)
//   edge_mlp (persistent waves, fp16 single-term MFMA): u = relu(atab[c]+btab[r]) in
//             packed fp16; m = u@W2+b2 (fp32 acc); hmax[c] = max (in regs)
//   gcn2 (fp32): h2 = hmax@Wg2 ; out[c] = bg + dv*(dv*h2[c] + gather sum dinv[r]*h2[r])

typedef __attribute__((ext_vector_type(8))) short short8;
typedef __attribute__((ext_vector_type(4))) float f32x4;
typedef __attribute__((ext_vector_type(8))) _Float16 f16x8;

#define SCAN_CHUNK 2048   // elements per scan block (256 thr x 8)
#define FILL_CH 4096      // edges per phase-A block (256 thr x 16)

__device__ __forceinline__ unsigned short f2bf(float x) {   // RNE f32->bf16 (cold paths only)
    unsigned int u = __float_as_uint(x);
    return (unsigned short)((u + 0x7FFFu + ((u >> 16) & 1u)) >> 16);
}
__device__ __forceinline__ float bf2f(unsigned short h) {
    return __uint_as_float(((unsigned int)h) << 16);
}
// cheap truncation split: u ~= hi + lo with |err| ~ 2^-16 |u|
__device__ __forceinline__ void splitT(float u, short& hi, short& lo) {
    unsigned int ub = __float_as_uint(u);
    hi = (short)(ub >> 16);
    float r = u - __uint_as_float(ub & 0xFFFF0000u);
    lo = (short)(__float_as_uint(r) >> 16);
}
__device__ __forceinline__ f16x8 relu8(f16x8 v) {
    f16x8 z = {0, 0, 0, 0, 0, 0, 0, 0};
#if __has_builtin(__builtin_elementwise_max)
    return __builtin_elementwise_max(v, z);
#else
    f16x8 o;
#pragma unroll
    for (int j = 0; j < 8; ++j) o[j] = v[j] > (_Float16)0 ? v[j] : (_Float16)0;
    return o;
#endif
}

__global__ void k_zero4(float4* p, int n4) {
    int i = blockIdx.x * blockDim.x + threadIdx.x;
    if (i < n4) p[i] = make_float4(0.f, 0.f, 0.f, 0.f);
}

__global__ void k_deg(const int* __restrict__ col, int* __restrict__ deg, int E) {
    int e = blockIdx.x * blockDim.x + threadIdx.x;
    if (e < E) atomicAdd(&deg[col[e]], 1);
}

__global__ __launch_bounds__(256) void k_scan_partial(const int* __restrict__ deg,
                                                      int* __restrict__ part, int n) {
    __shared__ int wtot[4];
    int tid = threadIdx.x;
    int base = blockIdx.x * SCAN_CHUNK + tid * 8;
    int s = 0;
#pragma unroll
    for (int i = 0; i < 8; ++i) { int idx = base + i; if (idx < n) s += deg[idx]; }
    for (int off = 1; off < 64; off <<= 1) s += __shfl_xor(s, off);
    if ((tid & 63) == 0) wtot[tid >> 6] = s;
    __syncthreads();
    if (tid == 0) part[blockIdx.x] = wtot[0] + wtot[1] + wtot[2] + wtot[3];
}

__global__ __launch_bounds__(64) void k_scan_offsets(const int* __restrict__ part,
                                                     int* __restrict__ offs,
                                                     int* __restrict__ ptr, int nb, int n, int E) {
    int lane = threadIdx.x;
    int p = (lane < nb) ? part[lane] : 0;
    int s = p;
    for (int off = 1; off < 64; off <<= 1) {
        int t = __shfl_up(s, off, 64);
        if (lane >= off) s += t;
    }
    if (lane < nb) offs[lane] = s - p;     // exclusive
    if (lane == 0) ptr[n] = E;
}

// block-local exclusive scan + global offset -> ptr ; fused dinv + bucket bases
__global__ __launch_bounds__(256) void k_scan_final(const int* __restrict__ deg,
                                                    const int* __restrict__ offs,
                                                    int* __restrict__ ptr,
                                                    int* __restrict__ bcur,
                                                    float* __restrict__ dinv, int n) {
    __shared__ int wtot[4];
    int tid = threadIdx.x;
    int lane = tid & 63, wv = tid >> 6;
    int base = blockIdx.x * SCAN_CHUNK + tid * 8;
    int d[8];
    int t8 = 0;
#pragma unroll
    for (int i = 0; i < 8; ++i) {
        int idx = base + i;
        d[i] = (idx < n) ? deg[idx] : 0;
        t8 += d[i];
    }
    int s = t8;
    for (int off = 1; off < 64; off <<= 1) {
        int t = __shfl_up(s, off, 64);
        if (lane >= off) s += t;
    }
    if (lane == 63) wtot[wv] = s;
    __syncthreads();
    int wpre = 0;
    for (int w = 0; w < 4; ++w) if (w < wv) wpre += wtot[w];
    int run = offs[blockIdx.x] + wpre + (s - t8);
#pragma unroll
    for (int i = 0; i < 8; ++i) {
        int idx = base + i;
        if (idx < n) {
            ptr[idx] = run;
            if ((idx & 127) == 0) bcur[idx >> 7] = run;   // bucket staging base
            dinv[idx] = rsqrtf((float)(d[i] + 1));        // +1 self loop
            run += d[i];
        }
    }
}

// fill phase A: bucket edges (128 cols/bucket) into contiguous per-bucket runs
__global__ __launch_bounds__(256) void k_fill_a(const int* __restrict__ row,
                                                const int* __restrict__ col,
                                                int* __restrict__ bcur,
                                                int2* __restrict__ stage, int E, int nb) {
    __shared__ int cnt[512];
    __shared__ int base[512];
    int tid = threadIdx.x;
    int e0 = blockIdx.x * FILL_CH;
    for (int i = tid; i < nb; i += 256) cnt[i] = 0;
    __syncthreads();
    int r[16], c[16];
#pragma unroll
    for (int i = 0; i < 16; ++i) {
        int e = e0 + tid + i * 256;
        if (e < E) {
            r[i] = row[e]; c[i] = col[e];
            atomicAdd(&cnt[c[i] >> 7], 1);
        } else c[i] = -1;
    }
    __syncthreads();
    for (int i = tid; i < nb; i += 256)
        base[i] = cnt[i] ? atomicAdd(&bcur[i], cnt[i]) : 0;
    __syncthreads();
    for (int i = tid; i < nb; i += 256) cnt[i] = 0;
    __syncthreads();
#pragma unroll
    for (int i = 0; i < 16; ++i) {
        if (c[i] >= 0) {
            int b = c[i] >> 7;
            int lp = atomicAdd(&cnt[b], 1);
            stage[base[b] + lp] = make_int2(r[i], c[i]);
        }
    }
}

// fill phase B: one block per bucket; LDS cursors; csr writes stay in one L2
__global__ __launch_bounds__(256) void k_fill_b(const int* __restrict__ ptr,
                                                const int2* __restrict__ stage,
                                                int* __restrict__ csr, int n) {
    __shared__ int lcur[128];
    int b = blockIdx.x;
    int tid = threadIdx.x;
    int c0 = b << 7;
    for (int j = tid; j < 128; j += 256) {
        int idx = c0 + j; if (idx > n) idx = n;
        lcur[j] = ptr[idx];
    }
    __syncthreads();
    int start = ptr[c0];
    int endi = c0 + 128; if (endi > n) endi = n;
    int end = ptr[endi];
    for (int p = start + tid; p < end; p += 256) {
        int2 rc = stage[p];
        int pos = atomicAdd(&lcur[rc.y & 127], 1);
        csr[pos] = rc.x;
    }
}

// irregular gather: agg[v] = dv*(sum dinv[r]*x[r]) + dv^2*x[v]
// 8 edge slots x 8 lanes x float4; one-ahead index prefetch
__global__ __launch_bounds__(256) void k_gather32(
        const int* __restrict__ ptr, const int* __restrict__ csr_row,
        const float* __restrict__ x, const float* __restrict__ dinv,
        float* __restrict__ agg, int n) {
    int wid = blockIdx.x * 4 + (threadIdx.x >> 6);
    if (wid >= n) return;
    int lane = threadIdx.x & 63;
    int f4 = lane & 7, slot = lane >> 3;
    int v = wid;
    int start = ptr[v], end = ptr[v + 1];
    const float4* x4 = (const float4*)x;
    float sx = 0.f, sy = 0.f, sz = 0.f, sw = 0.f;
    int p = start + slot;
    int r = (p < end) ? csr_row[p] : 0;
    while (p < end) {
        int rcur = r;
        int pn = p + 8;
        if (pn < end) r = csr_row[pn];
        float dr = dinv[rcur];
        float4 xv = x4[(size_t)rcur * 8 + f4];
        sx = fmaf(dr, xv.x, sx);
        sy = fmaf(dr, xv.y, sy);
        sz = fmaf(dr, xv.z, sz);
        sw = fmaf(dr, xv.w, sw);
        p = pn;
    }
#pragma unroll
    for (int off = 8; off < 64; off <<= 1) {
        sx += __shfl_xor(sx, off); sy += __shfl_xor(sy, off);
        sz += __shfl_xor(sz, off); sw += __shfl_xor(sw, off);
    }
    if (slot == 0) {
        float dv = dinv[v], d2 = dv * dv;
        float4 xv = x4[(size_t)v * 8 + f4];
        float4 o;
        o.x = dv * sx + d2 * xv.x;
        o.y = dv * sy + d2 * xv.y;
        o.z = dv * sz + d2 * xv.z;
        o.w = dv * sw + d2 * xv.w;
        ((float4*)agg)[(size_t)v * 8 + f4] = o;
    }
}

// dense MFMA: h1 = tanh(agg @ Wg1 + gb), tiles of 16 nodes, one wave/tile
__global__ __launch_bounds__(256) void k_h1(
        const float* __restrict__ agg, const float* __restrict__ gw,
        const float* __restrict__ gb, float* __restrict__ h1, int ntiles) {
    int wid = blockIdx.x * 4 + (threadIdx.x >> 6);
    if (wid >= ntiles) return;
    int lane = threadIdx.x & 63;
    int n16 = lane & 15, q = lane >> 4;

    short8 bh[4], bl[4];
    float bias[4];
#pragma unroll
    for (int t = 0; t < 4; ++t) {
        bias[t] = gb[t * 16 + n16];
        short8 hh, ll;
#pragma unroll
        for (int j = 0; j < 8; ++j) {
            float w = gw[(q * 8 + j) * 64 + t * 16 + n16];
            unsigned short wh = f2bf(w);
            hh[j] = (short)wh;
            ll[j] = (short)f2bf(w - bf2f(wh));
        }
        bh[t] = hh; bl[t] = ll;
    }

    int v0 = wid * 16;
    const float4* a4 = (const float4*)(agg + (size_t)(v0 + n16) * 32);
    float4 A0 = a4[2 * q], A1 = a4[2 * q + 1];
    float a[8] = {A0.x, A0.y, A0.z, A0.w, A1.x, A1.y, A1.z, A1.w};
    short8 ah, al;
#pragma unroll
    for (int j = 0; j < 8; ++j) { short h, l; splitT(a[j], h, l); ah[j] = h; al[j] = l; }

#pragma unroll
    for (int t = 0; t < 4; ++t) {
        f32x4 acc = (f32x4){bias[t], bias[t], bias[t], bias[t]};
        acc = __builtin_amdgcn_mfma_f32_16x16x32_bf16(ah, bh[t], acc, 0, 0, 0);
        acc = __builtin_amdgcn_mfma_f32_16x16x32_bf16(al, bh[t], acc, 0, 0, 0);
        acc = __builtin_amdgcn_mfma_f32_16x16x32_bf16(ah, bl[t], acc, 0, 0, 0);
#pragma unroll
        for (int i = 0; i < 4; ++i)
            h1[(size_t)(v0 + q * 4 + i) * 64 + t * 16 + n16] = tanhf(acc[i]);
    }
}

// dense MFMA (bf16 3-term ~fp32 internally): atab = h1@(W1a-W1b)+b1 ; btab = h1@W1b
// outputs stored as FP16 (RNE) for the fp16 edge MLP
__global__ __launch_bounds__(256, 1) void k_w1tab(
        const float* __restrict__ h1, const float* __restrict__ w1,
        const float* __restrict__ b1,
        _Float16* __restrict__ atab, _Float16* __restrict__ btab, int ntiles) {
    int lane = threadIdx.x & 63;
    int n16 = lane & 15, q = lane >> 4;

    short8 th[4][2], tl[4][2], uh[4][2], ul[4][2];   // wt=W1a-W1b, wb=W1b frags
    float bias[4];
#pragma unroll
    for (int t = 0; t < 4; ++t) {
        bias[t] = b1[t * 16 + n16];
#pragma unroll
        for (int ck = 0; ck < 2; ++ck) {
            short8 h1v, l1v, h2v, l2v;
#pragma unroll
            for (int j = 0; j < 8; ++j) {
                int d = ck * 32 + q * 8 + j;
                float wbv = w1[(64 + d) * 64 + t * 16 + n16];
                float wtv = w1[d * 64 + t * 16 + n16] - wbv;
                unsigned short x1 = f2bf(wtv);
                h1v[j] = (short)x1; l1v[j] = (short)f2bf(wtv - bf2f(x1));
                unsigned short x2 = f2bf(wbv);
                h2v[j] = (short)x2; l2v[j] = (short)f2bf(wbv - bf2f(x2));
            }
            th[t][ck] = h1v; tl[t][ck] = l1v;
            uh[t][ck] = h2v; ul[t][ck] = l2v;
        }
    }

    int nwaves = gridDim.x * 4;
    int wid = blockIdx.x * 4 + (threadIdx.x >> 6);
    for (int tile = wid; tile < ntiles; tile += nwaves) {
        int v0 = tile * 16;
        const float4* a4 = (const float4*)(h1 + (size_t)(v0 + n16) * 64);
        float4 A0 = a4[2 * q], A1 = a4[2 * q + 1];
        float4 A2 = a4[8 + 2 * q], A3 = a4[8 + 2 * q + 1];
        float a[16] = {A0.x, A0.y, A0.z, A0.w, A1.x, A1.y, A1.z, A1.w,
                       A2.x, A2.y, A2.z, A2.w, A3.x, A3.y, A3.z, A3.w};
        short8 ah0, ah1, al0, al1;
#pragma unroll
        for (int j = 0; j < 8; ++j) {
            short h, l;
            splitT(a[j], h, l);      ah0[j] = h; al0[j] = l;
            splitT(a[8 + j], h, l);  ah1[j] = h; al1[j] = l;
        }
#pragma unroll
        for (int t = 0; t < 4; ++t) {
            f32x4 aa = (f32x4){bias[t], bias[t], bias[t], bias[t]};
            aa = __builtin_amdgcn_mfma_f32_16x16x32_bf16(ah0, th[t][0], aa, 0, 0, 0);
            aa = __builtin_amdgcn_mfma_f32_16x16x32_bf16(ah1, th[t][1], aa, 0, 0, 0);
            aa = __builtin_amdgcn_mfma_f32_16x16x32_bf16(al0, th[t][0], aa, 0, 0, 0);
            aa = __builtin_amdgcn_mfma_f32_16x16x32_bf16(al1, th[t][1], aa, 0, 0, 0);
            aa = __builtin_amdgcn_mfma_f32_16x16x32_bf16(ah0, tl[t][0], aa, 0, 0, 0);
            aa = __builtin_amdgcn_mfma_f32_16x16x32_bf16(ah1, tl[t][1], aa, 0, 0, 0);
            f32x4 bb = (f32x4){0.f, 0.f, 0.f, 0.f};
            bb = __builtin_amdgcn_mfma_f32_16x16x32_bf16(ah0, uh[t][0], bb, 0, 0, 0);
            bb = __builtin_amdgcn_mfma_f32_16x16x32_bf16(ah1, uh[t][1], bb, 0, 0, 0);
            bb = __builtin_amdgcn_mfma_f32_16x16x32_bf16(al0, uh[t][0], bb, 0, 0, 0);
            bb = __builtin_amdgcn_mfma_f32_16x16x32_bf16(al1, uh[t][1], bb, 0, 0, 0);
            bb = __builtin_amdgcn_mfma_f32_16x16x32_bf16(ah0, ul[t][0], bb, 0, 0, 0);
            bb = __builtin_amdgcn_mfma_f32_16x16x32_bf16(ah1, ul[t][1], bb, 0, 0, 0);
#pragma unroll
            for (int i = 0; i < 4; ++i) {
                size_t off = (size_t)(v0 + q * 4 + i) * 64 + t * 16 + n16;
                atab[off] = (_Float16)aa[i];
                btab[off] = (_Float16)bb[i];
            }
        }
    }
}

// persistent waves, one-node-ahead pipeline; fp16 single-term MFMA (fp32 acc);
// u built in packed fp16; full-tile fast path + masked epilogue; no atomics
__global__ __launch_bounds__(256) void k_edge_mlp(
        const int* __restrict__ ptr, const int* __restrict__ csr_row,
        const _Float16* __restrict__ atab, const _Float16* __restrict__ btab,
        const float* __restrict__ w2, const float* __restrict__ b2,
        float* __restrict__ hmax, int n) {
    int lane = threadIdx.x & 63;
    int n16 = lane & 15, q = lane >> 4;

    f16x8 wh[4][2];
    float bias[4];
#pragma unroll
    for (int t = 0; t < 4; ++t) {
        bias[t] = b2[t * 16 + n16];
#pragma unroll
        for (int ck = 0; ck < 2; ++ck) {
            f16x8 hh;
#pragma unroll
            for (int j = 0; j < 8; ++j)
                hh[j] = (_Float16)w2[(ck * 32 + q * 8 + j) * 64 + t * 16 + n16];
            wh[t][ck] = hh;
        }
    }

    int nwaves = gridDim.x * 4;
    int wid = blockIdx.x * 4 + (threadIdx.x >> 6);
    if (wid >= n) return;

    int c = wid;
    int start = ptr[c], end = ptr[c + 1];
    const f16x8* ah8 = (const f16x8*)(atab + (size_t)c * 64);
    f16x8 A0 = ah8[q], A1 = ah8[4 + q];
    int cn = c + nwaves;
    int sn = 0, en = 0;
    if (cn < n) { sn = ptr[cn]; en = ptr[cn + 1]; }
    int rf = (start + n16 < end) ? csr_row[start + n16] : 0;

    while (true) {
        int cc = c, st = start, ed = end, rfirst = rf;
        f16x8 Ac0 = A0, Ac1 = A1;
        c = cn; start = sn; end = en;
        bool more = (c < n);
        if (more) {
            cn = c + nwaves;
            if (cn < n) { sn = ptr[cn]; en = ptr[cn + 1]; }
            const f16x8* ah8n = (const f16x8*)(atab + (size_t)c * 64);
            A0 = ah8n[q]; A1 = ah8n[4 + q];
            rf = (start + n16 < end) ? csr_row[start + n16] : 0;
        }

        float red[4] = {0.f, 0.f, 0.f, 0.f};   // init 0 folds relu + empty-segment-0
        int r = rfirst;
        int p0 = st;
        int nfull = (ed - st) >> 4;
        for (int ft = 0; ft < nfull; ++ft, p0 += 16) {
            int rcur = r;
            int pn = p0 + 16 + n16;
            if (pn < ed) r = csr_row[pn];
            const f16x8* bh8 = (const f16x8*)(btab + (size_t)rcur * 64);
            f16x8 u0 = relu8(Ac0 + bh8[q]);
            f16x8 u1 = relu8(Ac1 + bh8[4 + q]);
#pragma unroll
            for (int t = 0; t < 4; ++t) {
                f32x4 acc = (f32x4){bias[t], bias[t], bias[t], bias[t]};
                acc = __builtin_amdgcn_mfma_f32_16x16x32_f16(u0, wh[t][0], acc, 0, 0, 0);
                acc = __builtin_amdgcn_mfma_f32_16x16x32_f16(u1, wh[t][1], acc, 0, 0, 0);
                red[t] = fmaxf(red[t], fmaxf(fmaxf(acc[0], acc[1]), fmaxf(acc[2], acc[3])));
            }
        }
        int rem = ed - p0;
        if (rem > 0) {
            f16x8 u0 = {0, 0, 0, 0, 0, 0, 0, 0};
            f16x8 u1 = {0, 0, 0, 0, 0, 0, 0, 0};
            if (n16 < rem) {
                const f16x8* bh8 = (const f16x8*)(btab + (size_t)r * 64);
                u0 = relu8(Ac0 + bh8[q]);
                u1 = relu8(Ac1 + bh8[4 + q]);
            }
#pragma unroll
            for (int t = 0; t < 4; ++t) {
                f32x4 acc = (f32x4){bias[t], bias[t], bias[t], bias[t]};
                acc = __builtin_amdgcn_mfma_f32_16x16x32_f16(u0, wh[t][0], acc, 0, 0, 0);
                acc = __builtin_amdgcn_mfma_f32_16x16x32_f16(u1, wh[t][1], acc, 0, 0, 0);
#pragma unroll
                for (int i = 0; i < 4; ++i)
                    if (q * 4 + i < rem) red[t] = fmaxf(red[t], acc[i]);
            }
        }
#pragma unroll
        for (int t = 0; t < 4; ++t) {
            red[t] = fmaxf(red[t], __shfl_xor(red[t], 16));
            red[t] = fmaxf(red[t], __shfl_xor(red[t], 32));
        }
        if (q == 0) {
#pragma unroll
            for (int t = 0; t < 4; ++t)
                hmax[(size_t)cc * 64 + t * 16 + n16] = red[t];
        }
        if (!more) break;
    }
}

// h2 = hmax @ Wg2 (64->16), fp32
__global__ void k_gcn2_node(const float* __restrict__ hmax,
                            const float* __restrict__ wg,
                            float* __restrict__ h2, int n) {
    int t = blockIdx.x * blockDim.x + threadIdx.x;
    int v = t >> 4, j = t & 15;
    if (v >= n) return;
    float acc = 0.f;
#pragma unroll 8
    for (int d = 0; d < 64; ++d)
        acc = fmaf(hmax[v * 64 + d], wg[d * 16 + j], acc);
    h2[v * 16 + j] = acc;
}

// out[c] = bg + dv*(dv*h2[c] + sum_in dinv[r]*h2[r]) ; fully writes d_out
// 8 edge slots x 8 lanes x float2
__global__ __launch_bounds__(256) void k_gcn2_gather(
        const int* __restrict__ ptr, const int* __restrict__ csr_row,
        const float* __restrict__ h2, const float* __restrict__ dinv,
        const float* __restrict__ bg, float* __restrict__ out, int n) {
    int wid = blockIdx.x * 4 + (threadIdx.x >> 6);
    if (wid >= n) return;
    int lane = threadIdx.x & 63;
    int f2 = lane & 7, slot = lane >> 3;
    int c = wid;
    int start = ptr[c], end = ptr[c + 1];
    const float2* h22 = (const float2*)h2;
    float sx = 0.f, sy = 0.f;
    int p = start + slot;
    int r = (p < end) ? csr_row[p] : 0;
    while (p < end) {
        int rcur = r;
        int pn = p + 8;
        if (pn < end) r = csr_row[pn];
        float dr = dinv[rcur];
        float2 hv = h22[(size_t)rcur * 8 + f2];
        sx = fmaf(dr, hv.x, sx);
        sy = fmaf(dr, hv.y, sy);
        p = pn;
    }
#pragma unroll
    for (int off = 8; off < 64; off <<= 1) {
        sx += __shfl_xor(sx, off);
        sy += __shfl_xor(sy, off);
    }
    if (slot == 0) {
        float dv = dinv[c];
        float2 hv = h22[(size_t)c * 8 + f2];
        float2 o;
        o.x = bg[2 * f2]     + dv * (dv * hv.x + sx);
        o.y = bg[2 * f2 + 1] + dv * (dv * hv.y + sy);
        ((float2*)out)[(size_t)c * 8 + f2] = o;
    }
}

extern "C" void kernel_launch(void* const* d_in, const int* in_sizes, int n_in,
                              void* d_out, int out_size, void* d_ws, size_t ws_size,
                              hipStream_t stream) {
    const float* x   = (const float*)d_in[0];
    const int*   ei  = (const int*)d_in[1];
    const float* g1w = (const float*)d_in[2];
    const float* g1b = (const float*)d_in[3];
    const float* ew1 = (const float*)d_in[4];
    const float* eb1 = (const float*)d_in[5];
    const float* ew2 = (const float*)d_in[6];
    const float* eb2 = (const float*)d_in[7];
    const float* g2w = (const float*)d_in[8];
    const float* g2b = (const float*)d_in[9];
    float* out = (float*)d_out;
    float* ws  = (float*)d_ws;

    const int n = in_sizes[0] / 32;      // 50000
    const int E = in_sizes[1] / 2;       // 800000
    const int* row = ei;
    const int* col = ei + E;
    const int ntiles = (n + 15) / 16;    // 3125
    const int nbuck = (n + 127) >> 7;    // 391 buckets of 128 cols

    size_t npad    = ((size_t)n + 63) & ~(size_t)63;
    size_t o_deg   = 0;
    size_t o_ptr   = npad;                      // n+1 (+pad)
    size_t o_csr   = o_ptr + npad + 64;         // E ints
    size_t o_dinv  = o_csr + (size_t)E;
    size_t o_hmax  = o_dinv + npad;             // n*64 fp32 ; h1 overlays
    size_t o_atab  = o_hmax + (size_t)n * 64;   // n*64 fp16 = n*32 floats
    size_t o_btab  = o_atab + (size_t)n * 32;   // n*64 fp16
    size_t o_agg   = o_btab + (size_t)n * 32;   // n*32 fp32 ; h2 overlays front
    size_t o_stage = o_agg + (size_t)n * 32;    // E int2 = 2E ints (8B aligned: even)
    size_t o_bcur  = o_stage + (size_t)E * 2;   // nbuck ints
    size_t o_part  = o_bcur + 512;              // 64 ints
    size_t o_offs  = o_part + 64;               // 64 ints

    int*      deg    = (int*)(ws + o_deg);
    int*      ptr    = (int*)(ws + o_ptr);
    int*      csr    = (int*)(ws + o_csr);
    float*    dinv   = ws + o_dinv;
    float*    hmax   = ws + o_hmax;
    float*    h1     = ws + o_hmax;      // overlay
    _Float16* atab   = (_Float16*)(ws + o_atab);
    _Float16* btab   = (_Float16*)(ws + o_btab);
    float*    agg    = ws + o_agg;
    float*    h2     = ws + o_agg;       // overlay (agg dead after k_h1)
    int2*     stage  = (int2*)(ws + o_stage);
    int*      bcur   = (int*)(ws + o_bcur);
    int*      part   = (int*)(ws + o_part);
    int*      offs   = (int*)(ws + o_offs);

    int nblk = (n + 3) / 4;                      // wave-per-node kernels, 4 waves/block
    int tblk = (ntiles + 3) / 4;
    int scan_nb = (n + SCAN_CHUNK - 1) / SCAN_CHUNK;   // 25 <= 64
    int fill_nb = (E + FILL_CH - 1) / FILL_CH;         // 196

    k_zero4<<<(int)((npad / 4 + 255) / 256), 256, 0, stream>>>((float4*)deg, (int)(npad / 4));
    k_deg<<<(E + 255) / 256, 256, 0, stream>>>(col, deg, E);
    k_scan_partial<<<scan_nb, 256, 0, stream>>>(deg, part, n);
    k_scan_offsets<<<1, 64, 0, stream>>>(part, offs, ptr, scan_nb, n, E);
    k_scan_final<<<scan_nb, 256, 0, stream>>>(deg, offs, ptr, bcur, dinv, n);
    k_fill_a<<<fill_nb, 256, 0, stream>>>(row, col, bcur, stage, E, nbuck);
    k_fill_b<<<nbuck, 256, 0, stream>>>(ptr, stage, csr, n);
    k_gather32<<<nblk, 256, 0, stream>>>(ptr, csr, x, dinv, agg, n);
    k_h1<<<tblk, 256, 0, stream>>>(agg, g1w, g1b, h1, ntiles);
    k_w1tab<<<256, 256, 0, stream>>>(h1, ew1, eb1, atab, btab, ntiles);
    k_edge_mlp<<<2048, 256, 0, stream>>>(ptr, csr, atab, btab, ew2, eb2, hmax, n);
    k_gcn2_node<<<(n * 16 + 255) / 256, 256, 0, stream>>>(hmax, g2w, h2, n);
    k_gcn2_gather<<<nblk, 256, 0, stream>>>(ptr, csr, h2, dinv, g2b, out, n);
}

// Round 13
// 243.030 us; speedup vs baseline: 5.0704x; 1.0152x over previous
//
#include <hip/hip_runtime.h>

// CSR-gather pipeline (no float atomics):
//   deg -> multi-block scan(ptr, fused dinv + bucket bases) -> two-phase bucketed fill
//   xcast: x -> fp16 copy (gather traffic halving)
//   gather32: agg[v] = dv*sum(dinv[r]*xh[r]) + dv^2*x[v]     (irregular, 32 dims)
//   h1 (MFMA dense, bf16 3-term ~fp32): h1 = tanh(agg @ Wg1 + gb)
//   w1tab (MFMA dense, bf16 3-term): atab/btab = h1@{W1a-W1b,W1b} stored as FP16 (RNE)
//   edge_mlp (persistent waves, fp16 MFMA, fused GCN2 node matmul): u = relu(atab[c]+btab[r]);
//             m = u@W2+b2 (fp32 acc); hmax = max (in regs); h2[c] = hmax@Wg2 -> fp16
//   gcn2_gather (fp16 h2): out[c] = bg + dv*(dv*h2[c] + gather sum dinv[r]*h2[r])

typedef __attribute__((ext_vector_type(8))) short short8;
typedef __attribute__((ext_vector_type(4))) float f32x4;
typedef __attribute__((ext_vector_type(8))) _Float16 f16x8;
typedef __attribute__((ext_vector_type(4))) _Float16 f16x4;
typedef __attribute__((ext_vector_type(2))) _Float16 f16x2;

#define SCAN_CHUNK 2048   // elements per scan block (256 thr x 8)
#define FILL_CH 4096      // edges per phase-A block (256 thr x 16)

__device__ __forceinline__ unsigned short f2bf(float x) {   // RNE f32->bf16 (cold paths only)
    unsigned int u = __float_as_uint(x);
    return (unsigned short)((u + 0x7FFFu + ((u >> 16) & 1u)) >> 16);
}
__device__ __forceinline__ float bf2f(unsigned short h) {
    return __uint_as_float(((unsigned int)h) << 16);
}
// cheap truncation split: u ~= hi + lo with |err| ~ 2^-16 |u|
__device__ __forceinline__ void splitT(float u, short& hi, short& lo) {
    unsigned int ub = __float_as_uint(u);
    hi = (short)(ub >> 16);
    float r = u - __uint_as_float(ub & 0xFFFF0000u);
    lo = (short)(__float_as_uint(r) >> 16);
}
__device__ __forceinline__ f16x8 relu8(f16x8 v) {
    f16x8 z = {0, 0, 0, 0, 0, 0, 0, 0};
#if __has_builtin(__builtin_elementwise_max)
    return __builtin_elementwise_max(v, z);
#else
    f16x8 o;
#pragma unroll
    for (int j = 0; j < 8; ++j) o[j] = v[j] > (_Float16)0 ? v[j] : (_Float16)0;
    return o;
#endif
}

__global__ void k_zero4(float4* p, int n4) {
    int i = blockIdx.x * blockDim.x + threadIdx.x;
    if (i < n4) p[i] = make_float4(0.f, 0.f, 0.f, 0.f);
}

__global__ void k_deg(const int* __restrict__ col, int* __restrict__ deg, int E) {
    int e = blockIdx.x * blockDim.x + threadIdx.x;
    if (e < E) atomicAdd(&deg[col[e]], 1);
}

__global__ void k_xcast(const float4* __restrict__ x4, f16x4* __restrict__ xh4, int m4) {
    int i = blockIdx.x * blockDim.x + threadIdx.x;
    if (i >= m4) return;
    float4 v = x4[i];
    f16x4 o;
    o[0] = (_Float16)v.x; o[1] = (_Float16)v.y;
    o[2] = (_Float16)v.z; o[3] = (_Float16)v.w;
    xh4[i] = o;
}

__global__ __launch_bounds__(256) void k_scan_partial(const int* __restrict__ deg,
                                                      int* __restrict__ part, int n) {
    __shared__ int wtot[4];
    int tid = threadIdx.x;
    int base = blockIdx.x * SCAN_CHUNK + tid * 8;
    int s = 0;
#pragma unroll
    for (int i = 0; i < 8; ++i) { int idx = base + i; if (idx < n) s += deg[idx]; }
    for (int off = 1; off < 64; off <<= 1) s += __shfl_xor(s, off);
    if ((tid & 63) == 0) wtot[tid >> 6] = s;
    __syncthreads();
    if (tid == 0) part[blockIdx.x] = wtot[0] + wtot[1] + wtot[2] + wtot[3];
}

__global__ __launch_bounds__(64) void k_scan_offsets(const int* __restrict__ part,
                                                     int* __restrict__ offs,
                                                     int* __restrict__ ptr, int nb, int n, int E) {
    int lane = threadIdx.x;
    int p = (lane < nb) ? part[lane] : 0;
    int s = p;
    for (int off = 1; off < 64; off <<= 1) {
        int t = __shfl_up(s, off, 64);
        if (lane >= off) s += t;
    }
    if (lane < nb) offs[lane] = s - p;     // exclusive
    if (lane == 0) ptr[n] = E;
}

// block-local exclusive scan + global offset -> ptr ; fused dinv + bucket bases
__global__ __launch_bounds__(256) void k_scan_final(const int* __restrict__ deg,
                                                    const int* __restrict__ offs,
                                                    int* __restrict__ ptr,
                                                    int* __restrict__ bcur,
                                                    float* __restrict__ dinv, int n) {
    __shared__ int wtot[4];
    int tid = threadIdx.x;
    int lane = tid & 63, wv = tid >> 6;
    int base = blockIdx.x * SCAN_CHUNK + tid * 8;
    int d[8];
    int t8 = 0;
#pragma unroll
    for (int i = 0; i < 8; ++i) {
        int idx = base + i;
        d[i] = (idx < n) ? deg[idx] : 0;
        t8 += d[i];
    }
    int s = t8;
    for (int off = 1; off < 64; off <<= 1) {
        int t = __shfl_up(s, off, 64);
        if (lane >= off) s += t;
    }
    if (lane == 63) wtot[wv] = s;
    __syncthreads();
    int wpre = 0;
    for (int w = 0; w < 4; ++w) if (w < wv) wpre += wtot[w];
    int run = offs[blockIdx.x] + wpre + (s - t8);
#pragma unroll
    for (int i = 0; i < 8; ++i) {
        int idx = base + i;
        if (idx < n) {
            ptr[idx] = run;
            if ((idx & 127) == 0) bcur[idx >> 7] = run;   // bucket staging base
            dinv[idx] = rsqrtf((float)(d[i] + 1));        // +1 self loop
            run += d[i];
        }
    }
}

// fill phase A: bucket edges (128 cols/bucket) into contiguous per-bucket runs
__global__ __launch_bounds__(256) void k_fill_a(const int* __restrict__ row,
                                                const int* __restrict__ col,
                                                int* __restrict__ bcur,
                                                int2* __restrict__ stage, int E, int nb) {
    __shared__ int cnt[512];
    __shared__ int base[512];
    int tid = threadIdx.x;
    int e0 = blockIdx.x * FILL_CH;
    for (int i = tid; i < nb; i += 256) cnt[i] = 0;
    __syncthreads();
    int r[16], c[16];
#pragma unroll
    for (int i = 0; i < 16; ++i) {
        int e = e0 + tid + i * 256;
        if (e < E) {
            r[i] = row[e]; c[i] = col[e];
            atomicAdd(&cnt[c[i] >> 7], 1);
        } else c[i] = -1;
    }
    __syncthreads();
    for (int i = tid; i < nb; i += 256)
        base[i] = cnt[i] ? atomicAdd(&bcur[i], cnt[i]) : 0;
    __syncthreads();
    for (int i = tid; i < nb; i += 256) cnt[i] = 0;
    __syncthreads();
#pragma unroll
    for (int i = 0; i < 16; ++i) {
        if (c[i] >= 0) {
            int b = c[i] >> 7;
            int lp = atomicAdd(&cnt[b], 1);
            stage[base[b] + lp] = make_int2(r[i], c[i]);
        }
    }
}

// fill phase B: one block per bucket; LDS cursors; csr writes stay in one L2
__global__ __launch_bounds__(256) void k_fill_b(const int* __restrict__ ptr,
                                                const int2* __restrict__ stage,
                                                int* __restrict__ csr, int n) {
    __shared__ int lcur[128];
    int b = blockIdx.x;
    int tid = threadIdx.x;
    int c0 = b << 7;
    for (int j = tid; j < 128; j += 256) {
        int idx = c0 + j; if (idx > n) idx = n;
        lcur[j] = ptr[idx];
    }
    __syncthreads();
    int start = ptr[c0];
    int endi = c0 + 128; if (endi > n) endi = n;
    int end = ptr[endi];
    for (int p = start + tid; p < end; p += 256) {
        int2 rc = stage[p];
        int pos = atomicAdd(&lcur[rc.y & 127], 1);
        csr[pos] = rc.x;
    }
}

// irregular gather (fp16 x): agg[v] = dv*(sum dinv[r]*xh[r]) + dv^2*x[v]
// 8 edge slots x 8 lanes x half4; one-ahead index prefetch; fp32 accumulate
__global__ __launch_bounds__(256) void k_gather32(
        const int* __restrict__ ptr, const int* __restrict__ csr_row,
        const float* __restrict__ x, const _Float16* __restrict__ xh,
        const float* __restrict__ dinv, float* __restrict__ agg, int n) {
    int wid = blockIdx.x * 4 + (threadIdx.x >> 6);
    if (wid >= n) return;
    int lane = threadIdx.x & 63;
    int f4 = lane & 7, slot = lane >> 3;
    int v = wid;
    int start = ptr[v], end = ptr[v + 1];
    const f16x4* xh4 = (const f16x4*)xh;
    float sx = 0.f, sy = 0.f, sz = 0.f, sw = 0.f;
    int p = start + slot;
    int r = (p < end) ? csr_row[p] : 0;
    while (p < end) {
        int rcur = r;
        int pn = p + 8;
        if (pn < end) r = csr_row[pn];
        float dr = dinv[rcur];
        f16x4 xv = xh4[(size_t)rcur * 8 + f4];
        sx = fmaf(dr, (float)xv[0], sx);
        sy = fmaf(dr, (float)xv[1], sy);
        sz = fmaf(dr, (float)xv[2], sz);
        sw = fmaf(dr, (float)xv[3], sw);
        p = pn;
    }
#pragma unroll
    for (int off = 8; off < 64; off <<= 1) {
        sx += __shfl_xor(sx, off); sy += __shfl_xor(sy, off);
        sz += __shfl_xor(sz, off); sw += __shfl_xor(sw, off);
    }
    if (slot == 0) {
        float dv = dinv[v], d2 = dv * dv;
        float4 xv = ((const float4*)x)[(size_t)v * 8 + f4];   // self term fp32
        float4 o;
        o.x = dv * sx + d2 * xv.x;
        o.y = dv * sy + d2 * xv.y;
        o.z = dv * sz + d2 * xv.z;
        o.w = dv * sw + d2 * xv.w;
        ((float4*)agg)[(size_t)v * 8 + f4] = o;
    }
}

// dense MFMA: h1 = tanh(agg @ Wg1 + gb), tiles of 16 nodes, one wave/tile
__global__ __launch_bounds__(256) void k_h1(
        const float* __restrict__ agg, const float* __restrict__ gw,
        const float* __restrict__ gb, float* __restrict__ h1, int ntiles) {
    int wid = blockIdx.x * 4 + (threadIdx.x >> 6);
    if (wid >= ntiles) return;
    int lane = threadIdx.x & 63;
    int n16 = lane & 15, q = lane >> 4;

    short8 bh[4], bl[4];
    float bias[4];
#pragma unroll
    for (int t = 0; t < 4; ++t) {
        bias[t] = gb[t * 16 + n16];
        short8 hh, ll;
#pragma unroll
        for (int j = 0; j < 8; ++j) {
            float w = gw[(q * 8 + j) * 64 + t * 16 + n16];
            unsigned short wh = f2bf(w);
            hh[j] = (short)wh;
            ll[j] = (short)f2bf(w - bf2f(wh));
        }
        bh[t] = hh; bl[t] = ll;
    }

    int v0 = wid * 16;
    const float4* a4 = (const float4*)(agg + (size_t)(v0 + n16) * 32);
    float4 A0 = a4[2 * q], A1 = a4[2 * q + 1];
    float a[8] = {A0.x, A0.y, A0.z, A0.w, A1.x, A1.y, A1.z, A1.w};
    short8 ah, al;
#pragma unroll
    for (int j = 0; j < 8; ++j) { short h, l; splitT(a[j], h, l); ah[j] = h; al[j] = l; }

#pragma unroll
    for (int t = 0; t < 4; ++t) {
        f32x4 acc = (f32x4){bias[t], bias[t], bias[t], bias[t]};
        acc = __builtin_amdgcn_mfma_f32_16x16x32_bf16(ah, bh[t], acc, 0, 0, 0);
        acc = __builtin_amdgcn_mfma_f32_16x16x32_bf16(al, bh[t], acc, 0, 0, 0);
        acc = __builtin_amdgcn_mfma_f32_16x16x32_bf16(ah, bl[t], acc, 0, 0, 0);
#pragma unroll
        for (int i = 0; i < 4; ++i)
            h1[(size_t)(v0 + q * 4 + i) * 64 + t * 16 + n16] = tanhf(acc[i]);
    }
}

// dense MFMA (bf16 3-term ~fp32 internally): atab = h1@(W1a-W1b)+b1 ; btab = h1@W1b
// outputs stored as FP16 (RNE) for the fp16 edge MLP
__global__ __launch_bounds__(256, 1) void k_w1tab(
        const float* __restrict__ h1, const float* __restrict__ w1,
        const float* __restrict__ b1,
        _Float16* __restrict__ atab, _Float16* __restrict__ btab, int ntiles) {
    int lane = threadIdx.x & 63;
    int n16 = lane & 15, q = lane >> 4;

    short8 th[4][2], tl[4][2], uh[4][2], ul[4][2];   // wt=W1a-W1b, wb=W1b frags
    float bias[4];
#pragma unroll
    for (int t = 0; t < 4; ++t) {
        bias[t] = b1[t * 16 + n16];
#pragma unroll
        for (int ck = 0; ck < 2; ++ck) {
            short8 h1v, l1v, h2v, l2v;
#pragma unroll
            for (int j = 0; j < 8; ++j) {
                int d = ck * 32 + q * 8 + j;
                float wbv = w1[(64 + d) * 64 + t * 16 + n16];
                float wtv = w1[d * 64 + t * 16 + n16] - wbv;
                unsigned short x1 = f2bf(wtv);
                h1v[j] = (short)x1; l1v[j] = (short)f2bf(wtv - bf2f(x1));
                unsigned short x2 = f2bf(wbv);
                h2v[j] = (short)x2; l2v[j] = (short)f2bf(wbv - bf2f(x2));
            }
            th[t][ck] = h1v; tl[t][ck] = l1v;
            uh[t][ck] = h2v; ul[t][ck] = l2v;
        }
    }

    int nwaves = gridDim.x * 4;
    int wid = blockIdx.x * 4 + (threadIdx.x >> 6);
    for (int tile = wid; tile < ntiles; tile += nwaves) {
        int v0 = tile * 16;
        const float4* a4 = (const float4*)(h1 + (size_t)(v0 + n16) * 64);
        float4 A0 = a4[2 * q], A1 = a4[2 * q + 1];
        float4 A2 = a4[8 + 2 * q], A3 = a4[8 + 2 * q + 1];
        float a[16] = {A0.x, A0.y, A0.z, A0.w, A1.x, A1.y, A1.z, A1.w,
                       A2.x, A2.y, A2.z, A2.w, A3.x, A3.y, A3.z, A3.w};
        short8 ah0, ah1, al0, al1;
#pragma unroll
        for (int j = 0; j < 8; ++j) {
            short h, l;
            splitT(a[j], h, l);      ah0[j] = h; al0[j] = l;
            splitT(a[8 + j], h, l);  ah1[j] = h; al1[j] = l;
        }
#pragma unroll
        for (int t = 0; t < 4; ++t) {
            f32x4 aa = (f32x4){bias[t], bias[t], bias[t], bias[t]};
            aa = __builtin_amdgcn_mfma_f32_16x16x32_bf16(ah0, th[t][0], aa, 0, 0, 0);
            aa = __builtin_amdgcn_mfma_f32_16x16x32_bf16(ah1, th[t][1], aa, 0, 0, 0);
            aa = __builtin_amdgcn_mfma_f32_16x16x32_bf16(al0, th[t][0], aa, 0, 0, 0);
            aa = __builtin_amdgcn_mfma_f32_16x16x32_bf16(al1, th[t][1], aa, 0, 0, 0);
            aa = __builtin_amdgcn_mfma_f32_16x16x32_bf16(ah0, tl[t][0], aa, 0, 0, 0);
            aa = __builtin_amdgcn_mfma_f32_16x16x32_bf16(ah1, tl[t][1], aa, 0, 0, 0);
            f32x4 bb = (f32x4){0.f, 0.f, 0.f, 0.f};
            bb = __builtin_amdgcn_mfma_f32_16x16x32_bf16(ah0, uh[t][0], bb, 0, 0, 0);
            bb = __builtin_amdgcn_mfma_f32_16x16x32_bf16(ah1, uh[t][1], bb, 0, 0, 0);
            bb = __builtin_amdgcn_mfma_f32_16x16x32_bf16(al0, uh[t][0], bb, 0, 0, 0);
            bb = __builtin_amdgcn_mfma_f32_16x16x32_bf16(al1, uh[t][1], bb, 0, 0, 0);
            bb = __builtin_amdgcn_mfma_f32_16x16x32_bf16(ah0, ul[t][0], bb, 0, 0, 0);
            bb = __builtin_amdgcn_mfma_f32_16x16x32_bf16(ah1, ul[t][1], bb, 0, 0, 0);
#pragma unroll
            for (int i = 0; i < 4; ++i) {
                size_t off = (size_t)(v0 + q * 4 + i) * 64 + t * 16 + n16;
                atab[off] = (_Float16)aa[i];
                btab[off] = (_Float16)bb[i];
            }
        }
    }
}

// persistent waves, one-node-ahead pipeline; fp16 MFMA (fp32 acc); fused GCN2
// node matmul in epilogue (hmax never materialized); h2 stored fp16; no atomics
__global__ __launch_bounds__(256) void k_edge_mlp(
        const int* __restrict__ ptr, const int* __restrict__ csr_row,
        const _Float16* __restrict__ atab, const _Float16* __restrict__ btab,
        const float* __restrict__ w2, const float* __restrict__ b2,
        const float* __restrict__ wg, _Float16* __restrict__ h2h, int n) {
    int lane = threadIdx.x & 63;
    int n16 = lane & 15, q = lane >> 4;

    f16x8 wh[4][2];
    float bias[4];
    float wgf[4][4];    // Wg2 rows {t*16+n16}, cols {q*4+jj}
#pragma unroll
    for (int t = 0; t < 4; ++t) {
        bias[t] = b2[t * 16 + n16];
#pragma unroll
        for (int jj = 0; jj < 4; ++jj)
            wgf[t][jj] = wg[(t * 16 + n16) * 16 + q * 4 + jj];
#pragma unroll
        for (int ck = 0; ck < 2; ++ck) {
            f16x8 hh;
#pragma unroll
            for (int j = 0; j < 8; ++j)
                hh[j] = (_Float16)w2[(ck * 32 + q * 8 + j) * 64 + t * 16 + n16];
            wh[t][ck] = hh;
        }
    }

    int nwaves = gridDim.x * 4;
    int wid = blockIdx.x * 4 + (threadIdx.x >> 6);
    if (wid >= n) return;

    int c = wid;
    int start = ptr[c], end = ptr[c + 1];
    const f16x8* ah8 = (const f16x8*)(atab + (size_t)c * 64);
    f16x8 A0 = ah8[q], A1 = ah8[4 + q];
    int cn = c + nwaves;
    int sn = 0, en = 0;
    if (cn < n) { sn = ptr[cn]; en = ptr[cn + 1]; }
    int rf = (start + n16 < end) ? csr_row[start + n16] : 0;

    while (true) {
        int cc = c, st = start, ed = end, rfirst = rf;
        f16x8 Ac0 = A0, Ac1 = A1;
        c = cn; start = sn; end = en;
        bool more = (c < n);
        if (more) {
            cn = c + nwaves;
            if (cn < n) { sn = ptr[cn]; en = ptr[cn + 1]; }
            const f16x8* ah8n = (const f16x8*)(atab + (size_t)c * 64);
            A0 = ah8n[q]; A1 = ah8n[4 + q];
            rf = (start + n16 < end) ? csr_row[start + n16] : 0;
        }

        float red[4] = {0.f, 0.f, 0.f, 0.f};   // init 0 folds relu + empty-segment-0
        int r = rfirst;
        int p0 = st;
        int nfull = (ed - st) >> 4;
        for (int ft = 0; ft < nfull; ++ft, p0 += 16) {
            int rcur = r;
            int pn = p0 + 16 + n16;
            if (pn < ed) r = csr_row[pn];
            const f16x8* bh8 = (const f16x8*)(btab + (size_t)rcur * 64);
            f16x8 u0 = relu8(Ac0 + bh8[q]);
            f16x8 u1 = relu8(Ac1 + bh8[4 + q]);
#pragma unroll
            for (int t = 0; t < 4; ++t) {
                f32x4 acc = (f32x4){bias[t], bias[t], bias[t], bias[t]};
                acc = __builtin_amdgcn_mfma_f32_16x16x32_f16(u0, wh[t][0], acc, 0, 0, 0);
                acc = __builtin_amdgcn_mfma_f32_16x16x32_f16(u1, wh[t][1], acc, 0, 0, 0);
                red[t] = fmaxf(red[t], fmaxf(fmaxf(acc[0], acc[1]), fmaxf(acc[2], acc[3])));
            }
        }
        int rem = ed - p0;
        if (rem > 0) {
            f16x8 u0 = {0, 0, 0, 0, 0, 0, 0, 0};
            f16x8 u1 = {0, 0, 0, 0, 0, 0, 0, 0};
            if (n16 < rem) {
                const f16x8* bh8 = (const f16x8*)(btab + (size_t)r * 64);
                u0 = relu8(Ac0 + bh8[q]);
                u1 = relu8(Ac1 + bh8[4 + q]);
            }
#pragma unroll
            for (int t = 0; t < 4; ++t) {
                f32x4 acc = (f32x4){bias[t], bias[t], bias[t], bias[t]};
                acc = __builtin_amdgcn_mfma_f32_16x16x32_f16(u0, wh[t][0], acc, 0, 0, 0);
                acc = __builtin_amdgcn_mfma_f32_16x16x32_f16(u1, wh[t][1], acc, 0, 0, 0);
#pragma unroll
                for (int i = 0; i < 4; ++i)
                    if (q * 4 + i < rem) red[t] = fmaxf(red[t], acc[i]);
            }
        }
        // butterfly: all lanes get final segment-max for features t*16+n16
#pragma unroll
        for (int t = 0; t < 4; ++t) {
            red[t] = fmaxf(red[t], __shfl_xor(red[t], 16));
            red[t] = fmaxf(red[t], __shfl_xor(red[t], 32));
        }
        // fused GCN2 node matmul: h2[cc][q*4+jj] = sum_d hmax[d]*wg[d][q*4+jj]
        float part[4];
#pragma unroll
        for (int jj = 0; jj < 4; ++jj) {
            part[jj] = red[0] * wgf[0][jj];
            part[jj] = fmaf(red[1], wgf[1][jj], part[jj]);
            part[jj] = fmaf(red[2], wgf[2][jj], part[jj]);
            part[jj] = fmaf(red[3], wgf[3][jj], part[jj]);
        }
#pragma unroll
        for (int off = 1; off < 16; off <<= 1) {
#pragma unroll
            for (int jj = 0; jj < 4; ++jj)
                part[jj] += __shfl_xor(part[jj], off);
        }
        if (n16 == 0) {
            f16x4 ph;
            ph[0] = (_Float16)part[0]; ph[1] = (_Float16)part[1];
            ph[2] = (_Float16)part[2]; ph[3] = (_Float16)part[3];
            ((f16x4*)(h2h + (size_t)cc * 16))[q] = ph;
        }
        if (!more) break;
    }
}

// out[c] = bg + dv*(dv*h2[c] + sum_in dinv[r]*h2[r]) ; fully writes d_out
// 8 edge slots x 8 lanes x fp16 pair
__global__ __launch_bounds__(256) void k_gcn2_gather(
        const int* __restrict__ ptr, const int* __restrict__ csr_row,
        const _Float16* __restrict__ h2h, const float* __restrict__ dinv,
        const float* __restrict__ bg, float* __restrict__ out, int n) {
    int wid = blockIdx.x * 4 + (threadIdx.x >> 6);
    if (wid >= n) return;
    int lane = threadIdx.x & 63;
    int f2 = lane & 7, slot = lane >> 3;
    int c = wid;
    int start = ptr[c], end = ptr[c + 1];
    const f16x2* h22 = (const f16x2*)h2h;
    float sx = 0.f, sy = 0.f;
    int p = start + slot;
    int r = (p < end) ? csr_row[p] : 0;
    while (p < end) {
        int rcur = r;
        int pn = p + 8;
        if (pn < end) r = csr_row[pn];
        float dr = dinv[rcur];
        f16x2 hv = h22[(size_t)rcur * 8 + f2];
        sx = fmaf(dr, (float)hv[0], sx);
        sy = fmaf(dr, (float)hv[1], sy);
        p = pn;
    }
#pragma unroll
    for (int off = 8; off < 64; off <<= 1) {
        sx += __shfl_xor(sx, off);
        sy += __shfl_xor(sy, off);
    }
    if (slot == 0) {
        float dv = dinv[c];
        f16x2 hv = h22[(size_t)c * 8 + f2];
        float2 o;
        o.x = bg[2 * f2]     + dv * (dv * (float)hv[0] + sx);
        o.y = bg[2 * f2 + 1] + dv * (dv * (float)hv[1] + sy);
        ((float2*)out)[(size_t)c * 8 + f2] = o;
    }
}

extern "C" void kernel_launch(void* const* d_in, const int* in_sizes, int n_in,
                              void* d_out, int out_size, void* d_ws, size_t ws_size,
                              hipStream_t stream) {
    const float* x   = (const float*)d_in[0];
    const int*   ei  = (const int*)d_in[1];
    const float* g1w = (const float*)d_in[2];
    const float* g1b = (const float*)d_in[3];
    const float* ew1 = (const float*)d_in[4];
    const float* eb1 = (const float*)d_in[5];
    const float* ew2 = (const float*)d_in[6];
    const float* eb2 = (const float*)d_in[7];
    const float* g2w = (const float*)d_in[8];
    const float* g2b = (const float*)d_in[9];
    float* out = (float*)d_out;
    float* ws  = (float*)d_ws;

    const int n = in_sizes[0] / 32;      // 50000
    const int E = in_sizes[1] / 2;       // 800000
    const int* row = ei;
    const int* col = ei + E;
    const int ntiles = (n + 15) / 16;    // 3125
    const int nbuck = (n + 127) >> 7;    // 391 buckets of 128 cols

    size_t npad    = ((size_t)n + 63) & ~(size_t)63;
    size_t o_deg   = 0;
    size_t o_ptr   = npad;                      // n+1 (+pad)
    size_t o_csr   = o_ptr + npad + 64;         // E ints
    size_t o_dinv  = o_csr + (size_t)E;
    size_t o_h1    = o_dinv + npad;             // n*64 fp32
    size_t o_atab  = o_h1 + (size_t)n * 64;     // n*64 fp16 = n*32 floats
    size_t o_btab  = o_atab + (size_t)n * 32;   // n*64 fp16
    size_t o_agg   = o_btab + (size_t)n * 32;   // n*32 fp32
    size_t o_xh    = o_agg + (size_t)n * 32;    // n*32 fp16 = n*16 floats
    size_t o_h2h   = o_xh + (size_t)n * 16;     // n*16 fp16 = n*8 floats
    size_t o_stage = o_h2h + (size_t)n * 8;     // E int2 (8B aligned: offsets even)
    size_t o_bcur  = o_stage + (size_t)E * 2;   // nbuck ints
    size_t o_part  = o_bcur + 512;              // 64 ints
    size_t o_offs  = o_part + 64;               // 64 ints

    int*      deg    = (int*)(ws + o_deg);
    int*      ptr    = (int*)(ws + o_ptr);
    int*      csr    = (int*)(ws + o_csr);
    float*    dinv   = ws + o_dinv;
    float*    h1     = ws + o_h1;
    _Float16* atab   = (_Float16*)(ws + o_atab);
    _Float16* btab   = (_Float16*)(ws + o_btab);
    float*    agg    = ws + o_agg;
    _Float16* xh     = (_Float16*)(ws + o_xh);
    _Float16* h2h    = (_Float16*)(ws + o_h2h);
    int2*     stage  = (int2*)(ws + o_stage);
    int*      bcur   = (int*)(ws + o_bcur);
    int*      part   = (int*)(ws + o_part);
    int*      offs   = (int*)(ws + o_offs);

    int nblk = (n + 3) / 4;                      // wave-per-node kernels, 4 waves/block
    int tblk = (ntiles + 3) / 4;
    int scan_nb = (n + SCAN_CHUNK - 1) / SCAN_CHUNK;   // 25 <= 64
    int fill_nb = (E + FILL_CH - 1) / FILL_CH;         // 196
    int m4 = n * 8;                                    // x float4 count

    k_zero4<<<(int)((npad / 4 + 255) / 256), 256, 0, stream>>>((float4*)deg, (int)(npad / 4));
    k_xcast<<<(m4 + 255) / 256, 256, 0, stream>>>((const float4*)x, (f16x4*)xh, m4);
    k_deg<<<(E + 255) / 256, 256, 0, stream>>>(col, deg, E);
    k_scan_partial<<<scan_nb, 256, 0, stream>>>(deg, part, n);
    k_scan_offsets<<<1, 64, 0, stream>>>(part, offs, ptr, scan_nb, n, E);
    k_scan_final<<<scan_nb, 256, 0, stream>>>(deg, offs, ptr, bcur, dinv, n);
    k_fill_a<<<fill_nb, 256, 0, stream>>>(row, col, bcur, stage, E, nbuck);
    k_fill_b<<<nbuck, 256, 0, stream>>>(ptr, stage, csr, n);
    k_gather32<<<nblk, 256, 0, stream>>>(ptr, csr, x, xh, dinv, agg, n);
    k_h1<<<tblk, 256, 0, stream>>>(agg, g1w, g1b, h1, ntiles);
    k_w1tab<<<256, 256, 0, stream>>>(h1, ew1, eb1, atab, btab, ntiles);
    k_edge_mlp<<<2048, 256, 0, stream>>>(ptr, csr, atab, btab, ew2, eb2, g2w, h2h, n);
    k_gcn2_gather<<<nblk, 256, 0, stream>>>(ptr, csr, h2h, dinv, g2b, out, n);
}